// Round 2
// baseline (598.025 us; speedup 1.0000x reference)
//
#include <hip/hip_runtime.h>

// CausalSelfAttention on MI355X: bf16 MFMA pipeline.
// B=4, S=2048, D=1024, H=16, hd=64. fp32 in/out, bf16 internal compute.

#define DEV __device__ __forceinline__

typedef unsigned short u16;
typedef u16   u16x8 __attribute__((ext_vector_type(8)));
typedef u16   u16x4 __attribute__((ext_vector_type(4)));
typedef float f32x4v __attribute__((ext_vector_type(4)));
typedef __bf16 bf16x8 __attribute__((ext_vector_type(8)));

#define BB 4
#define SS 2048
#define DD 1024
#define HH 16
#define HD 64
#define MM (BB*SS)          // 8192
#define N3D (3*DD)          // 3072
#define L2E 1.44269504088896340736f

DEV u16 f2bf(float f) { return __builtin_bit_cast(u16, (__bf16)f); }  // RNE, v_cvt_pk_bf16_f32
DEV float bf2f(u16 h) { return __builtin_bit_cast(float, (unsigned)h << 16); }

DEV f32x4v mfma16(u16x8 a, u16x8 b, f32x4v c) {
  return __builtin_amdgcn_mfma_f32_16x16x32_bf16(
      __builtin_bit_cast(bf16x8, a), __builtin_bit_cast(bf16x8, b), c, 0, 0, 0);
}

// async global->LDS, 16B per lane. LDS dest must be linear in lane order.
DEV void async16(const void* g, void* l) {
  __builtin_amdgcn_global_load_lds(
      (const __attribute__((address_space(1))) void*)g,
      (__attribute__((address_space(3))) void*)l, 16, 0, 0);
}

// DPP rotate-reduce within 16-lane rows (VALU pipe, no LDS traffic).
template <int C> DEV float dpp_fmax(float x) {
  int xi = __builtin_bit_cast(int, x);
  int y = __builtin_amdgcn_update_dpp(xi, xi, C, 0xF, 0xF, false);
  return fmaxf(x, __builtin_bit_cast(float, y));
}
template <int C> DEV float dpp_fadd(float x) {
  int xi = __builtin_bit_cast(int, x);
  int y = __builtin_amdgcn_update_dpp(xi, xi, C, 0xF, 0xF, false);
  return x + __builtin_bit_cast(float, y);
}
DEV float rowmax16(float x) {  // max over the 16 lanes of a DPP row
  x = dpp_fmax<0x121>(x);  // row_ror:1
  x = dpp_fmax<0x122>(x);  // row_ror:2
  x = dpp_fmax<0x124>(x);  // row_ror:4
  x = dpp_fmax<0x128>(x);  // row_ror:8
  return x;
}
DEV float rowsum16(float x) {
  x = dpp_fadd<0x121>(x);
  x = dpp_fadd<0x122>(x);
  x = dpp_fadd<0x124>(x);
  x = dpp_fadd<0x128>(x);
  return x;
}

// ---------------- 1. fp32 -> bf16 convert (vectorized, grid-stride) ----------
__global__ void convert_f32_bf16(const float* __restrict__ in, u16* __restrict__ out,
                                 long long n) {
  long long i = (long long)blockIdx.x * blockDim.x + threadIdx.x;
  long long stride = (long long)gridDim.x * blockDim.x;
  for (long long j = i * 4; j < n; j += stride * 4) {
    f32x4v v = *(const f32x4v*)(in + j);
    u16x4 o;
    o.x = f2bf(v.x); o.y = f2bf(v.y); o.z = f2bf(v.z); o.w = f2bf(v.w);
    *(u16x4*)(out + j) = o;
  }
}

// ---------------- 2. weight transpose: W[K][N] f32 -> Wt[N][K] bf16 ----------
__global__ void transpose_w(const float* __restrict__ W, u16* __restrict__ Wt,
                            int K, int N) {
  __shared__ float t[32][33];
  int n0 = blockIdx.x * 32, k0 = blockIdx.y * 32;
  for (int i = threadIdx.y; i < 32; i += 8)
    t[i][threadIdx.x] = W[(long long)(k0 + i) * N + n0 + threadIdx.x];
  __syncthreads();
  for (int i = threadIdx.y; i < 32; i += 8)
    Wt[(long long)(n0 + i) * K + k0 + threadIdx.x] = f2bf(t[threadIdx.x][i]);
}

// ---------------- 3. GEMM: C[M][N] = A[M][K] * Bt[N][K]^T + bias -------------
// 128x128 tile, BK=64, 4 waves (each 64x64), 16x16x32 bf16 MFMA (m97 structure).
__global__ __launch_bounds__(256) void gemm_kernel(
    const u16* __restrict__ A, const u16* __restrict__ Bt,
    const float* __restrict__ bias, void* __restrict__ Cout,
    int Ndim, int Kdim, int bf16out) {
  __shared__ __align__(16) u16 As[128 * 64];
  __shared__ __align__(16) u16 Bs[128 * 64];

  const int tid = threadIdx.x;
  const int lane = tid & 63, wid = tid >> 6;
  const int l15 = lane & 15, lg = lane >> 4;
  const int rb = blockIdx.y * 128, cb = blockIdx.x * 128;
  const int wr = (wid >> 1) * 64, wc = (wid & 1) * 64;

  f32x4v acc[4][4] = {};

  const int scol = (tid & 7) * 8;     // k-offset within tile this thread fetches
  const int srow = tid >> 3;          // base row (0..31), +32 per issue

  for (int kt = 0; kt < Kdim; kt += 64) {
#pragma unroll
    for (int i = 0; i < 4; ++i) {
      int row = i * 32 + srow;
      async16(A + (long long)(rb + row) * Kdim + kt + scol, (char*)As + i * 4096 + tid * 16);
      async16(Bt + (long long)(cb + row) * Kdim + kt + scol, (char*)Bs + i * 4096 + tid * 16);
    }
    __syncthreads();
#pragma unroll
    for (int kk = 0; kk < 2; ++kk) {
      u16x8 a[4], b[4];
#pragma unroll
      for (int mi = 0; mi < 4; ++mi)
        a[mi] = *(const u16x8*)&As[(wr + mi * 16 + l15) * 64 + kk * 32 + lg * 8];
#pragma unroll
      for (int ni = 0; ni < 4; ++ni)
        b[ni] = *(const u16x8*)&Bs[(wc + ni * 16 + l15) * 64 + kk * 32 + lg * 8];
#pragma unroll
      for (int mi = 0; mi < 4; ++mi)
#pragma unroll
        for (int ni = 0; ni < 4; ++ni)
          acc[mi][ni] = mfma16(a[mi], b[ni], acc[mi][ni]);
    }
    __syncthreads();
  }

#pragma unroll
  for (int mi = 0; mi < 4; ++mi)
#pragma unroll
    for (int ni = 0; ni < 4; ++ni) {
      int col = cb + wc + ni * 16 + l15;
      float bv = bias[col];
#pragma unroll
      for (int r = 0; r < 4; ++r) {
        int row = rb + wr + mi * 16 + lg * 4 + r;
        float v = acc[mi][ni][r] + bv;
        if (bf16out) ((u16*)Cout)[(long long)row * Ndim + col] = f2bf(v);
        else         ((float*)Cout)[(long long)row * Ndim + col] = v;
      }
    }
}

// ---------------- 4. pack Q,K: qkv[8192][3072] -> per-head [BH][S][64] -------
// Q scaled by 1/8 (exact in bf16).
__global__ void pack_qk(const u16* __restrict__ qkv, u16* __restrict__ Qw,
                        u16* __restrict__ Kw) {
  int sglob = blockIdx.x;
  int c = threadIdx.x * 8;  // 0..2047 (Q and K halves)
  u16x8 v = *(const u16x8*)(qkv + (long long)sglob * N3D + c);
  int part = c >> 10;
  int h = (c & 1023) >> 6;
  int d = c & 63;
  int b = sglob >> 11;
  int s = sglob & 2047;
  long long dst = ((long long)(b * HH + h) * SS + s) * HD + d;
  if (part == 0) {
#pragma unroll
    for (int j = 0; j < 8; ++j) v[j] = f2bf(bf2f(v[j]) * 0.125f);
    *(u16x8*)(Qw + dst) = v;
  } else {
    *(u16x8*)(Kw + dst) = v;
  }
}

// ---------------- 5. V transpose: qkv V part -> Vt[BH][64][S] ----------------
__global__ void transpose_v(const u16* __restrict__ qkv, u16* __restrict__ Vt) {
  __shared__ u16 t[32][33];
  int s0 = blockIdx.x * 32, d0 = blockIdx.y * 32, bh = blockIdx.z;
  int b = bh >> 4, h = bh & 15;
  for (int i = threadIdx.y; i < 32; i += 8)
    t[i][threadIdx.x] =
        qkv[(long long)(b * SS + s0 + i) * N3D + 2 * DD + h * HD + d0 + threadIdx.x];
  __syncthreads();
  for (int i = threadIdx.y; i < 32; i += 8)
    Vt[((long long)bh * HD + d0 + i) * SS + s0 + threadIdx.x] = t[threadIdx.x][i];
}

// ---------------- 6. flash attention, causal -------------------------------
// block = 256 thr (4 waves), q-tile = 64 rows (16/wave), kv-tile = 64.
// No K/V LDS staging (L2-resident: K+V = 512KB/head); no __syncthreads at all.
// Heavy q-tiles first: qt = 31 - blockIdx.x. P via per-wave XOR-swizzled LDS.
__global__ __launch_bounds__(256) void attn_kernel(
    const u16* __restrict__ Qw, const u16* __restrict__ Kw,
    const u16* __restrict__ Vt, u16* __restrict__ ctx) {
  __shared__ __align__(16) u16 Ps[4][16 * 64];

  const int tid = threadIdx.x, lane = tid & 63, wid = tid >> 6;
  const int l15 = lane & 15, lg = lane >> 4;
  const int qt = (int)gridDim.x - 1 - (int)blockIdx.x;   // heavy-first
  const int q0 = qt * 64, bh = blockIdx.y;
  const int qw = q0 + wid * 16;
  const int b = bh >> 4, h = bh & 15;

  const u16* Qbh = Qw + (long long)bh * SS * HD;
  const u16* Kbh = Kw + (long long)bh * SS * HD;
  const u16* Vbh = Vt + (long long)bh * HD * SS;
  char* Pw = (char*)&Ps[wid][0];

  // Q fragments (pre-scaled by 1/8); A-frag: row = l15, k = kk*32+lg*8+j
  u16x8 qf[2];
#pragma unroll
  for (int kk = 0; kk < 2; ++kk)
    qf[kk] = *(const u16x8*)(Qbh + (long long)(qw + l15) * HD + kk * 32 + lg * 8);

  f32x4v acc[4] = {};
  float m_s[4], l_s[4];
#pragma unroll
  for (int r = 0; r < 4; ++r) { m_s[r] = -1e30f; l_s[r] = 0.f; }

  const int nkb = qt + 1;
  for (int kb = 0; kb < nkb; ++kb) {
    const int kbase = kb * 64;

    // ---- S = Q K^T  (C: row=lg*4+r -> q, col=l15 -> k within ni*16) ----
    f32x4v s[4] = {};
#pragma unroll
    for (int kk = 0; kk < 2; ++kk) {
      u16x8 bfr[4];
#pragma unroll
      for (int ni = 0; ni < 4; ++ni)
        bfr[ni] = *(const u16x8*)(Kbh + (long long)(kbase + ni * 16 + l15) * HD + kk * 32 + lg * 8);
#pragma unroll
      for (int ni = 0; ni < 4; ++ni)
        s[ni] = mfma16(qf[kk], bfr[ni], s[ni]);
    }

    // ---- causal mask (diagonal tile only) ----
    if (kb == nkb - 1) {
#pragma unroll
      for (int ni = 0; ni < 4; ++ni) {
        int kcol = kbase + ni * 16 + l15;
#pragma unroll
        for (int r = 0; r < 4; ++r) {
          int qrow = qw + lg * 4 + r;
          if (kcol > qrow) s[ni][r] = -1e30f;
        }
      }
    }

    // ---- online softmax; log2-domain via fma(s, L2E, -m*L2E) ----
#pragma unroll
    for (int r = 0; r < 4; ++r) {
      float smax = fmaxf(fmaxf(s[0][r], s[1][r]), fmaxf(s[2][r], s[3][r]));
      smax = rowmax16(smax);
      float newm = fmaxf(m_s[r], smax);
      float scale = __builtin_exp2f((m_s[r] - newm) * L2E);
      float mL2 = newm * L2E;
      m_s[r] = newm;
      float rsum = 0.f;
#pragma unroll
      for (int ni = 0; ni < 4; ++ni) {
        float p = __builtin_exp2f(__builtin_fmaf(s[ni][r], L2E, -mL2));
        s[ni][r] = p;
        rsum += p;
      }
      rsum = rowsum16(rsum);
      l_s[r] = l_s[r] * scale + rsum;
#pragma unroll
      for (int di = 0; di < 4; ++di) acc[di][r] *= scale;
    }

    // ---- P -> LDS (bf16), XOR-swizzled; same-wave RAW, no barrier ----
#pragma unroll
    for (int ni = 0; ni < 4; ++ni)
#pragma unroll
      for (int r = 0; r < 4; ++r) {
        int row = lg * 4 + r;
        int cb2 = (ni * 16 + l15) * 2;
        *(u16*)(Pw + row * 128 + (cb2 ^ ((row & 7) << 4))) = f2bf(s[ni][r]);
      }

    // ---- O += P V ----
#pragma unroll
    for (int ks = 0; ks < 2; ++ks) {
      u16x8 pa = *(const u16x8*)(Pw + l15 * 128 + ((ks * 64 + lg * 16) ^ ((l15 & 7) << 4)));
      u16x8 vb[4];
#pragma unroll
      for (int di = 0; di < 4; ++di)
        vb[di] = *(const u16x8*)(Vbh + (long long)(di * 16 + l15) * SS + kbase + ks * 32 + lg * 8);
#pragma unroll
      for (int di = 0; di < 4; ++di)
        acc[di] = mfma16(pa, vb[di], acc[di]);
    }
  }

  // finalize: ctx[b, q, h*64+d]
#pragma unroll
  for (int r = 0; r < 4; ++r) {
    float inv = 1.f / l_s[r];
    int qrow = qw + lg * 4 + r;
#pragma unroll
    for (int di = 0; di < 4; ++di) {
      int d = di * 16 + l15;
      ctx[((long long)(b * SS + qrow)) * DD + h * HD + d] = f2bf(acc[di][r] * inv);
    }
  }
}

// ---------------- launch -----------------------------------------------------
extern "C" void kernel_launch(void* const* d_in, const int* in_sizes, int n_in,
                              void* d_out, int out_size, void* d_ws, size_t ws_size,
                              hipStream_t stream) {
  const float* inp    = (const float*)d_in[0];
  const float* w_attn = (const float*)d_in[1];
  const float* b_attn = (const float*)d_in[2];
  const float* w_proj = (const float*)d_in[3];
  const float* b_proj = (const float*)d_in[4];
  float* out = (float*)d_out;
  char* ws = (char*)d_ws;

  // workspace layout (bytes)
  const long long off_A   = 0;                       // inp bf16 [8192][1024]  16MB (reused as Qw)
  const long long off_WAt = 16777216;                // w_attn^T bf16 [3072][1024]  6MB
  const long long off_WPt = 23068672;                // w_proj^T bf16 [1024][1024]  2MB
  const long long off_qkv = 25165824;                // qkv bf16 [8192][3072]  48MB (reused as ctx)
  const long long off_K   = 75497472;                // K  [64][2048][64] 16MB
  const long long off_Vt  = 92274688;                // Vt [64][64][2048] 16MB
  const long long need    = 109051904;
  if (ws_size < (size_t)need) return;

  u16* Abf = (u16*)(ws + off_A);
  u16* WAt = (u16*)(ws + off_WAt);
  u16* WPt = (u16*)(ws + off_WPt);
  u16* qkv = (u16*)(ws + off_qkv);
  u16* Qw  = Abf;        // reuse: Abf dead after QKV gemm
  u16* Kw  = (u16*)(ws + off_K);
  u16* Vt  = (u16*)(ws + off_Vt);
  u16* ctx = qkv;        // reuse: qkv dead after pack/transpose

  // 1. inp -> bf16
  convert_f32_bf16<<<2048, 256, 0, stream>>>(inp, Abf, (long long)MM * DD);
  // 2. weight transposes
  transpose_w<<<dim3(N3D / 32, DD / 32), dim3(32, 8), 0, stream>>>(w_attn, WAt, DD, N3D);
  transpose_w<<<dim3(DD / 32, DD / 32), dim3(32, 8), 0, stream>>>(w_proj, WPt, DD, DD);
  // 3. QKV gemm: [8192][3072] bf16
  gemm_kernel<<<dim3(N3D / 128, MM / 128), 256, 0, stream>>>(Abf, WAt, b_attn, qkv, N3D, DD, 1);
  // 4. pack Q (scaled), K
  pack_qk<<<MM, 256, 0, stream>>>(qkv, Qw, Kw);
  // 5. transpose V
  transpose_v<<<dim3(SS / 32, HD / 32, BB * HH), dim3(32, 8), 0, stream>>>(qkv, Vt);
  // 6. attention -> ctx bf16 [8192][1024]  (64-row q-tiles, heavy-first)
  attn_kernel<<<dim3(SS / 64, BB * HH), 256, 0, stream>>>(Qw, Kw, Vt, ctx);
  // 7. output projection -> fp32 d_out
  gemm_kernel<<<dim3(DD / 128, MM / 128), 256, 0, stream>>>(ctx, WPt, b_proj, out, DD, DD, 0);
}

// Round 3
// 321.634 us; speedup vs baseline: 1.8593x; 1.8593x over previous
//
#include <hip/hip_runtime.h>

// CausalSelfAttention on MI355X: bf16 MFMA pipeline.
// B=4, S=2048, D=1024, H=16, hd=64. fp32 in/out, bf16 internal compute.

#define DEV __device__ __forceinline__

typedef unsigned short u16;
typedef u16   u16x8 __attribute__((ext_vector_type(8)));
typedef u16   u16x4 __attribute__((ext_vector_type(4)));
typedef float f32x4v __attribute__((ext_vector_type(4)));
typedef __bf16 bf16x8 __attribute__((ext_vector_type(8)));

#define BB 4
#define SS 2048
#define DD 1024
#define HH 16
#define HD 64
#define MM (BB*SS)          // 8192
#define N3D (3*DD)          // 3072
#define L2E 1.44269504088896340736f

DEV u16 f2bf(float f) { return __builtin_bit_cast(u16, (__bf16)f); }  // RNE
DEV float bf2f(u16 h) { return __builtin_bit_cast(float, (unsigned)h << 16); }

DEV f32x4v mfma16(u16x8 a, u16x8 b, f32x4v c) {
  return __builtin_amdgcn_mfma_f32_16x16x32_bf16(
      __builtin_bit_cast(bf16x8, a), __builtin_bit_cast(bf16x8, b), c, 0, 0, 0);
}

// async global->LDS, 16B per lane. LDS dest must be linear in lane order.
DEV void async16(const void* g, void* l) {
  __builtin_amdgcn_global_load_lds(
      (const __attribute__((address_space(1))) void*)g,
      (__attribute__((address_space(3))) void*)l, 16, 0, 0);
}

// DPP rotate-reduce within 16-lane rows (VALU pipe, no LDS traffic).
template <int C> DEV float dpp_fmax(float x) {
  int xi = __builtin_bit_cast(int, x);
  int y = __builtin_amdgcn_update_dpp(xi, xi, C, 0xF, 0xF, false);
  return fmaxf(x, __builtin_bit_cast(float, y));
}
template <int C> DEV float dpp_fadd(float x) {
  int xi = __builtin_bit_cast(int, x);
  int y = __builtin_amdgcn_update_dpp(xi, xi, C, 0xF, 0xF, false);
  return x + __builtin_bit_cast(float, y);
}
DEV float rowmax16(float x) {  // max over the 16 lanes of a DPP row
  x = dpp_fmax<0x121>(x);
  x = dpp_fmax<0x122>(x);
  x = dpp_fmax<0x124>(x);
  x = dpp_fmax<0x128>(x);
  return x;
}
DEV float rowsum16(float x) {
  x = dpp_fadd<0x121>(x);
  x = dpp_fadd<0x122>(x);
  x = dpp_fadd<0x124>(x);
  x = dpp_fadd<0x128>(x);
  return x;
}

// ---------------- 1. fp32 -> bf16 convert (vectorized, grid-stride) ----------
__global__ void convert_f32_bf16(const float* __restrict__ in, u16* __restrict__ out,
                                 long long n) {
  long long i = (long long)blockIdx.x * blockDim.x + threadIdx.x;
  long long stride = (long long)gridDim.x * blockDim.x;
  for (long long j = i * 4; j < n; j += stride * 4) {
    f32x4v v = *(const f32x4v*)(in + j);
    u16x4 o;
    o.x = f2bf(v.x); o.y = f2bf(v.y); o.z = f2bf(v.z); o.w = f2bf(v.w);
    *(u16x4*)(out + j) = o;
  }
}

// ---------------- 2. weight transpose: W[K][N] f32 -> Wt[N][K] bf16 ----------
__global__ void transpose_w(const float* __restrict__ W, u16* __restrict__ Wt,
                            int K, int N) {
  __shared__ float t[32][33];
  int n0 = blockIdx.x * 32, k0 = blockIdx.y * 32;
  for (int i = threadIdx.y; i < 32; i += 8)
    t[i][threadIdx.x] = W[(long long)(k0 + i) * N + n0 + threadIdx.x];
  __syncthreads();
  for (int i = threadIdx.y; i < 32; i += 8)
    Wt[(long long)(n0 + i) * K + k0 + threadIdx.x] = f2bf(t[threadIdx.x][i]);
}

// ---------------- 3. GEMM: C[M][N] = A[M][K] * Bt[N][K]^T + bias -------------
// 128x128 tile, BK=64, 4 waves (each 64x64), 16x16x32 bf16 MFMA (m97 structure).
__global__ __launch_bounds__(256) void gemm_kernel(
    const u16* __restrict__ A, const u16* __restrict__ Bt,
    const float* __restrict__ bias, void* __restrict__ Cout,
    int Ndim, int Kdim, int bf16out) {
  __shared__ __align__(16) u16 As[128 * 64];
  __shared__ __align__(16) u16 Bs[128 * 64];

  const int tid = threadIdx.x;
  const int lane = tid & 63, wid = tid >> 6;
  const int l15 = lane & 15, lg = lane >> 4;
  const int rb = blockIdx.y * 128, cb = blockIdx.x * 128;
  const int wr = (wid >> 1) * 64, wc = (wid & 1) * 64;

  f32x4v acc[4][4] = {};

  const int scol = (tid & 7) * 8;     // k-offset within tile this thread fetches
  const int srow = tid >> 3;          // base row (0..31), +32 per issue

  for (int kt = 0; kt < Kdim; kt += 64) {
#pragma unroll
    for (int i = 0; i < 4; ++i) {
      int row = i * 32 + srow;
      async16(A + (long long)(rb + row) * Kdim + kt + scol, (char*)As + i * 4096 + tid * 16);
      async16(Bt + (long long)(cb + row) * Kdim + kt + scol, (char*)Bs + i * 4096 + tid * 16);
    }
    __syncthreads();
#pragma unroll
    for (int kk = 0; kk < 2; ++kk) {
      u16x8 a[4], b[4];
#pragma unroll
      for (int mi = 0; mi < 4; ++mi)
        a[mi] = *(const u16x8*)&As[(wr + mi * 16 + l15) * 64 + kk * 32 + lg * 8];
#pragma unroll
      for (int ni = 0; ni < 4; ++ni)
        b[ni] = *(const u16x8*)&Bs[(wc + ni * 16 + l15) * 64 + kk * 32 + lg * 8];
#pragma unroll
      for (int mi = 0; mi < 4; ++mi)
#pragma unroll
        for (int ni = 0; ni < 4; ++ni)
          acc[mi][ni] = mfma16(a[mi], b[ni], acc[mi][ni]);
    }
    __syncthreads();
  }

#pragma unroll
  for (int mi = 0; mi < 4; ++mi)
#pragma unroll
    for (int ni = 0; ni < 4; ++ni) {
      int col = cb + wc + ni * 16 + l15;
      float bv = bias[col];
#pragma unroll
      for (int r = 0; r < 4; ++r) {
        int row = rb + wr + mi * 16 + lg * 4 + r;
        float v = acc[mi][ni][r] + bv;
        if (bf16out) ((u16*)Cout)[(long long)row * Ndim + col] = f2bf(v);
        else         ((float*)Cout)[(long long)row * Ndim + col] = v;
      }
    }
}

// ---------------- 4. pack Q,K: qkv[8192][3072] -> per-head [BH][S][64] -------
// Q scaled by 1/8 (exact in bf16).
__global__ void pack_qk(const u16* __restrict__ qkv, u16* __restrict__ Qw,
                        u16* __restrict__ Kw) {
  int sglob = blockIdx.x;
  int c = threadIdx.x * 8;  // 0..2047 (Q and K halves)
  u16x8 v = *(const u16x8*)(qkv + (long long)sglob * N3D + c);
  int part = c >> 10;
  int h = (c & 1023) >> 6;
  int d = c & 63;
  int b = sglob >> 11;
  int s = sglob & 2047;
  long long dst = ((long long)(b * HH + h) * SS + s) * HD + d;
  if (part == 0) {
#pragma unroll
    for (int j = 0; j < 8; ++j) v[j] = f2bf(bf2f(v[j]) * 0.125f);
    *(u16x8*)(Qw + dst) = v;
  } else {
    *(u16x8*)(Kw + dst) = v;
  }
}

// ---------------- 5. V transpose: qkv V part -> Vt[BH][64][S] ----------------
__global__ void transpose_v(const u16* __restrict__ qkv, u16* __restrict__ Vt) {
  __shared__ u16 t[32][33];
  int s0 = blockIdx.x * 32, d0 = blockIdx.y * 32, bh = blockIdx.z;
  int b = bh >> 4, h = bh & 15;
  for (int i = threadIdx.y; i < 32; i += 8)
    t[i][threadIdx.x] =
        qkv[(long long)(b * SS + s0 + i) * N3D + 2 * DD + h * HD + d0 + threadIdx.x];
  __syncthreads();
  for (int i = threadIdx.y; i < 32; i += 8)
    Vt[((long long)bh * HD + d0 + i) * SS + s0 + threadIdx.x] = t[threadIdx.x][i];
}

// ---------------- 6. flash attention, causal -------------------------------
// block = 256 thr (4 waves), q-tile = 128 rows (32/wave), kv-tile = 64.
// K/V double-buffered in LDS via global_load_lds with pre-swizzled source
// (linear dest + inverse-swizzled src + swizzled ds_read). 2-phase pipeline:
// stage(next) issued before compute(cur); one barrier per tile drains vmcnt.
// Heavy q-tiles first + bijective XCD swizzle (nwg=1024 % 8 == 0).
__global__ __launch_bounds__(256) void attn_kernel(
    const u16* __restrict__ Qw, const u16* __restrict__ Kw,
    const u16* __restrict__ Vt, u16* __restrict__ ctx) {
  __shared__ __align__(16) u16 Ks[2][64 * 64];
  __shared__ __align__(16) u16 Vs[2][64 * 64];
  __shared__ __align__(16) u16 Ps[4][32 * 64];

  const int tid = threadIdx.x, lane = tid & 63, wid = tid >> 6;
  const int l15 = lane & 15, lg = lane >> 4;

  // XCD-aware swizzle: orig -> (orig%8)*128 + orig/8  (1024 blocks, bijective)
  const int orig = (int)(blockIdx.y * gridDim.x + blockIdx.x);
  const int wgid = (orig & 7) * 128 + (orig >> 3);
  const int qt = 15 - (wgid & 15);       // heavy-first within each head
  const int bh = wgid >> 4;
  const int q0 = qt * 128;
  const int qw = q0 + wid * 32;
  const int b = bh >> 4, h = bh & 15;

  const u16* Qbh = Qw + (long long)bh * SS * HD;
  const u16* Kbh = Kw + (long long)bh * SS * HD;
  const u16* Vbh = Vt + (long long)bh * HD * SS;
  char* Pw = (char*)&Ps[wid][0];

  // Q fragments (pre-scaled by 1/8); A-frag: row = l15, k = kk*32+lg*8+j
  u16x8 qf[2][2];
#pragma unroll
  for (int mi = 0; mi < 2; ++mi)
#pragma unroll
    for (int kk = 0; kk < 2; ++kk)
      qf[mi][kk] = *(const u16x8*)(Qbh + (long long)(qw + mi * 16 + l15) * HD + kk * 32 + lg * 8);

  f32x4v acc[2][4] = {};
  float m_s[2][4], l_s[2][4];
#pragma unroll
  for (int mi = 0; mi < 2; ++mi)
#pragma unroll
    for (int r = 0; r < 4; ++r) { m_s[mi][r] = -1e30f; l_s[mi][r] = 0.f; }

  // stage tile (64 rows x 128B) of K and V into buffer bi, source pre-swizzled
  const int rlo = tid >> 3;            // 0..31
  const int cbS = (tid & 7) * 16;      // byte col 0..112
  const int swS = cbS ^ ((rlo & 7) << 4);
  auto stage = [&](int bi, int kbase) {
#pragma unroll
    for (int i = 0; i < 2; ++i) {
      int row = i * 32 + rlo;
      async16((const char*)(Kbh + (long long)(kbase + row) * HD) + swS,
              (char*)&Ks[bi][0] + row * 128 + cbS);
      async16((const char*)(Vbh + (long long)row * SS + kbase) + swS,
              (char*)&Vs[bi][0] + row * 128 + cbS);
    }
  };

  const int nkb = 2 * qt + 2;   // tiles with kbase <= q0+127
  stage(0, 0);
  __syncthreads();              // drains vmcnt before first compute

  int cur = 0;
  for (int kb = 0; kb < nkb; ++kb) {
    const int kbase = kb * 64;
    if (kb + 1 < nkb) stage(cur ^ 1, (kb + 1) * 64);   // prefetch next tile

    if (kbase <= qw + 31) {     // skip fully-masked tiles (waves 0/1 tail)
      const char* Kb = (const char*)&Ks[cur][0];
      const char* Vb = (const char*)&Vs[cur][0];

      // ---- S = Q K^T ----
      f32x4v s[2][4] = {};
#pragma unroll
      for (int kk = 0; kk < 2; ++kk) {
        u16x8 bfr[4];
#pragma unroll
        for (int ni = 0; ni < 4; ++ni)
          bfr[ni] = *(const u16x8*)(Kb + (ni * 16 + l15) * 128 +
                                    ((kk * 64 + lg * 16) ^ ((l15 & 7) << 4)));
#pragma unroll
        for (int mi = 0; mi < 2; ++mi)
#pragma unroll
          for (int ni = 0; ni < 4; ++ni)
            s[mi][ni] = mfma16(qf[mi][kk], bfr[ni], s[mi][ni]);
      }

      // ---- causal mask (diagonal-overlap tiles only) ----
      if (kbase + 63 > qw) {
#pragma unroll
        for (int mi = 0; mi < 2; ++mi)
#pragma unroll
          for (int ni = 0; ni < 4; ++ni) {
            int kcol = kbase + ni * 16 + l15;
#pragma unroll
            for (int r = 0; r < 4; ++r) {
              int qrow = qw + mi * 16 + lg * 4 + r;
              if (kcol > qrow) s[mi][ni][r] = -1e30f;
            }
          }
      }

      // ---- online softmax (DPP row reductions, log2 domain) ----
#pragma unroll
      for (int mi = 0; mi < 2; ++mi)
#pragma unroll
        for (int r = 0; r < 4; ++r) {
          float smax = fmaxf(fmaxf(s[mi][0][r], s[mi][1][r]),
                             fmaxf(s[mi][2][r], s[mi][3][r]));
          smax = rowmax16(smax);
          float newm = fmaxf(m_s[mi][r], smax);
          float scale = __builtin_exp2f((m_s[mi][r] - newm) * L2E);
          float mL2 = newm * L2E;
          m_s[mi][r] = newm;
          float rsum = 0.f;
#pragma unroll
          for (int ni = 0; ni < 4; ++ni) {
            float p = __builtin_exp2f(__builtin_fmaf(s[mi][ni][r], L2E, -mL2));
            s[mi][ni][r] = p;
            rsum += p;
          }
          rsum = rowsum16(rsum);
          l_s[mi][r] = l_s[mi][r] * scale + rsum;
#pragma unroll
          for (int di = 0; di < 4; ++di) acc[mi][di][r] *= scale;
        }

      // ---- P -> LDS (bf16, swizzled); same-wave RAW, no barrier ----
#pragma unroll
      for (int mi = 0; mi < 2; ++mi)
#pragma unroll
        for (int ni = 0; ni < 4; ++ni)
#pragma unroll
          for (int r = 0; r < 4; ++r) {
            int row = mi * 16 + lg * 4 + r;
            int cb2 = (ni * 16 + l15) * 2;
            *(u16*)(Pw + row * 128 + (cb2 ^ ((row & 7) << 4))) = f2bf(s[mi][ni][r]);
          }

      // ---- O += P V ----
#pragma unroll
      for (int ks = 0; ks < 2; ++ks) {
        u16x8 pa[2], vb[4];
#pragma unroll
        for (int mi = 0; mi < 2; ++mi)
          pa[mi] = *(const u16x8*)(Pw + (mi * 16 + l15) * 128 +
                                   ((ks * 64 + lg * 16) ^ ((l15 & 7) << 4)));
#pragma unroll
        for (int di = 0; di < 4; ++di)
          vb[di] = *(const u16x8*)(Vb + (di * 16 + l15) * 128 +
                                   ((ks * 64 + lg * 16) ^ ((l15 & 7) << 4)));
#pragma unroll
        for (int mi = 0; mi < 2; ++mi)
#pragma unroll
          for (int di = 0; di < 4; ++di)
            acc[mi][di] = mfma16(pa[mi], vb[di], acc[mi][di]);
      }
    }

    __syncthreads();   // drains staged loads (vmcnt) + protects dbuf swap
    cur ^= 1;
  }

  // finalize: ctx[b, q, h*64+d]
#pragma unroll
  for (int mi = 0; mi < 2; ++mi)
#pragma unroll
    for (int r = 0; r < 4; ++r) {
      float inv = 1.f / l_s[mi][r];
      int qrow = qw + mi * 16 + lg * 4 + r;
#pragma unroll
      for (int di = 0; di < 4; ++di) {
        int d = di * 16 + l15;
        ctx[((long long)(b * SS + qrow)) * DD + h * HD + d] = f2bf(acc[mi][di][r] * inv);
      }
    }
}

// ---------------- launch -----------------------------------------------------
extern "C" void kernel_launch(void* const* d_in, const int* in_sizes, int n_in,
                              void* d_out, int out_size, void* d_ws, size_t ws_size,
                              hipStream_t stream) {
  const float* inp    = (const float*)d_in[0];
  const float* w_attn = (const float*)d_in[1];
  const float* b_attn = (const float*)d_in[2];
  const float* w_proj = (const float*)d_in[3];
  const float* b_proj = (const float*)d_in[4];
  float* out = (float*)d_out;
  char* ws = (char*)d_ws;

  // workspace layout (bytes)
  const long long off_A   = 0;                       // inp bf16 [8192][1024]  16MB (reused as Qw)
  const long long off_WAt = 16777216;                // w_attn^T bf16 [3072][1024]  6MB
  const long long off_WPt = 23068672;                // w_proj^T bf16 [1024][1024]  2MB
  const long long off_qkv = 25165824;                // qkv bf16 [8192][3072]  48MB (reused as ctx)
  const long long off_K   = 75497472;                // K  [64][2048][64] 16MB
  const long long off_Vt  = 92274688;                // Vt [64][64][2048] 16MB
  const long long need    = 109051904;
  if (ws_size < (size_t)need) return;

  u16* Abf = (u16*)(ws + off_A);
  u16* WAt = (u16*)(ws + off_WAt);
  u16* WPt = (u16*)(ws + off_WPt);
  u16* qkv = (u16*)(ws + off_qkv);
  u16* Qw  = Abf;        // reuse: Abf dead after QKV gemm
  u16* Kw  = (u16*)(ws + off_K);
  u16* Vt  = (u16*)(ws + off_Vt);
  u16* ctx = qkv;        // reuse: qkv dead after pack/transpose

  // 1. inp -> bf16
  convert_f32_bf16<<<2048, 256, 0, stream>>>(inp, Abf, (long long)MM * DD);
  // 2. weight transposes
  transpose_w<<<dim3(N3D / 32, DD / 32), dim3(32, 8), 0, stream>>>(w_attn, WAt, DD, N3D);
  transpose_w<<<dim3(DD / 32, DD / 32), dim3(32, 8), 0, stream>>>(w_proj, WPt, DD, DD);
  // 3. QKV gemm: [8192][3072] bf16
  gemm_kernel<<<dim3(N3D / 128, MM / 128), 256, 0, stream>>>(Abf, WAt, b_attn, qkv, N3D, DD, 1);
  // 4. pack Q (scaled), K
  pack_qk<<<MM, 256, 0, stream>>>(qkv, Qw, Kw);
  // 5. transpose V
  transpose_v<<<dim3(SS / 32, HD / 32, BB * HH), dim3(32, 8), 0, stream>>>(qkv, Vt);
  // 6. attention -> ctx bf16 [8192][1024]  (128-row q-tiles, heavy-first, XCD-swizzled)
  attn_kernel<<<dim3(SS / 128, BB * HH), 256, 0, stream>>>(Qw, Kw, Vt, ctx);
  // 7. output projection -> fp32 d_out
  gemm_kernel<<<dim3(DD / 128, MM / 128), 256, 0, stream>>>(ctx, WPt, b_proj, out, DD, DD, 0);
}

// Round 4
// 288.370 us; speedup vs baseline: 2.0738x; 1.1154x over previous
//
#include <hip/hip_runtime.h>

// CausalSelfAttention on MI355X: bf16 MFMA pipeline.
// B=4, S=2048, D=1024, H=16, hd=64. fp32 in/out, bf16 internal compute.

#define DEV __device__ __forceinline__

typedef unsigned short u16;
typedef u16   u16x8 __attribute__((ext_vector_type(8)));
typedef u16   u16x4 __attribute__((ext_vector_type(4)));
typedef float f32x4v __attribute__((ext_vector_type(4)));
typedef __bf16 bf16x8 __attribute__((ext_vector_type(8)));

#define BB 4
#define SS 2048
#define DD 1024
#define HH 16
#define HD 64
#define MM (BB*SS)          // 8192
#define N3D (3*DD)          // 3072
#define L2E 1.44269504088896340736f

DEV u16 f2bf(float f) { return __builtin_bit_cast(u16, (__bf16)f); }  // RNE
DEV float bf2f(u16 h) { return __builtin_bit_cast(float, (unsigned)h << 16); }

DEV f32x4v mfma16(u16x8 a, u16x8 b, f32x4v c) {
  return __builtin_amdgcn_mfma_f32_16x16x32_bf16(
      __builtin_bit_cast(bf16x8, a), __builtin_bit_cast(bf16x8, b), c, 0, 0, 0);
}

// async global->LDS, 16B per lane. LDS dest must be linear in lane order.
DEV void async16(const void* g, void* l) {
  __builtin_amdgcn_global_load_lds(
      (const __attribute__((address_space(1))) void*)g,
      (__attribute__((address_space(3))) void*)l, 16, 0, 0);
}

// DPP rotate-reduce within 16-lane rows (VALU pipe, no LDS traffic).
template <int C> DEV float dpp_fmax(float x) {
  int xi = __builtin_bit_cast(int, x);
  int y = __builtin_amdgcn_update_dpp(xi, xi, C, 0xF, 0xF, false);
  return fmaxf(x, __builtin_bit_cast(float, y));
}
template <int C> DEV float dpp_fadd(float x) {
  int xi = __builtin_bit_cast(int, x);
  int y = __builtin_amdgcn_update_dpp(xi, xi, C, 0xF, 0xF, false);
  return x + __builtin_bit_cast(float, y);
}
DEV float rowmax16(float x) {  // max over the 16 lanes of a DPP row
  x = dpp_fmax<0x121>(x);
  x = dpp_fmax<0x122>(x);
  x = dpp_fmax<0x124>(x);
  x = dpp_fmax<0x128>(x);
  return x;
}
DEV float rowsum16(float x) {
  x = dpp_fadd<0x121>(x);
  x = dpp_fadd<0x122>(x);
  x = dpp_fadd<0x124>(x);
  x = dpp_fadd<0x128>(x);
  return x;
}

// ---------------- 1. fp32 -> bf16 convert (vectorized, grid-stride) ----------
__global__ void convert_f32_bf16(const float* __restrict__ in, u16* __restrict__ out,
                                 long long n) {
  long long i = (long long)blockIdx.x * blockDim.x + threadIdx.x;
  long long stride = (long long)gridDim.x * blockDim.x;
  for (long long j = i * 4; j < n; j += stride * 4) {
    f32x4v v = *(const f32x4v*)(in + j);
    u16x4 o;
    o.x = f2bf(v.x); o.y = f2bf(v.y); o.z = f2bf(v.z); o.w = f2bf(v.w);
    *(u16x4*)(out + j) = o;
  }
}

// ---------------- 2. weight transpose: W[K][N] f32 -> Wt[N][K] bf16 ----------
__global__ void transpose_w(const float* __restrict__ W, u16* __restrict__ Wt,
                            int K, int N) {
  __shared__ float t[32][33];
  int n0 = blockIdx.x * 32, k0 = blockIdx.y * 32;
  for (int i = threadIdx.y; i < 32; i += 8)
    t[i][threadIdx.x] = W[(long long)(k0 + i) * N + n0 + threadIdx.x];
  __syncthreads();
  for (int i = threadIdx.y; i < 32; i += 8)
    Wt[(long long)(n0 + i) * K + k0 + threadIdx.x] = f2bf(t[threadIdx.x][i]);
}

// ---------------- 3. GEMM: C[M][N] = A[M][K] * Bt[N][K]^T + bias -------------
// 128x128 tile, BK=64, 4 waves (each 64x64), 16x16x32 bf16 MFMA (m97 structure).
__global__ __launch_bounds__(256) void gemm_kernel(
    const u16* __restrict__ A, const u16* __restrict__ Bt,
    const float* __restrict__ bias, void* __restrict__ Cout,
    int Ndim, int Kdim, int bf16out) {
  __shared__ __align__(16) u16 As[128 * 64];
  __shared__ __align__(16) u16 Bs[128 * 64];

  const int tid = threadIdx.x;
  const int lane = tid & 63, wid = tid >> 6;
  const int l15 = lane & 15, lg = lane >> 4;
  const int rb = blockIdx.y * 128, cb = blockIdx.x * 128;
  const int wr = (wid >> 1) * 64, wc = (wid & 1) * 64;

  f32x4v acc[4][4] = {};

  const int scol = (tid & 7) * 8;     // k-offset within tile this thread fetches
  const int srow = tid >> 3;          // base row (0..31), +32 per issue

  for (int kt = 0; kt < Kdim; kt += 64) {
#pragma unroll
    for (int i = 0; i < 4; ++i) {
      int row = i * 32 + srow;
      async16(A + (long long)(rb + row) * Kdim + kt + scol, (char*)As + i * 4096 + tid * 16);
      async16(Bt + (long long)(cb + row) * Kdim + kt + scol, (char*)Bs + i * 4096 + tid * 16);
    }
    __syncthreads();
#pragma unroll
    for (int kk = 0; kk < 2; ++kk) {
      u16x8 a[4], b[4];
#pragma unroll
      for (int mi = 0; mi < 4; ++mi)
        a[mi] = *(const u16x8*)&As[(wr + mi * 16 + l15) * 64 + kk * 32 + lg * 8];
#pragma unroll
      for (int ni = 0; ni < 4; ++ni)
        b[ni] = *(const u16x8*)&Bs[(wc + ni * 16 + l15) * 64 + kk * 32 + lg * 8];
#pragma unroll
      for (int mi = 0; mi < 4; ++mi)
#pragma unroll
        for (int ni = 0; ni < 4; ++ni)
          acc[mi][ni] = mfma16(a[mi], b[ni], acc[mi][ni]);
    }
    __syncthreads();
  }

#pragma unroll
  for (int mi = 0; mi < 4; ++mi)
#pragma unroll
    for (int ni = 0; ni < 4; ++ni) {
      int col = cb + wc + ni * 16 + l15;
      float bv = bias[col];
#pragma unroll
      for (int r = 0; r < 4; ++r) {
        int row = rb + wr + mi * 16 + lg * 4 + r;
        float v = acc[mi][ni][r] + bv;
        if (bf16out) ((u16*)Cout)[(long long)row * Ndim + col] = f2bf(v);
        else         ((float*)Cout)[(long long)row * Ndim + col] = v;
      }
    }
}

// ---------------- 4. pack Q,K: qkv[8192][3072] -> per-head [BH][S][64] -------
// Q scaled by 1/8 (exact in bf16).
__global__ void pack_qk(const u16* __restrict__ qkv, u16* __restrict__ Qw,
                        u16* __restrict__ Kw) {
  int sglob = blockIdx.x;
  int c = threadIdx.x * 8;  // 0..2047 (Q and K halves)
  u16x8 v = *(const u16x8*)(qkv + (long long)sglob * N3D + c);
  int part = c >> 10;
  int h = (c & 1023) >> 6;
  int d = c & 63;
  int b = sglob >> 11;
  int s = sglob & 2047;
  long long dst = ((long long)(b * HH + h) * SS + s) * HD + d;
  if (part == 0) {
#pragma unroll
    for (int j = 0; j < 8; ++j) v[j] = f2bf(bf2f(v[j]) * 0.125f);
    *(u16x8*)(Qw + dst) = v;
  } else {
    *(u16x8*)(Kw + dst) = v;
  }
}

// ---------------- 5. V transpose: qkv V part -> Vt[BH][64][S] ----------------
__global__ void transpose_v(const u16* __restrict__ qkv, u16* __restrict__ Vt) {
  __shared__ u16 t[32][33];
  int s0 = blockIdx.x * 32, d0 = blockIdx.y * 32, bh = blockIdx.z;
  int b = bh >> 4, h = bh & 15;
  for (int i = threadIdx.y; i < 32; i += 8)
    t[i][threadIdx.x] =
        qkv[(long long)(b * SS + s0 + i) * N3D + 2 * DD + h * HD + d0 + threadIdx.x];
  __syncthreads();
  for (int i = threadIdx.y; i < 32; i += 8)
    Vt[((long long)bh * HD + d0 + i) * SS + s0 + threadIdx.x] = t[threadIdx.x][i];
}

// ---------------- 6. flash attention, causal -------------------------------
// block = 512 thr (8 waves), q-tile = 128 rows (16/wave), kv-tile = 64.
// K/V double-buffered in LDS via global_load_lds with pre-swizzled source;
// P per-wave 2KB swizzled LDS. LDS total 48KB -> 3 blocks/CU = 24 waves/CU
// (6/SIMD), 2x round-3 latency hiding; K/V staging amortized over 8 waves.
// Heavy q-tiles first + bijective XCD swizzle (nwg=1024 % 8 == 0).
__global__ __launch_bounds__(512) void attn_kernel(
    const u16* __restrict__ Qw, const u16* __restrict__ Kw,
    const u16* __restrict__ Vt, u16* __restrict__ ctx) {
  __shared__ __align__(16) u16 Ks[2][64 * 64];
  __shared__ __align__(16) u16 Vs[2][64 * 64];
  __shared__ __align__(16) u16 Ps[8][16 * 64];

  const int tid = threadIdx.x, lane = tid & 63, wid = tid >> 6;   // wid 0..7
  const int l15 = lane & 15, lg = lane >> 4;

  // XCD-aware swizzle: orig -> (orig%8)*128 + orig/8  (1024 blocks, bijective)
  const int orig = (int)(blockIdx.y * gridDim.x + blockIdx.x);
  const int wgid = (orig & 7) * 128 + (orig >> 3);
  const int qt = 15 - (wgid & 15);       // heavy-first within each head
  const int bh = wgid >> 4;
  const int q0 = qt * 128;
  const int qw = q0 + wid * 16;          // 16 q-rows per wave
  const int b = bh >> 4, h = bh & 15;

  const u16* Qbh = Qw + (long long)bh * SS * HD;
  const u16* Kbh = Kw + (long long)bh * SS * HD;
  const u16* Vbh = Vt + (long long)bh * HD * SS;
  char* Pw = (char*)&Ps[wid][0];

  // Q fragments (pre-scaled by 1/8); A-frag: row = l15, k = kk*32+lg*8+j
  u16x8 qf[2];
#pragma unroll
  for (int kk = 0; kk < 2; ++kk)
    qf[kk] = *(const u16x8*)(Qbh + (long long)(qw + l15) * HD + kk * 32 + lg * 8);

  f32x4v acc[4] = {};
  float m_s[4], l_s[4];
#pragma unroll
  for (int r = 0; r < 4; ++r) { m_s[r] = -1e30f; l_s[r] = 0.f; }

  // stage tile (64 rows x 128B) of K and V into buffer bi; src pre-swizzled.
  // 512 threads: one 16B async each for K and V covers 8KB+8KB.
  const int rlo = tid >> 3;            // 0..63
  const int cbS = (tid & 7) * 16;      // byte col 0..112
  const int swS = cbS ^ ((rlo & 7) << 4);
  auto stage = [&](int bi, int kbase) {
    async16((const char*)(Kbh + (long long)(kbase + rlo) * HD) + swS,
            (char*)&Ks[bi][0] + rlo * 128 + cbS);
    async16((const char*)(Vbh + (long long)rlo * SS + kbase) + swS,
            (char*)&Vs[bi][0] + rlo * 128 + cbS);
  };

  const int nkb = 2 * qt + 2;   // tiles with kbase <= q0+127
  stage(0, 0);
  __syncthreads();              // drains vmcnt before first compute

  int cur = 0;
  for (int kb = 0; kb < nkb; ++kb) {
    const int kbase = kb * 64;
    if (kb + 1 < nkb) stage(cur ^ 1, (kb + 1) * 64);   // prefetch next tile

    if (kbase <= qw + 15) {     // skip fully-masked tiles for this wave
      const char* Kb = (const char*)&Ks[cur][0];
      const char* Vb = (const char*)&Vs[cur][0];

      // ---- S = Q K^T ----
      f32x4v s[4] = {};
#pragma unroll
      for (int kk = 0; kk < 2; ++kk) {
        u16x8 bfr[4];
#pragma unroll
        for (int ni = 0; ni < 4; ++ni)
          bfr[ni] = *(const u16x8*)(Kb + (ni * 16 + l15) * 128 +
                                    ((kk * 64 + lg * 16) ^ ((l15 & 7) << 4)));
        __builtin_amdgcn_s_setprio(1);
#pragma unroll
        for (int ni = 0; ni < 4; ++ni)
          s[ni] = mfma16(qf[kk], bfr[ni], s[ni]);
        __builtin_amdgcn_s_setprio(0);
      }

      // ---- causal mask (diagonal-overlap tiles only) ----
      if (kbase + 63 > qw) {
#pragma unroll
        for (int ni = 0; ni < 4; ++ni) {
          int kcol = kbase + ni * 16 + l15;
#pragma unroll
          for (int r = 0; r < 4; ++r) {
            int qrow = qw + lg * 4 + r;
            if (kcol > qrow) s[ni][r] = -1e30f;
          }
        }
      }

      // ---- online softmax (DPP row reductions, log2 domain) ----
#pragma unroll
      for (int r = 0; r < 4; ++r) {
        float smax = fmaxf(fmaxf(s[0][r], s[1][r]), fmaxf(s[2][r], s[3][r]));
        smax = rowmax16(smax);
        float newm = fmaxf(m_s[r], smax);
        float scale = __builtin_exp2f((m_s[r] - newm) * L2E);
        float mL2 = newm * L2E;
        m_s[r] = newm;
        float rsum = 0.f;
#pragma unroll
        for (int ni = 0; ni < 4; ++ni) {
          float p = __builtin_exp2f(__builtin_fmaf(s[ni][r], L2E, -mL2));
          s[ni][r] = p;
          rsum += p;
        }
        rsum = rowsum16(rsum);
        l_s[r] = l_s[r] * scale + rsum;
#pragma unroll
        for (int di = 0; di < 4; ++di) acc[di][r] *= scale;
      }

      // ---- P -> LDS (bf16, swizzled); same-wave RAW, no barrier ----
#pragma unroll
      for (int ni = 0; ni < 4; ++ni)
#pragma unroll
        for (int r = 0; r < 4; ++r) {
          int row = lg * 4 + r;
          int cb2 = (ni * 16 + l15) * 2;
          *(u16*)(Pw + row * 128 + (cb2 ^ ((row & 7) << 4))) = f2bf(s[ni][r]);
        }

      // ---- O += P V ----
#pragma unroll
      for (int ks = 0; ks < 2; ++ks) {
        u16x8 pa = *(const u16x8*)(Pw + l15 * 128 +
                                   ((ks * 64 + lg * 16) ^ ((l15 & 7) << 4)));
        u16x8 vb[4];
#pragma unroll
        for (int di = 0; di < 4; ++di)
          vb[di] = *(const u16x8*)(Vb + (di * 16 + l15) * 128 +
                                   ((ks * 64 + lg * 16) ^ ((l15 & 7) << 4)));
        __builtin_amdgcn_s_setprio(1);
#pragma unroll
        for (int di = 0; di < 4; ++di)
          acc[di] = mfma16(pa, vb[di], acc[di]);
        __builtin_amdgcn_s_setprio(0);
      }
    }

    __syncthreads();   // drains staged loads (vmcnt) + protects dbuf swap
    cur ^= 1;
  }

  // finalize: ctx[b, q, h*64+d]
#pragma unroll
  for (int r = 0; r < 4; ++r) {
    float inv = 1.f / l_s[r];
    int qrow = qw + lg * 4 + r;
#pragma unroll
    for (int di = 0; di < 4; ++di) {
      int d = di * 16 + l15;
      ctx[((long long)(b * SS + qrow)) * DD + h * HD + d] = f2bf(acc[di][r] * inv);
    }
  }
}

// ---------------- launch -----------------------------------------------------
extern "C" void kernel_launch(void* const* d_in, const int* in_sizes, int n_in,
                              void* d_out, int out_size, void* d_ws, size_t ws_size,
                              hipStream_t stream) {
  const float* inp    = (const float*)d_in[0];
  const float* w_attn = (const float*)d_in[1];
  const float* b_attn = (const float*)d_in[2];
  const float* w_proj = (const float*)d_in[3];
  const float* b_proj = (const float*)d_in[4];
  float* out = (float*)d_out;
  char* ws = (char*)d_ws;

  // workspace layout (bytes)
  const long long off_A   = 0;                       // inp bf16 [8192][1024]  16MB (reused as Qw)
  const long long off_WAt = 16777216;                // w_attn^T bf16 [3072][1024]  6MB
  const long long off_WPt = 23068672;                // w_proj^T bf16 [1024][1024]  2MB
  const long long off_qkv = 25165824;                // qkv bf16 [8192][3072]  48MB (reused as ctx)
  const long long off_K   = 75497472;                // K  [64][2048][64] 16MB
  const long long off_Vt  = 92274688;                // Vt [64][64][2048] 16MB
  const long long need    = 109051904;
  if (ws_size < (size_t)need) return;

  u16* Abf = (u16*)(ws + off_A);
  u16* WAt = (u16*)(ws + off_WAt);
  u16* WPt = (u16*)(ws + off_WPt);
  u16* qkv = (u16*)(ws + off_qkv);
  u16* Qw  = Abf;        // reuse: Abf dead after QKV gemm
  u16* Kw  = (u16*)(ws + off_K);
  u16* Vt  = (u16*)(ws + off_Vt);
  u16* ctx = qkv;        // reuse: qkv dead after pack/transpose

  // 1. inp -> bf16
  convert_f32_bf16<<<2048, 256, 0, stream>>>(inp, Abf, (long long)MM * DD);
  // 2. weight transposes
  transpose_w<<<dim3(N3D / 32, DD / 32), dim3(32, 8), 0, stream>>>(w_attn, WAt, DD, N3D);
  transpose_w<<<dim3(DD / 32, DD / 32), dim3(32, 8), 0, stream>>>(w_proj, WPt, DD, DD);
  // 3. QKV gemm: [8192][3072] bf16
  gemm_kernel<<<dim3(N3D / 128, MM / 128), 256, 0, stream>>>(Abf, WAt, b_attn, qkv, N3D, DD, 1);
  // 4. pack Q (scaled), K
  pack_qk<<<MM, 256, 0, stream>>>(qkv, Qw, Kw);
  // 5. transpose V
  transpose_v<<<dim3(SS / 32, HD / 32, BB * HH), dim3(32, 8), 0, stream>>>(qkv, Vt);
  // 6. attention -> ctx bf16 [8192][1024]  (128-row q-tiles, 8 waves, heavy-first)
  attn_kernel<<<dim3(SS / 128, BB * HH), 512, 0, stream>>>(Qw, Kw, Vt, ctx);
  // 7. output projection -> fp32 d_out
  gemm_kernel<<<dim3(DD / 128, MM / 128), 256, 0, stream>>>(ctx, WPt, b_proj, out, DD, DD, 0);
}

// Round 5
// 243.631 us; speedup vs baseline: 2.4546x; 1.1836x over previous
//
#include <hip/hip_runtime.h>

// CausalSelfAttention on MI355X: bf16 MFMA pipeline.
// B=4, S=2048, D=1024, H=16, hd=64. fp32 in/out, bf16 internal compute.

#define DEV __device__ __forceinline__

typedef unsigned short u16;
typedef u16   u16x8 __attribute__((ext_vector_type(8)));
typedef u16   u16x4 __attribute__((ext_vector_type(4)));
typedef float f32x4v __attribute__((ext_vector_type(4)));
typedef __bf16 bf16x8 __attribute__((ext_vector_type(8)));

#define BB 4
#define SS 2048
#define DD 1024
#define HH 16
#define HD 64
#define MM (BB*SS)          // 8192
#define N3D (3*DD)          // 3072
#define L2E 1.44269504088896340736f

DEV u16 f2bf(float f) { return __builtin_bit_cast(u16, (__bf16)f); }  // RNE
DEV float bf2f(u16 h) { return __builtin_bit_cast(float, (unsigned)h << 16); }

DEV f32x4v mfma16(u16x8 a, u16x8 b, f32x4v c) {
  return __builtin_amdgcn_mfma_f32_16x16x32_bf16(
      __builtin_bit_cast(bf16x8, a), __builtin_bit_cast(bf16x8, b), c, 0, 0, 0);
}

// async global->LDS, 16B per lane. LDS dest must be linear in lane order.
DEV void async16(const void* g, void* l) {
  __builtin_amdgcn_global_load_lds(
      (const __attribute__((address_space(1))) void*)g,
      (__attribute__((address_space(3))) void*)l, 16, 0, 0);
}

// DPP rotate-reduce within 16-lane rows (VALU pipe, no LDS traffic).
template <int C> DEV float dpp_fmax(float x) {
  int xi = __builtin_bit_cast(int, x);
  int y = __builtin_amdgcn_update_dpp(xi, xi, C, 0xF, 0xF, false);
  return fmaxf(x, __builtin_bit_cast(float, y));
}
template <int C> DEV float dpp_fadd(float x) {
  int xi = __builtin_bit_cast(int, x);
  int y = __builtin_amdgcn_update_dpp(xi, xi, C, 0xF, 0xF, false);
  return x + __builtin_bit_cast(float, y);
}
DEV float rowmax16(float x) {  // max over the 16 lanes of a DPP row
  x = dpp_fmax<0x121>(x);
  x = dpp_fmax<0x122>(x);
  x = dpp_fmax<0x124>(x);
  x = dpp_fmax<0x128>(x);
  return x;
}
DEV float rowsum16(float x) {
  x = dpp_fadd<0x121>(x);
  x = dpp_fadd<0x122>(x);
  x = dpp_fadd<0x124>(x);
  x = dpp_fadd<0x128>(x);
  return x;
}

// ---------------- 1. fp32 -> bf16 convert (vectorized, grid-stride) ----------
__global__ void convert_f32_bf16(const float* __restrict__ in, u16* __restrict__ out,
                                 long long n) {
  long long i = (long long)blockIdx.x * blockDim.x + threadIdx.x;
  long long stride = (long long)gridDim.x * blockDim.x;
  for (long long j = i * 4; j < n; j += stride * 4) {
    f32x4v v = *(const f32x4v*)(in + j);
    u16x4 o;
    o.x = f2bf(v.x); o.y = f2bf(v.y); o.z = f2bf(v.z); o.w = f2bf(v.w);
    *(u16x4*)(out + j) = o;
  }
}

// ---------------- 2. weight transpose: W[K][N] f32 -> Wt[N][K] bf16 ----------
__global__ void transpose_w(const float* __restrict__ W, u16* __restrict__ Wt,
                            int K, int N) {
  __shared__ float t[32][33];
  int n0 = blockIdx.x * 32, k0 = blockIdx.y * 32;
  for (int i = threadIdx.y; i < 32; i += 8)
    t[i][threadIdx.x] = W[(long long)(k0 + i) * N + n0 + threadIdx.x];
  __syncthreads();
  for (int i = threadIdx.y; i < 32; i += 8)
    Wt[(long long)(n0 + i) * K + k0 + threadIdx.x] = f2bf(t[threadIdx.x][i]);
}

// ---------------- 3. GEMM: C[M][N] = A[M][K] * Bt[N][K]^T + bias -------------
// 128x128 tile, BK=64, 4 waves (each 64x64), 16x16x32 bf16 MFMA (m97 structure).
__global__ __launch_bounds__(256) void gemm_kernel(
    const u16* __restrict__ A, const u16* __restrict__ Bt,
    const float* __restrict__ bias, void* __restrict__ Cout,
    int Ndim, int Kdim, int bf16out) {
  __shared__ __align__(16) u16 As[128 * 64];
  __shared__ __align__(16) u16 Bs[128 * 64];

  const int tid = threadIdx.x;
  const int lane = tid & 63, wid = tid >> 6;
  const int l15 = lane & 15, lg = lane >> 4;
  const int rb = blockIdx.y * 128, cb = blockIdx.x * 128;
  const int wr = (wid >> 1) * 64, wc = (wid & 1) * 64;

  f32x4v acc[4][4] = {};

  const int scol = (tid & 7) * 8;     // k-offset within tile this thread fetches
  const int srow = tid >> 3;          // base row (0..31), +32 per issue

  for (int kt = 0; kt < Kdim; kt += 64) {
#pragma unroll
    for (int i = 0; i < 4; ++i) {
      int row = i * 32 + srow;
      async16(A + (long long)(rb + row) * Kdim + kt + scol, (char*)As + i * 4096 + tid * 16);
      async16(Bt + (long long)(cb + row) * Kdim + kt + scol, (char*)Bs + i * 4096 + tid * 16);
    }
    __syncthreads();
#pragma unroll
    for (int kk = 0; kk < 2; ++kk) {
      u16x8 a[4], b[4];
#pragma unroll
      for (int mi = 0; mi < 4; ++mi)
        a[mi] = *(const u16x8*)&As[(wr + mi * 16 + l15) * 64 + kk * 32 + lg * 8];
#pragma unroll
      for (int ni = 0; ni < 4; ++ni)
        b[ni] = *(const u16x8*)&Bs[(wc + ni * 16 + l15) * 64 + kk * 32 + lg * 8];
#pragma unroll
      for (int mi = 0; mi < 4; ++mi)
#pragma unroll
        for (int ni = 0; ni < 4; ++ni)
          acc[mi][ni] = mfma16(a[mi], b[ni], acc[mi][ni]);
    }
    __syncthreads();
  }

#pragma unroll
  for (int mi = 0; mi < 4; ++mi)
#pragma unroll
    for (int ni = 0; ni < 4; ++ni) {
      int col = cb + wc + ni * 16 + l15;
      float bv = bias[col];
#pragma unroll
      for (int r = 0; r < 4; ++r) {
        int row = rb + wr + mi * 16 + lg * 4 + r;
        float v = acc[mi][ni][r] + bv;
        if (bf16out) ((u16*)Cout)[(long long)row * Ndim + col] = f2bf(v);
        else         ((float*)Cout)[(long long)row * Ndim + col] = v;
      }
    }
}

// ---------------- 4. pack Q,K: qkv[8192][3072] -> per-head [BH][S][64] -------
// Q scaled by 1/8 (exact in bf16).
__global__ void pack_qk(const u16* __restrict__ qkv, u16* __restrict__ Qw,
                        u16* __restrict__ Kw) {
  int sglob = blockIdx.x;
  int c = threadIdx.x * 8;  // 0..2047 (Q and K halves)
  u16x8 v = *(const u16x8*)(qkv + (long long)sglob * N3D + c);
  int part = c >> 10;
  int h = (c & 1023) >> 6;
  int d = c & 63;
  int b = sglob >> 11;
  int s = sglob & 2047;
  long long dst = ((long long)(b * HH + h) * SS + s) * HD + d;
  if (part == 0) {
#pragma unroll
    for (int j = 0; j < 8; ++j) v[j] = f2bf(bf2f(v[j]) * 0.125f);
    *(u16x8*)(Qw + dst) = v;
  } else {
    *(u16x8*)(Kw + dst) = v;
  }
}

// ---------------- 5. V transpose: qkv V part -> Vt[BH][64][S] ----------------
__global__ void transpose_v(const u16* __restrict__ qkv, u16* __restrict__ Vt) {
  __shared__ u16 t[32][33];
  int s0 = blockIdx.x * 32, d0 = blockIdx.y * 32, bh = blockIdx.z;
  int b = bh >> 4, h = bh & 15;
  for (int i = threadIdx.y; i < 32; i += 8)
    t[i][threadIdx.x] =
        qkv[(long long)(b * SS + s0 + i) * N3D + 2 * DD + h * HD + d0 + threadIdx.x];
  __syncthreads();
  for (int i = threadIdx.y; i < 32; i += 8)
    Vt[((long long)bh * HD + d0 + i) * SS + s0 + threadIdx.x] = t[threadIdx.x][i];
}

// ---------------- 6. flash attention, causal -------------------------------
// block = 512 thr (8 waves), fold-paired q-tiles: each block does q-tile
// (15-pair) then (pair) -> uniform 34 k-tile iters per block, no tail.
// Grid 512 (2/CU), XCD-bijective swizzle. K/V double-buffered (static bases,
// k-loop unrolled x2 since nkb is always even). All LDS offsets precomputed
// in statically-indexed registers. Defer-max softmax (THR=8).
__global__ __launch_bounds__(512, 4) void attn_kernel(
    const u16* __restrict__ Qw, const u16* __restrict__ Kw,
    const u16* __restrict__ Vt, u16* __restrict__ ctx) {
  __shared__ __align__(16) u16 Ks[2][64 * 64];
  __shared__ __align__(16) u16 Vs[2][64 * 64];
  __shared__ __align__(16) u16 Ps[8][16 * 64];

  const int tid = threadIdx.x, lane = tid & 63, wid = tid >> 6;   // wid 0..7
  const int l15 = lane & 15, lg = lane >> 4;

  // XCD-bijective swizzle: 512 blocks, cpx = 64
  const int orig = (int)blockIdx.x;
  const int wgid = (orig & 7) * 64 + (orig >> 3);
  const int pair = wgid & 7;          // 0..7
  const int bh = wgid >> 3;           // 0..63
  const int b = bh >> 4, h = bh & 15;

  const u16* Qbh = Qw + (long long)bh * SS * HD;
  const u16* Kbh = Kw + (long long)bh * SS * HD;
  const u16* Vbh = Vt + (long long)bh * HD * SS;
  char* Pw = (char*)&Ps[wid][0];

  // ---- loop-invariant LDS byte offsets (statically indexed -> registers) ----
  const int xr = (l15 & 7) << 4;
  int rdoff[2][4];   // K/V fragment reads: [kk|ks][ni|di]
#pragma unroll
  for (int kk = 0; kk < 2; ++kk)
#pragma unroll
    for (int ni = 0; ni < 4; ++ni)
      rdoff[kk][ni] = (ni * 16 + l15) * 128 + ((kk * 64 + lg * 16) ^ xr);
  int proff[2];      // P reads
#pragma unroll
  for (int ks = 0; ks < 2; ++ks)
    proff[ks] = l15 * 128 + ((ks * 64 + lg * 16) ^ xr);
  int pwoff[4][4];   // P writes [r][ni]
#pragma unroll
  for (int r = 0; r < 4; ++r) {
    int row = lg * 4 + r;
#pragma unroll
    for (int ni = 0; ni < 4; ++ni)
      pwoff[r][ni] = row * 128 + (((ni * 16 + l15) * 2) ^ ((row & 7) << 4));
  }

  // staging: 512 threads cover 64 rows x 128B for K and V each (src pre-swizzled)
  const int rlo = tid >> 3;            // 0..63
  const int cbS = (tid & 7) * 16;      // byte col
  const int swS = cbS ^ ((rlo & 7) << 4);

#pragma unroll 1
  for (int half = 0; half < 2; ++half) {
    const int qt = half ? pair : 15 - pair;   // heavy tile first
    const int q0 = qt * 128;
    const int qw = q0 + wid * 16;             // 16 q-rows per wave
    const int nkb = 2 * qt + 2;               // always even

    // Q fragments (pre-scaled by 1/8)
    u16x8 qf[2];
#pragma unroll
    for (int kk = 0; kk < 2; ++kk)
      qf[kk] = *(const u16x8*)(Qbh + (long long)(qw + l15) * HD + kk * 32 + lg * 8);

    f32x4v acc[4] = {};
    float m_s[4], l_s[4];
#pragma unroll
    for (int r = 0; r < 4; ++r) { m_s[r] = -1e30f; l_s[r] = 0.f; }

    auto stage = [&](u16* Kdst, u16* Vdst, int kbase) {
      async16((const char*)(Kbh + (long long)(kbase + rlo) * HD) + swS,
              (char*)Kdst + rlo * 128 + cbS);
      async16((const char*)(Vbh + (long long)rlo * SS + kbase) + swS,
              (char*)Vdst + rlo * 128 + cbS);
    };

    auto compute = [&](const char* Kb, const char* Vb, int kbase) {
      if (kbase > qw + 15) return;   // fully masked for this wave

      // ---- S = Q K^T ----
      f32x4v s[4] = {};
#pragma unroll
      for (int kk = 0; kk < 2; ++kk) {
        u16x8 bfr[4];
#pragma unroll
        for (int ni = 0; ni < 4; ++ni)
          bfr[ni] = *(const u16x8*)(Kb + rdoff[kk][ni]);
        __builtin_amdgcn_s_setprio(1);
#pragma unroll
        for (int ni = 0; ni < 4; ++ni)
          s[ni] = mfma16(qf[kk], bfr[ni], s[ni]);
        __builtin_amdgcn_s_setprio(0);
      }

      // ---- causal mask (diagonal-overlap tiles only) ----
      if (kbase + 63 > qw) {
#pragma unroll
        for (int ni = 0; ni < 4; ++ni) {
          int kcol = kbase + ni * 16 + l15;
#pragma unroll
          for (int r = 0; r < 4; ++r) {
            int qrow = qw + lg * 4 + r;
            if (kcol > qrow) s[ni][r] = -1e30f;
          }
        }
      }

      // ---- online softmax with defer-max (THR=8) ----
      float rmax[4];
      bool need = false;
#pragma unroll
      for (int r = 0; r < 4; ++r) {
        float sm = fmaxf(fmaxf(s[0][r], s[1][r]), fmaxf(s[2][r], s[3][r]));
        rmax[r] = rowmax16(sm);
        need = need || (rmax[r] > m_s[r] + 8.f);
      }
      if (__any(need)) {
#pragma unroll
        for (int r = 0; r < 4; ++r) {
          float newm = fmaxf(m_s[r], rmax[r]);
          float sc = __builtin_exp2f((m_s[r] - newm) * L2E);
          m_s[r] = newm;
          l_s[r] *= sc;
#pragma unroll
          for (int di = 0; di < 4; ++di) acc[di][r] *= sc;
        }
      }
#pragma unroll
      for (int r = 0; r < 4; ++r) {
        float mL2 = m_s[r] * L2E;
        float rsum = 0.f;
#pragma unroll
        for (int ni = 0; ni < 4; ++ni) {
          float p = __builtin_exp2f(__builtin_fmaf(s[ni][r], L2E, -mL2));
          s[ni][r] = p;
          rsum += p;
        }
        l_s[r] += rowsum16(rsum);
      }

      // ---- P -> LDS (bf16, swizzled); same-wave RAW, no barrier ----
#pragma unroll
      for (int r = 0; r < 4; ++r)
#pragma unroll
        for (int ni = 0; ni < 4; ++ni)
          *(u16*)(Pw + pwoff[r][ni]) = f2bf(s[ni][r]);

      // ---- O += P V ----
#pragma unroll
      for (int ks = 0; ks < 2; ++ks) {
        u16x8 pa = *(const u16x8*)(Pw + proff[ks]);
        u16x8 vb[4];
#pragma unroll
        for (int di = 0; di < 4; ++di)
          vb[di] = *(const u16x8*)(Vb + rdoff[ks][di]);
        __builtin_amdgcn_s_setprio(1);
#pragma unroll
        for (int di = 0; di < 4; ++di)
          acc[di] = mfma16(pa, vb[di], acc[di]);
        __builtin_amdgcn_s_setprio(0);
      }
    };

    stage(&Ks[0][0], &Vs[0][0], 0);
    __syncthreads();              // drains vmcnt; buf0 ready

    for (int kb = 0; kb < nkb; kb += 2) {
      stage(&Ks[1][0], &Vs[1][0], (kb + 1) * 64);   // kb+1 < nkb (nkb even)
      compute((const char*)&Ks[0][0], (const char*)&Vs[0][0], kb * 64);
      __syncthreads();            // done reading buf0; buf1 staged
      if (kb + 2 < nkb) stage(&Ks[0][0], &Vs[0][0], (kb + 2) * 64);
      compute((const char*)&Ks[1][0], (const char*)&Vs[1][0], (kb + 1) * 64);
      __syncthreads();            // done reading buf1; buf0 staged
    }

    // finalize: ctx[b, q, h*64+d]
#pragma unroll
    for (int r = 0; r < 4; ++r) {
      float inv = 1.f / l_s[r];
      int qrow = qw + lg * 4 + r;
#pragma unroll
      for (int di = 0; di < 4; ++di) {
        int d = di * 16 + l15;
        ctx[((long long)(b * SS + qrow)) * DD + h * HD + d] = f2bf(acc[di][r] * inv);
      }
    }
  }
}

// ---------------- launch -----------------------------------------------------
extern "C" void kernel_launch(void* const* d_in, const int* in_sizes, int n_in,
                              void* d_out, int out_size, void* d_ws, size_t ws_size,
                              hipStream_t stream) {
  const float* inp    = (const float*)d_in[0];
  const float* w_attn = (const float*)d_in[1];
  const float* b_attn = (const float*)d_in[2];
  const float* w_proj = (const float*)d_in[3];
  const float* b_proj = (const float*)d_in[4];
  float* out = (float*)d_out;
  char* ws = (char*)d_ws;

  // workspace layout (bytes)
  const long long off_A   = 0;                       // inp bf16 [8192][1024]  16MB (reused as Qw)
  const long long off_WAt = 16777216;                // w_attn^T bf16 [3072][1024]  6MB
  const long long off_WPt = 23068672;                // w_proj^T bf16 [1024][1024]  2MB
  const long long off_qkv = 25165824;                // qkv bf16 [8192][3072]  48MB (reused as ctx)
  const long long off_K   = 75497472;                // K  [64][2048][64] 16MB
  const long long off_Vt  = 92274688;                // Vt [64][64][2048] 16MB
  const long long need    = 109051904;
  if (ws_size < (size_t)need) return;

  u16* Abf = (u16*)(ws + off_A);
  u16* WAt = (u16*)(ws + off_WAt);
  u16* WPt = (u16*)(ws + off_WPt);
  u16* qkv = (u16*)(ws + off_qkv);
  u16* Qw  = Abf;        // reuse: Abf dead after QKV gemm
  u16* Kw  = (u16*)(ws + off_K);
  u16* Vt  = (u16*)(ws + off_Vt);
  u16* ctx = qkv;        // reuse: qkv dead after pack/transpose

  // 1. inp -> bf16
  convert_f32_bf16<<<2048, 256, 0, stream>>>(inp, Abf, (long long)MM * DD);
  // 2. weight transposes
  transpose_w<<<dim3(N3D / 32, DD / 32), dim3(32, 8), 0, stream>>>(w_attn, WAt, DD, N3D);
  transpose_w<<<dim3(DD / 32, DD / 32), dim3(32, 8), 0, stream>>>(w_proj, WPt, DD, DD);
  // 3. QKV gemm: [8192][3072] bf16
  gemm_kernel<<<dim3(N3D / 128, MM / 128), 256, 0, stream>>>(Abf, WAt, b_attn, qkv, N3D, DD, 1);
  // 4. pack Q (scaled), K
  pack_qk<<<MM, 256, 0, stream>>>(qkv, Qw, Kw);
  // 5. transpose V
  transpose_v<<<dim3(SS / 32, HD / 32, BB * HH), dim3(32, 8), 0, stream>>>(qkv, Vt);
  // 6. attention -> ctx bf16 [8192][1024]  (fold-paired uniform blocks)
  attn_kernel<<<512, 512, 0, stream>>>(Qw, Kw, Vt, ctx);
  // 7. output projection -> fp32 d_out
  gemm_kernel<<<dim3(DD / 128, MM / 128), 256, 0, stream>>>(ctx, WPt, b_proj, out, DD, DD, 0);
}

// Round 6
// 239.950 us; speedup vs baseline: 2.4923x; 1.0153x over previous
//
#include <hip/hip_runtime.h>

// CausalSelfAttention on MI355X: bf16 MFMA pipeline.
// B=4, S=2048, D=1024, H=16, hd=64. fp32 in/out, bf16 internal compute.

#define DEV __device__ __forceinline__

typedef unsigned short u16;
typedef u16   u16x8 __attribute__((ext_vector_type(8)));
typedef u16   u16x4 __attribute__((ext_vector_type(4)));
typedef float f32x4v __attribute__((ext_vector_type(4)));
typedef __bf16 bf16x8 __attribute__((ext_vector_type(8)));

#define BB 4
#define SS 2048
#define DD 1024
#define HH 16
#define HD 64
#define MM (BB*SS)          // 8192
#define N3D (3*DD)          // 3072
#define L2E 1.44269504088896340736f
#define C8  0.18033688011112042f   // log2(e)/8  (folds the 1/sqrt(64) scale)

DEV u16 f2bf(float f) { return __builtin_bit_cast(u16, (__bf16)f); }  // RNE
DEV float bf2f(u16 h) { return __builtin_bit_cast(float, (unsigned)h << 16); }

DEV f32x4v mfma16(u16x8 a, u16x8 b, f32x4v c) {
  return __builtin_amdgcn_mfma_f32_16x16x32_bf16(
      __builtin_bit_cast(bf16x8, a), __builtin_bit_cast(bf16x8, b), c, 0, 0, 0);
}

// async global->LDS, 16B per lane. LDS dest must be linear in lane order.
DEV void async16(const void* g, void* l) {
  __builtin_amdgcn_global_load_lds(
      (const __attribute__((address_space(1))) void*)g,
      (__attribute__((address_space(3))) void*)l, 16, 0, 0);
}

// DPP rotate-reduce within 16-lane rows (VALU pipe, no LDS traffic).
template <int C> DEV float dpp_fmax(float x) {
  int xi = __builtin_bit_cast(int, x);
  int y = __builtin_amdgcn_update_dpp(xi, xi, C, 0xF, 0xF, false);
  return fmaxf(x, __builtin_bit_cast(float, y));
}
template <int C> DEV float dpp_fadd(float x) {
  int xi = __builtin_bit_cast(int, x);
  int y = __builtin_amdgcn_update_dpp(xi, xi, C, 0xF, 0xF, false);
  return x + __builtin_bit_cast(float, y);
}
DEV float rowmax16(float x) {  // max over the 16 lanes of a DPP row
  x = dpp_fmax<0x121>(x);
  x = dpp_fmax<0x122>(x);
  x = dpp_fmax<0x124>(x);
  x = dpp_fmax<0x128>(x);
  return x;
}
DEV float rowsum16(float x) {
  x = dpp_fadd<0x121>(x);
  x = dpp_fadd<0x122>(x);
  x = dpp_fadd<0x124>(x);
  x = dpp_fadd<0x128>(x);
  return x;
}

// ---------------- 1. fp32 -> bf16 convert (vectorized, grid-stride) ----------
__global__ void convert_f32_bf16(const float* __restrict__ in, u16* __restrict__ out,
                                 long long n) {
  long long i = (long long)blockIdx.x * blockDim.x + threadIdx.x;
  long long stride = (long long)gridDim.x * blockDim.x;
  for (long long j = i * 4; j < n; j += stride * 4) {
    f32x4v v = *(const f32x4v*)(in + j);
    u16x4 o;
    o.x = f2bf(v.x); o.y = f2bf(v.y); o.z = f2bf(v.z); o.w = f2bf(v.w);
    *(u16x4*)(out + j) = o;
  }
}

// ---------------- 2. weight transpose: W[K][N] f32 -> Wt[N][K] bf16 ----------
__global__ void transpose_w(const float* __restrict__ W, u16* __restrict__ Wt,
                            int K, int N) {
  __shared__ float t[32][33];
  int n0 = blockIdx.x * 32, k0 = blockIdx.y * 32;
  for (int i = threadIdx.y; i < 32; i += 8)
    t[i][threadIdx.x] = W[(long long)(k0 + i) * N + n0 + threadIdx.x];
  __syncthreads();
  for (int i = threadIdx.y; i < 32; i += 8)
    Wt[(long long)(n0 + i) * K + k0 + threadIdx.x] = f2bf(t[threadIdx.x][i]);
}

// ---------------- 3. GEMM: C[M][N] = A[M][K] * Bt[N][K]^T + bias -------------
// 128x128 tile, BK=64, 4 waves (each 64x64), 16x16x32 bf16 MFMA (m97 structure).
__global__ __launch_bounds__(256) void gemm_kernel(
    const u16* __restrict__ A, const u16* __restrict__ Bt,
    const float* __restrict__ bias, void* __restrict__ Cout,
    int Ndim, int Kdim, int bf16out) {
  __shared__ __align__(16) u16 As[128 * 64];
  __shared__ __align__(16) u16 Bs[128 * 64];

  const int tid = threadIdx.x;
  const int lane = tid & 63, wid = tid >> 6;
  const int l15 = lane & 15, lg = lane >> 4;
  const int rb = blockIdx.y * 128, cb = blockIdx.x * 128;
  const int wr = (wid >> 1) * 64, wc = (wid & 1) * 64;

  f32x4v acc[4][4] = {};

  const int scol = (tid & 7) * 8;     // k-offset within tile this thread fetches
  const int srow = tid >> 3;          // base row (0..31), +32 per issue

  for (int kt = 0; kt < Kdim; kt += 64) {
#pragma unroll
    for (int i = 0; i < 4; ++i) {
      int row = i * 32 + srow;
      async16(A + (long long)(rb + row) * Kdim + kt + scol, (char*)As + i * 4096 + tid * 16);
      async16(Bt + (long long)(cb + row) * Kdim + kt + scol, (char*)Bs + i * 4096 + tid * 16);
    }
    __syncthreads();
#pragma unroll
    for (int kk = 0; kk < 2; ++kk) {
      u16x8 a[4], b[4];
#pragma unroll
      for (int mi = 0; mi < 4; ++mi)
        a[mi] = *(const u16x8*)&As[(wr + mi * 16 + l15) * 64 + kk * 32 + lg * 8];
#pragma unroll
      for (int ni = 0; ni < 4; ++ni)
        b[ni] = *(const u16x8*)&Bs[(wc + ni * 16 + l15) * 64 + kk * 32 + lg * 8];
#pragma unroll
      for (int mi = 0; mi < 4; ++mi)
#pragma unroll
        for (int ni = 0; ni < 4; ++ni)
          acc[mi][ni] = mfma16(a[mi], b[ni], acc[mi][ni]);
    }
    __syncthreads();
  }

#pragma unroll
  for (int mi = 0; mi < 4; ++mi)
#pragma unroll
    for (int ni = 0; ni < 4; ++ni) {
      int col = cb + wc + ni * 16 + l15;
      float bv = bias[col];
#pragma unroll
      for (int r = 0; r < 4; ++r) {
        int row = rb + wr + mi * 16 + lg * 4 + r;
        float v = acc[mi][ni][r] + bv;
        if (bf16out) ((u16*)Cout)[(long long)row * Ndim + col] = f2bf(v);
        else         ((float*)Cout)[(long long)row * Ndim + col] = v;
      }
    }
}

// ---------------- 4. V transpose: qkv V part -> Vt[BH][64][S] ----------------
__global__ void transpose_v(const u16* __restrict__ qkv, u16* __restrict__ Vt) {
  __shared__ u16 t[32][33];
  int s0 = blockIdx.x * 32, d0 = blockIdx.y * 32, bh = blockIdx.z;
  int b = bh >> 4, h = bh & 15;
  for (int i = threadIdx.y; i < 32; i += 8)
    t[i][threadIdx.x] =
        qkv[(long long)(b * SS + s0 + i) * N3D + 2 * DD + h * HD + d0 + threadIdx.x];
  __syncthreads();
  for (int i = threadIdx.y; i < 32; i += 8)
    Vt[((long long)bh * HD + d0 + i) * SS + s0 + threadIdx.x] = t[threadIdx.x][i];
}

// ---------------- 5. flash attention, causal -------------------------------
// block = 512 thr (8 waves), ONE 128-row q-tile per block (16 rows/wave),
// kv-tile = 64. Grid 1024 (3 blocks/CU by LDS), heavy-first LPT + XCD-
// bijective swizzle. Q/K read directly from qkv (scale folded into C8).
// K/V double-buffered LDS (pre-swizzled src); P per-wave swizzled LDS.
// Softmax: lane-local defer-max (THR=64 raw), per-lane partial l, single
// DPP reduce at finalize.
__global__ __launch_bounds__(512, 4) void attn_kernel(
    const u16* __restrict__ qkv, const u16* __restrict__ Vt,
    u16* __restrict__ ctx) {
  __shared__ __align__(16) u16 Ks[2][64 * 64];
  __shared__ __align__(16) u16 Vs[2][64 * 64];
  __shared__ __align__(16) u16 Ps[8][16 * 64];

  const int tid = threadIdx.x, lane = tid & 63, wid = tid >> 6;   // wid 0..7
  const int l15 = lane & 15, lg = lane >> 4;

  // XCD-bijective swizzle: 1024 blocks, 128 per XCD
  const int orig = (int)blockIdx.x;
  const int wgid = (orig & 7) * 128 + (orig >> 3);
  const int qt = 15 - (wgid & 15);    // heavy-first within each head
  const int bh = wgid >> 4;           // 0..63
  const int b = bh >> 4, h = bh & 15;

  const u16* Qcol = qkv + (long long)b * SS * N3D + h * HD;            // Q cols
  const u16* Kcol = qkv + (long long)b * SS * N3D + DD + h * HD;       // K cols
  const u16* Vbh  = Vt + (long long)bh * HD * SS;
  char* Pw = (char*)&Ps[wid][0];

  // ---- loop-invariant LDS byte offsets (statically indexed -> registers) ----
  const int xr = (l15 & 7) << 4;
  int rdoff[2][4];   // K/V fragment reads: [kk|ks][ni|di]
#pragma unroll
  for (int kk = 0; kk < 2; ++kk)
#pragma unroll
    for (int ni = 0; ni < 4; ++ni)
      rdoff[kk][ni] = (ni * 16 + l15) * 128 + ((kk * 64 + lg * 16) ^ xr);
  int proff[2];      // P reads
#pragma unroll
  for (int ks = 0; ks < 2; ++ks)
    proff[ks] = l15 * 128 + ((ks * 64 + lg * 16) ^ xr);
  int pwoff[4][4];   // P writes [r][ni]
#pragma unroll
  for (int r = 0; r < 4; ++r) {
    int row = lg * 4 + r;
#pragma unroll
    for (int ni = 0; ni < 4; ++ni)
      pwoff[r][ni] = row * 128 + (((ni * 16 + l15) * 2) ^ ((row & 7) << 4));
  }

  // staging: 512 threads cover 64 rows x 128B for K and V each (src pre-swizzled)
  const int rlo = tid >> 3;            // 0..63
  const int cbS = (tid & 7) * 16;      // byte col
  const int swS = cbS ^ ((rlo & 7) << 4);

  const int q0 = qt * 128;
  const int qw = q0 + wid * 16;        // 16 q-rows per wave
  const int nkb = 2 * qt + 2;          // always even

  // Q fragments (raw; 1/8 scale folded into C8)
  u16x8 qf[2];
#pragma unroll
  for (int kk = 0; kk < 2; ++kk)
    qf[kk] = *(const u16x8*)(Qcol + (long long)(qw + l15) * N3D + kk * 32 + lg * 8);

  f32x4v acc[4] = {};
  float m_s[4], l_p[4];
#pragma unroll
  for (int r = 0; r < 4; ++r) { m_s[r] = -1e30f; l_p[r] = 0.f; }

  auto stage = [&](u16* Kdst, u16* Vdst, int kbase) {
    async16((const char*)(Kcol + (long long)(kbase + rlo) * N3D) + swS,
            (char*)Kdst + rlo * 128 + cbS);
    async16((const char*)(Vbh + (long long)rlo * SS + kbase) + swS,
            (char*)Vdst + rlo * 128 + cbS);
  };

  auto compute = [&](const char* Kb, const char* Vb, int kbase) {
    if (kbase > qw + 15) return;   // fully masked for this wave

    // ---- S = Q K^T (raw scores) ----
    f32x4v s[4] = {};
#pragma unroll
    for (int kk = 0; kk < 2; ++kk) {
      u16x8 bfr[4];
#pragma unroll
      for (int ni = 0; ni < 4; ++ni)
        bfr[ni] = *(const u16x8*)(Kb + rdoff[kk][ni]);
      __builtin_amdgcn_s_setprio(1);
#pragma unroll
      for (int ni = 0; ni < 4; ++ni)
        s[ni] = mfma16(qf[kk], bfr[ni], s[ni]);
      __builtin_amdgcn_s_setprio(0);
    }

    // ---- causal mask (diagonal-overlap tiles only) ----
    if (kbase + 63 > qw) {
#pragma unroll
      for (int ni = 0; ni < 4; ++ni) {
        int kcol = kbase + ni * 16 + l15;
#pragma unroll
        for (int r = 0; r < 4; ++r) {
          int qrow = qw + lg * 4 + r;
          if (kcol > qrow) s[ni][r] = -1e30f;
        }
      }
    }

    // ---- softmax: lane-local defer-max (THR=64 raw => p <= e^8) ----
    float lmax[4];
    bool need = false;
#pragma unroll
    for (int r = 0; r < 4; ++r) {
      lmax[r] = fmaxf(fmaxf(s[0][r], s[1][r]), fmaxf(s[2][r], s[3][r]));
      need = need || (lmax[r] > m_s[r] + 64.f);
    }
    if (__any(need)) {           // rare: establish/raise the shared row max
#pragma unroll
      for (int r = 0; r < 4; ++r) {
        float rm = rowmax16(lmax[r]);
        float newm = fmaxf(m_s[r], rm);
        float sc = __builtin_exp2f((m_s[r] - newm) * C8);
        m_s[r] = newm;
        l_p[r] *= sc;
#pragma unroll
        for (int di = 0; di < 4; ++di) acc[di][r] *= sc;
      }
    }
#pragma unroll
    for (int r = 0; r < 4; ++r) {
      float mC = m_s[r] * C8;
      float rsum = 0.f;
#pragma unroll
      for (int ni = 0; ni < 4; ++ni) {
        float p = __builtin_exp2f(__builtin_fmaf(s[ni][r], C8, -mC));
        s[ni][r] = p;
        rsum += p;
      }
      l_p[r] += rsum;            // per-lane partial; reduced once at finalize
    }

    // ---- P -> LDS (bf16, swizzled); same-wave RAW, no barrier ----
#pragma unroll
    for (int r = 0; r < 4; ++r)
#pragma unroll
      for (int ni = 0; ni < 4; ++ni)
        *(u16*)(Pw + pwoff[r][ni]) = f2bf(s[ni][r]);

    // ---- O += P V ----
#pragma unroll
    for (int ks = 0; ks < 2; ++ks) {
      u16x8 pa = *(const u16x8*)(Pw + proff[ks]);
      u16x8 vb[4];
#pragma unroll
      for (int di = 0; di < 4; ++di)
        vb[di] = *(const u16x8*)(Vb + rdoff[ks][di]);
      __builtin_amdgcn_s_setprio(1);
#pragma unroll
      for (int di = 0; di < 4; ++di)
        acc[di] = mfma16(pa, vb[di], acc[di]);
      __builtin_amdgcn_s_setprio(0);
    }
  };

  stage(&Ks[0][0], &Vs[0][0], 0);
  __syncthreads();              // drains vmcnt; buf0 ready

  for (int kb = 0; kb < nkb; kb += 2) {
    stage(&Ks[1][0], &Vs[1][0], (kb + 1) * 64);   // kb+1 < nkb (nkb even)
    compute((const char*)&Ks[0][0], (const char*)&Vs[0][0], kb * 64);
    __syncthreads();            // done reading buf0; buf1 staged
    if (kb + 2 < nkb) stage(&Ks[0][0], &Vs[0][0], (kb + 2) * 64);
    compute((const char*)&Ks[1][0], (const char*)&Vs[1][0], (kb + 1) * 64);
    __syncthreads();            // done reading buf1; buf0 staged
  }

  // finalize: ctx[b, q, h*64+d]
#pragma unroll
  for (int r = 0; r < 4; ++r) {
    float inv = 1.f / rowsum16(l_p[r]);
    int qrow = qw + lg * 4 + r;
#pragma unroll
    for (int di = 0; di < 4; ++di) {
      int d = di * 16 + l15;
      ctx[((long long)(b * SS + qrow)) * DD + h * HD + d] = f2bf(acc[di][r] * inv);
    }
  }
}

// ---------------- launch -----------------------------------------------------
extern "C" void kernel_launch(void* const* d_in, const int* in_sizes, int n_in,
                              void* d_out, int out_size, void* d_ws, size_t ws_size,
                              hipStream_t stream) {
  const float* inp    = (const float*)d_in[0];
  const float* w_attn = (const float*)d_in[1];
  const float* b_attn = (const float*)d_in[2];
  const float* w_proj = (const float*)d_in[3];
  const float* b_proj = (const float*)d_in[4];
  float* out = (float*)d_out;
  char* ws = (char*)d_ws;

  // workspace layout (bytes)
  const long long off_A   = 0;                       // inp bf16 [8192][1024]  16MB
  const long long off_WAt = 16777216;                // w_attn^T bf16 [3072][1024]  6MB
  const long long off_WPt = 23068672;                // w_proj^T bf16 [1024][1024]  2MB
  const long long off_qkv = 25165824;                // qkv bf16 [8192][3072]  48MB (live through attn)
  const long long off_ctx = 75497472;                // ctx bf16 [8192][1024] 16MB
  const long long off_Vt  = 92274688;                // Vt [64][64][2048] 16MB
  const long long need    = 109051904;
  if (ws_size < (size_t)need) return;

  u16* Abf = (u16*)(ws + off_A);
  u16* WAt = (u16*)(ws + off_WAt);
  u16* WPt = (u16*)(ws + off_WPt);
  u16* qkv = (u16*)(ws + off_qkv);
  u16* ctx = (u16*)(ws + off_ctx);
  u16* Vt  = (u16*)(ws + off_Vt);

  // 1. inp -> bf16
  convert_f32_bf16<<<2048, 256, 0, stream>>>(inp, Abf, (long long)MM * DD);
  // 2. weight transposes
  transpose_w<<<dim3(N3D / 32, DD / 32), dim3(32, 8), 0, stream>>>(w_attn, WAt, DD, N3D);
  transpose_w<<<dim3(DD / 32, DD / 32), dim3(32, 8), 0, stream>>>(w_proj, WPt, DD, DD);
  // 3. QKV gemm: [8192][3072] bf16
  gemm_kernel<<<dim3(N3D / 128, MM / 128), 256, 0, stream>>>(Abf, WAt, b_attn, qkv, N3D, DD, 1);
  // 4. transpose V
  transpose_v<<<dim3(SS / 32, HD / 32, BB * HH), dim3(32, 8), 0, stream>>>(qkv, Vt);
  // 5. attention -> ctx bf16 [8192][1024]  (1024 single-tile blocks, heavy-first)
  attn_kernel<<<1024, 512, 0, stream>>>(qkv, Vt, ctx);
  // 6. output projection -> fp32 d_out
  gemm_kernel<<<dim3(DD / 128, MM / 128), 256, 0, stream>>>(ctx, WPt, b_proj, out, DD, DD, 0);
}

// Round 7
// 204.929 us; speedup vs baseline: 2.9182x; 1.1709x over previous
//
#include <hip/hip_runtime.h>

// CausalSelfAttention on MI355X: bf16 MFMA pipeline.
// B=4, S=2048, D=1024, H=16, hd=64. fp32 in/out, bf16 internal compute.

#define DEV __device__ __forceinline__

typedef unsigned short u16;
typedef u16   u16x8 __attribute__((ext_vector_type(8)));
typedef u16   u16x4 __attribute__((ext_vector_type(4)));
typedef float f32x4v __attribute__((ext_vector_type(4)));
typedef __bf16 bf16x8 __attribute__((ext_vector_type(8)));

#define BB 4
#define SS 2048
#define DD 1024
#define HH 16
#define HD 64
#define MM (BB*SS)          // 8192
#define N3D (3*DD)          // 3072
#define L2E 1.44269504088896340736f
#define C8  0.18033688011112042f   // log2(e)/8  (folds the 1/sqrt(64) scale)

DEV u16 f2bf(float f) { return __builtin_bit_cast(u16, (__bf16)f); }  // RNE
DEV float bf2f(u16 h) { return __builtin_bit_cast(float, (unsigned)h << 16); }

DEV f32x4v mfma16(u16x8 a, u16x8 b, f32x4v c) {
  return __builtin_amdgcn_mfma_f32_16x16x32_bf16(
      __builtin_bit_cast(bf16x8, a), __builtin_bit_cast(bf16x8, b), c, 0, 0, 0);
}

// async global->LDS, 16B per lane. LDS dest must be linear in lane order.
DEV void async16(const void* g, void* l) {
  __builtin_amdgcn_global_load_lds(
      (const __attribute__((address_space(1))) void*)g,
      (__attribute__((address_space(3))) void*)l, 16, 0, 0);
}

// DPP rotate-reduce within 16-lane rows (VALU pipe, no LDS traffic).
template <int C> DEV float dpp_fmax(float x) {
  int xi = __builtin_bit_cast(int, x);
  int y = __builtin_amdgcn_update_dpp(xi, xi, C, 0xF, 0xF, false);
  return fmaxf(x, __builtin_bit_cast(float, y));
}
template <int C> DEV float dpp_fadd(float x) {
  int xi = __builtin_bit_cast(int, x);
  int y = __builtin_amdgcn_update_dpp(xi, xi, C, 0xF, 0xF, false);
  return x + __builtin_bit_cast(float, y);
}
DEV float rowmax16(float x) {  // max over the 16 lanes of a DPP row
  x = dpp_fmax<0x121>(x);
  x = dpp_fmax<0x122>(x);
  x = dpp_fmax<0x124>(x);
  x = dpp_fmax<0x128>(x);
  return x;
}
DEV float rowsum16(float x) {
  x = dpp_fadd<0x121>(x);
  x = dpp_fadd<0x122>(x);
  x = dpp_fadd<0x124>(x);
  x = dpp_fadd<0x128>(x);
  return x;
}

// ---------------- 1. prep: fp32->bf16 convert + both weight transposes -------
// blocks [0,3072): w_attn transpose tiles; [3072,4096): w_proj; [4096,6144): convert.
__global__ __launch_bounds__(256) void prep_kernel(
    const float* __restrict__ inp, const float* __restrict__ w_attn,
    const float* __restrict__ w_proj, u16* __restrict__ Abf,
    u16* __restrict__ WAt, u16* __restrict__ WPt) {
  const int bid = blockIdx.x;
  const int tid = threadIdx.x;
  if (bid < 4096) {
    __shared__ float t[32][33];
    const float* W; u16* Wt; int N, K, n0, k0;
    if (bid < 3072) { W = w_attn; Wt = WAt; N = N3D; K = DD;
                      n0 = (bid % 96) * 32; k0 = (bid / 96) * 32; }
    else            { W = w_proj; Wt = WPt; N = DD;  K = DD;
                      int tb = bid - 3072; n0 = (tb % 32) * 32; k0 = (tb / 32) * 32; }
    int tx = tid & 31, ty = tid >> 5;
    for (int i = ty; i < 32; i += 8)
      t[i][tx] = W[(long long)(k0 + i) * N + n0 + tx];
    __syncthreads();
    for (int i = ty; i < 32; i += 8)
      Wt[(long long)(n0 + i) * K + k0 + tx] = f2bf(t[tx][i]);
  } else {
    const long long n = (long long)MM * DD;
    long long i = (long long)(bid - 4096) * 256 + tid;
    for (long long j = i * 4; j < n; j += 2048LL * 256 * 4) {
      f32x4v v = *(const f32x4v*)(inp + j);
      u16x4 o;
      o.x = f2bf(v.x); o.y = f2bf(v.y); o.z = f2bf(v.z); o.w = f2bf(v.w);
      *(u16x4*)(Abf + j) = o;
    }
  }
}

// ---------------- 2. GEMM: C[M][N] = A[M][K] * Bt[N][K]^T + bias -------------
// 128x128 tile, BK=64, 4 waves (each 64x64), 16x16x32 bf16 MFMA (m97 structure).
// mode 0: fp32 out. mode 1: bf16 out; cols >= 2048 (V part) scatter directly
// into Vt[bh][d][s] (fused transpose_v), qkv V region left unwritten.
__global__ __launch_bounds__(256) void gemm_kernel(
    const u16* __restrict__ A, const u16* __restrict__ Bt,
    const float* __restrict__ bias, void* __restrict__ Cout,
    u16* __restrict__ Vt, int Ndim, int Kdim, int mode) {
  __shared__ __align__(16) u16 As[128 * 64];
  __shared__ __align__(16) u16 Bs[128 * 64];

  const int tid = threadIdx.x;
  const int lane = tid & 63, wid = tid >> 6;
  const int l15 = lane & 15, lg = lane >> 4;
  const int rb = blockIdx.y * 128, cb = blockIdx.x * 128;
  const int wr = (wid >> 1) * 64, wc = (wid & 1) * 64;

  f32x4v acc[4][4] = {};

  const int scol = (tid & 7) * 8;     // k-offset within tile this thread fetches
  const int srow = tid >> 3;          // base row (0..31), +32 per issue

  for (int kt = 0; kt < Kdim; kt += 64) {
#pragma unroll
    for (int i = 0; i < 4; ++i) {
      int row = i * 32 + srow;
      async16(A + (long long)(rb + row) * Kdim + kt + scol, (char*)As + i * 4096 + tid * 16);
      async16(Bt + (long long)(cb + row) * Kdim + kt + scol, (char*)Bs + i * 4096 + tid * 16);
    }
    __syncthreads();
#pragma unroll
    for (int kk = 0; kk < 2; ++kk) {
      u16x8 a[4], b[4];
#pragma unroll
      for (int mi = 0; mi < 4; ++mi)
        a[mi] = *(const u16x8*)&As[(wr + mi * 16 + l15) * 64 + kk * 32 + lg * 8];
#pragma unroll
      for (int ni = 0; ni < 4; ++ni)
        b[ni] = *(const u16x8*)&Bs[(wc + ni * 16 + l15) * 64 + kk * 32 + lg * 8];
#pragma unroll
      for (int mi = 0; mi < 4; ++mi)
#pragma unroll
        for (int ni = 0; ni < 4; ++ni)
          acc[mi][ni] = mfma16(a[mi], b[ni], acc[mi][ni]);
    }
    __syncthreads();
  }

#pragma unroll
  for (int mi = 0; mi < 4; ++mi)
#pragma unroll
    for (int ni = 0; ni < 4; ++ni) {
      int col = cb + wc + ni * 16 + l15;
      float bv = bias[col];
      if (mode == 1 && col >= 2 * DD) {
        // V part: write transposed into Vt[(b*16+h)*64 + d][s]
        int h = (col >> 6) & 15, d = col & 63;
#pragma unroll
        for (int r = 0; r < 4; ++r) {
          int row = rb + wr + mi * 16 + lg * 4 + r;
          int b = row >> 11, s = row & 2047;
          Vt[(((long long)(b * HH + h) * HD + d) << 11) + s] = f2bf(acc[mi][ni][r] + bv);
        }
      } else {
#pragma unroll
        for (int r = 0; r < 4; ++r) {
          int row = rb + wr + mi * 16 + lg * 4 + r;
          float v = acc[mi][ni][r] + bv;
          if (mode) ((u16*)Cout)[(long long)row * Ndim + col] = f2bf(v);
          else      ((float*)Cout)[(long long)row * Ndim + col] = v;
        }
      }
    }
}

// ---------------- 3. flash attention, causal -------------------------------
// block = 512 thr (8 waves), fold-paired q-tiles: each block does q-tile
// (15-pair) then (pair) -> uniform 34 k-tile iters per block, no tail.
// Grid 512 (2/CU), XCD-bijective swizzle. Q/K read directly from qkv (scale
// folded into C8); V from Vt. K/V double-buffered LDS (pre-swizzled src);
// P per-wave swizzled LDS. Softmax: lane-local defer-max (THR=64 raw),
// per-lane partial l, single DPP reduce at finalize.
__global__ __launch_bounds__(512, 4) void attn_kernel(
    const u16* __restrict__ qkv, const u16* __restrict__ Vt,
    u16* __restrict__ ctx) {
  __shared__ __align__(16) u16 Ks[2][64 * 64];
  __shared__ __align__(16) u16 Vs[2][64 * 64];
  __shared__ __align__(16) u16 Ps[8][16 * 64];

  const int tid = threadIdx.x, lane = tid & 63, wid = tid >> 6;   // wid 0..7
  const int l15 = lane & 15, lg = lane >> 4;

  // XCD-bijective swizzle: 512 blocks, cpx = 64
  const int orig = (int)blockIdx.x;
  const int wgid = (orig & 7) * 64 + (orig >> 3);
  const int pair = wgid & 7;          // 0..7
  const int bh = wgid >> 3;           // 0..63
  const int b = bh >> 4, h = bh & 15;

  const u16* Qcol = qkv + (long long)b * SS * N3D + h * HD;            // Q cols
  const u16* Kcol = qkv + (long long)b * SS * N3D + DD + h * HD;       // K cols
  const u16* Vbh  = Vt + (long long)bh * HD * SS;
  char* Pw = (char*)&Ps[wid][0];

  // ---- loop-invariant LDS byte offsets (statically indexed -> registers) ----
  const int xr = (l15 & 7) << 4;
  int rdoff[2][4];   // K/V fragment reads: [kk|ks][ni|di]
#pragma unroll
  for (int kk = 0; kk < 2; ++kk)
#pragma unroll
    for (int ni = 0; ni < 4; ++ni)
      rdoff[kk][ni] = (ni * 16 + l15) * 128 + ((kk * 64 + lg * 16) ^ xr);
  int proff[2];      // P reads
#pragma unroll
  for (int ks = 0; ks < 2; ++ks)
    proff[ks] = l15 * 128 + ((ks * 64 + lg * 16) ^ xr);
  int pwoff[4][4];   // P writes [r][ni]
#pragma unroll
  for (int r = 0; r < 4; ++r) {
    int row = lg * 4 + r;
#pragma unroll
    for (int ni = 0; ni < 4; ++ni)
      pwoff[r][ni] = row * 128 + (((ni * 16 + l15) * 2) ^ ((row & 7) << 4));
  }

  // staging: 512 threads cover 64 rows x 128B for K and V each (src pre-swizzled)
  const int rlo = tid >> 3;            // 0..63
  const int cbS = (tid & 7) * 16;      // byte col
  const int swS = cbS ^ ((rlo & 7) << 4);

#pragma unroll 1
  for (int half = 0; half < 2; ++half) {
    const int qt = half ? pair : 15 - pair;   // heavy tile first
    const int q0 = qt * 128;
    const int qw = q0 + wid * 16;             // 16 q-rows per wave
    const int nkb = 2 * qt + 2;               // always even

    // Q fragments (raw; 1/8 scale folded into C8)
    u16x8 qf[2];
#pragma unroll
    for (int kk = 0; kk < 2; ++kk)
      qf[kk] = *(const u16x8*)(Qcol + (long long)(qw + l15) * N3D + kk * 32 + lg * 8);

    f32x4v acc[4] = {};
    float m_s[4], l_p[4];
#pragma unroll
    for (int r = 0; r < 4; ++r) { m_s[r] = -1e30f; l_p[r] = 0.f; }

    auto stage = [&](u16* Kdst, u16* Vdst, int kbase) {
      async16((const char*)(Kcol + (long long)(kbase + rlo) * N3D) + swS,
              (char*)Kdst + rlo * 128 + cbS);
      async16((const char*)(Vbh + (long long)rlo * SS + kbase) + swS,
              (char*)Vdst + rlo * 128 + cbS);
    };

    auto compute = [&](const char* Kb, const char* Vb, int kbase) {
      if (kbase > qw + 15) return;   // fully masked for this wave

      // ---- S = Q K^T (raw scores) ----
      f32x4v s[4] = {};
#pragma unroll
      for (int kk = 0; kk < 2; ++kk) {
        u16x8 bfr[4];
#pragma unroll
        for (int ni = 0; ni < 4; ++ni)
          bfr[ni] = *(const u16x8*)(Kb + rdoff[kk][ni]);
        __builtin_amdgcn_s_setprio(1);
#pragma unroll
        for (int ni = 0; ni < 4; ++ni)
          s[ni] = mfma16(qf[kk], bfr[ni], s[ni]);
        __builtin_amdgcn_s_setprio(0);
      }

      // ---- causal mask (diagonal-overlap tiles only) ----
      if (kbase + 63 > qw) {
#pragma unroll
        for (int ni = 0; ni < 4; ++ni) {
          int kcol = kbase + ni * 16 + l15;
#pragma unroll
          for (int r = 0; r < 4; ++r) {
            int qrow = qw + lg * 4 + r;
            if (kcol > qrow) s[ni][r] = -1e30f;
          }
        }
      }

      // ---- softmax: lane-local defer-max (THR=64 raw => p <= e^8) ----
      float lmax[4];
      bool need = false;
#pragma unroll
      for (int r = 0; r < 4; ++r) {
        lmax[r] = fmaxf(fmaxf(s[0][r], s[1][r]), fmaxf(s[2][r], s[3][r]));
        need = need || (lmax[r] > m_s[r] + 64.f);
      }
      if (__any(need)) {           // rare: establish/raise the shared row max
#pragma unroll
        for (int r = 0; r < 4; ++r) {
          float rm = rowmax16(lmax[r]);
          float newm = fmaxf(m_s[r], rm);
          float sc = __builtin_exp2f((m_s[r] - newm) * C8);
          m_s[r] = newm;
          l_p[r] *= sc;
#pragma unroll
          for (int di = 0; di < 4; ++di) acc[di][r] *= sc;
        }
      }
#pragma unroll
      for (int r = 0; r < 4; ++r) {
        float mC = m_s[r] * C8;
        float rsum = 0.f;
#pragma unroll
        for (int ni = 0; ni < 4; ++ni) {
          float p = __builtin_exp2f(__builtin_fmaf(s[ni][r], C8, -mC));
          s[ni][r] = p;
          rsum += p;
        }
        l_p[r] += rsum;            // per-lane partial; reduced once at finalize
      }

      // ---- P -> LDS (bf16, swizzled); same-wave RAW, no barrier ----
#pragma unroll
      for (int r = 0; r < 4; ++r)
#pragma unroll
        for (int ni = 0; ni < 4; ++ni)
          *(u16*)(Pw + pwoff[r][ni]) = f2bf(s[ni][r]);

      // ---- O += P V ----
#pragma unroll
      for (int ks = 0; ks < 2; ++ks) {
        u16x8 pa = *(const u16x8*)(Pw + proff[ks]);
        u16x8 vb[4];
#pragma unroll
        for (int di = 0; di < 4; ++di)
          vb[di] = *(const u16x8*)(Vb + rdoff[ks][di]);
        __builtin_amdgcn_s_setprio(1);
#pragma unroll
        for (int di = 0; di < 4; ++di)
          acc[di] = mfma16(pa, vb[di], acc[di]);
        __builtin_amdgcn_s_setprio(0);
      }
    };

    stage(&Ks[0][0], &Vs[0][0], 0);
    __syncthreads();              // drains vmcnt; buf0 ready

    for (int kb = 0; kb < nkb; kb += 2) {
      stage(&Ks[1][0], &Vs[1][0], (kb + 1) * 64);   // kb+1 < nkb (nkb even)
      compute((const char*)&Ks[0][0], (const char*)&Vs[0][0], kb * 64);
      __syncthreads();            // done reading buf0; buf1 staged
      if (kb + 2 < nkb) stage(&Ks[0][0], &Vs[0][0], (kb + 2) * 64);
      compute((const char*)&Ks[1][0], (const char*)&Vs[1][0], (kb + 1) * 64);
      __syncthreads();            // done reading buf1; buf0 staged
    }

    // finalize: ctx[b, q, h*64+d]
#pragma unroll
    for (int r = 0; r < 4; ++r) {
      float inv = 1.f / rowsum16(l_p[r]);
      int qrow = qw + lg * 4 + r;
#pragma unroll
      for (int di = 0; di < 4; ++di) {
        int d = di * 16 + l15;
        ctx[((long long)(b * SS + qrow)) * DD + h * HD + d] = f2bf(acc[di][r] * inv);
      }
    }
  }
}

// ---------------- launch -----------------------------------------------------
extern "C" void kernel_launch(void* const* d_in, const int* in_sizes, int n_in,
                              void* d_out, int out_size, void* d_ws, size_t ws_size,
                              hipStream_t stream) {
  const float* inp    = (const float*)d_in[0];
  const float* w_attn = (const float*)d_in[1];
  const float* b_attn = (const float*)d_in[2];
  const float* w_proj = (const float*)d_in[3];
  const float* b_proj = (const float*)d_in[4];
  float* out = (float*)d_out;
  char* ws = (char*)d_ws;

  // workspace layout (bytes)
  const long long off_A   = 0;                       // inp bf16 [8192][1024]  16MB
  const long long off_WAt = 16777216;                // w_attn^T bf16 [3072][1024]  6MB
  const long long off_WPt = 23068672;                // w_proj^T bf16 [1024][1024]  2MB
  const long long off_qkv = 25165824;                // qkv bf16 [8192][3072]  48MB (Q,K live; V unwritten)
  const long long off_ctx = 75497472;                // ctx bf16 [8192][1024] 16MB
  const long long off_Vt  = 92274688;                // Vt [64][64][2048] 16MB
  const long long need    = 109051904;
  if (ws_size < (size_t)need) return;

  u16* Abf = (u16*)(ws + off_A);
  u16* WAt = (u16*)(ws + off_WAt);
  u16* WPt = (u16*)(ws + off_WPt);
  u16* qkv = (u16*)(ws + off_qkv);
  u16* ctx = (u16*)(ws + off_ctx);
  u16* Vt  = (u16*)(ws + off_Vt);

  // 1. prep: inp->bf16 + both weight transposes (one kernel)
  prep_kernel<<<6144, 256, 0, stream>>>(inp, w_attn, w_proj, Abf, WAt, WPt);
  // 2. QKV gemm -> qkv (Q,K cols) + Vt (V cols, fused transpose)
  gemm_kernel<<<dim3(N3D / 128, MM / 128), 256, 0, stream>>>(
      Abf, WAt, b_attn, qkv, Vt, N3D, DD, 1);
  // 3. attention -> ctx bf16 [8192][1024]  (fold-paired uniform blocks)
  attn_kernel<<<512, 512, 0, stream>>>(qkv, Vt, ctx);
  // 4. output projection -> fp32 d_out
  gemm_kernel<<<dim3(DD / 128, MM / 128), 256, 0, stream>>>(
      ctx, WPt, b_proj, out, nullptr, DD, DD, 0);
}

// Round 8
// 185.472 us; speedup vs baseline: 3.2243x; 1.1049x over previous
//
#include <hip/hip_runtime.h>

// CausalSelfAttention on MI355X: bf16 MFMA pipeline.
// B=4, S=2048, D=1024, H=16, hd=64. fp32 in/out, bf16 internal compute.

#define DEV __device__ __forceinline__

typedef unsigned short u16;
typedef u16   u16x8 __attribute__((ext_vector_type(8)));
typedef u16   u16x4 __attribute__((ext_vector_type(4)));
typedef float f32x4v __attribute__((ext_vector_type(4)));
typedef __bf16 bf16x8 __attribute__((ext_vector_type(8)));

#define BB 4
#define SS 2048
#define DD 1024
#define HH 16
#define HD 64
#define MM (BB*SS)          // 8192
#define N3D (3*DD)          // 3072
#define L2E 1.44269504088896340736f
#define C8  0.18033688011112042f   // log2(e)/8  (folds the 1/sqrt(64) scale)

DEV u16 f2bf(float f) { return __builtin_bit_cast(u16, (__bf16)f); }  // RNE
DEV float bf2f(u16 h) { return __builtin_bit_cast(float, (unsigned)h << 16); }

DEV f32x4v mfma16(u16x8 a, u16x8 b, f32x4v c) {
  return __builtin_amdgcn_mfma_f32_16x16x32_bf16(
      __builtin_bit_cast(bf16x8, a), __builtin_bit_cast(bf16x8, b), c, 0, 0, 0);
}

// async global->LDS, 16B per lane. LDS dest must be linear in lane order.
DEV void async16(const void* g, void* l) {
  __builtin_amdgcn_global_load_lds(
      (const __attribute__((address_space(1))) void*)g,
      (__attribute__((address_space(3))) void*)l, 16, 0, 0);
}

// DPP rotate-reduce within 16-lane rows (VALU pipe, no LDS traffic).
template <int C> DEV float dpp_fmax(float x) {
  int xi = __builtin_bit_cast(int, x);
  int y = __builtin_amdgcn_update_dpp(xi, xi, C, 0xF, 0xF, false);
  return fmaxf(x, __builtin_bit_cast(float, y));
}
template <int C> DEV float dpp_fadd(float x) {
  int xi = __builtin_bit_cast(int, x);
  int y = __builtin_amdgcn_update_dpp(xi, xi, C, 0xF, 0xF, false);
  return x + __builtin_bit_cast(float, y);
}
DEV float rowmax16(float x) {  // max over the 16 lanes of a DPP row
  x = dpp_fmax<0x121>(x);
  x = dpp_fmax<0x122>(x);
  x = dpp_fmax<0x124>(x);
  x = dpp_fmax<0x128>(x);
  return x;
}
DEV float rowsum16(float x) {
  x = dpp_fadd<0x121>(x);
  x = dpp_fadd<0x122>(x);
  x = dpp_fadd<0x124>(x);
  x = dpp_fadd<0x128>(x);
  return x;
}

// ---------------- 1. prep: fp32->bf16 convert + both weight transposes -------
// blocks [0,3072): w_attn transpose tiles; [3072,4096): w_proj; [4096,6144): convert.
__global__ __launch_bounds__(256) void prep_kernel(
    const float* __restrict__ inp, const float* __restrict__ w_attn,
    const float* __restrict__ w_proj, u16* __restrict__ Abf,
    u16* __restrict__ WAt, u16* __restrict__ WPt) {
  const int bid = blockIdx.x;
  const int tid = threadIdx.x;
  if (bid < 4096) {
    __shared__ float t[32][33];
    const float* W; u16* Wt; int N, K, n0, k0;
    if (bid < 3072) { W = w_attn; Wt = WAt; N = N3D; K = DD;
                      n0 = (bid % 96) * 32; k0 = (bid / 96) * 32; }
    else            { W = w_proj; Wt = WPt; N = DD;  K = DD;
                      int tb = bid - 3072; n0 = (tb % 32) * 32; k0 = (tb / 32) * 32; }
    int tx = tid & 31, ty = tid >> 5;
    for (int i = ty; i < 32; i += 8)
      t[i][tx] = W[(long long)(k0 + i) * N + n0 + tx];
    __syncthreads();
    for (int i = ty; i < 32; i += 8)
      Wt[(long long)(n0 + i) * K + k0 + tx] = f2bf(t[tx][i]);
  } else {
    const long long n = (long long)MM * DD;
    long long i = (long long)(bid - 4096) * 256 + tid;
    for (long long j = i * 4; j < n; j += 2048LL * 256 * 4) {
      f32x4v v = *(const f32x4v*)(inp + j);
      u16x4 o;
      o.x = f2bf(v.x); o.y = f2bf(v.y); o.z = f2bf(v.z); o.w = f2bf(v.w);
      *(u16x4*)(Abf + j) = o;
    }
  }
}

// ---------------- 2. GEMM: C[M][N] = A[M][K] * Bt[N][K]^T + bias -------------
// 128x128 tile, BK=64, 4 waves (each 64x64), 16x16x32 bf16 MFMA.
// Double-buffered 2-phase K-loop (stage(next) issued before compute(cur),
// one vmcnt-draining barrier per K-step); T2 XOR-swizzled LDS (pre-swizzled
// global_load_lds source + swizzled ds_read); XCD-chunked block swizzle.
// mode 0: fp32 out. mode 1: bf16 out; cols >= 2048 (V part) scatter directly
// into Vt[bh][d][s] (fused transpose_v), qkv V region left unwritten.
__global__ __launch_bounds__(256) void gemm_kernel(
    const u16* __restrict__ A, const u16* __restrict__ Bt,
    const float* __restrict__ bias, void* __restrict__ Cout,
    u16* __restrict__ Vt, int Ndim, int Kdim, int mode) {
  __shared__ __align__(16) u16 As[2][128 * 64];
  __shared__ __align__(16) u16 Bs[2][128 * 64];

  const int tid = threadIdx.x;
  const int lane = tid & 63, wid = tid >> 6;
  const int l15 = lane & 15, lg = lane >> 4;

  // XCD-chunked bijective swizzle (nwg % 8 == 0): XCD x owns a contiguous
  // chunk of wg-space -> A-panel stays resident in that XCD's L2.
  const int nwg = (int)(gridDim.x * gridDim.y);
  const int orig = (int)(blockIdx.y * gridDim.x + blockIdx.x);
  const int wg = (orig & 7) * (nwg >> 3) + (orig >> 3);
  const int bx = wg % (int)gridDim.x, by = wg / (int)gridDim.x;
  const int rb = by * 128, cb = bx * 128;
  const int wr = (wid >> 1) * 64, wc = (wid & 1) * 64;

  f32x4v acc[4][4] = {};

  // staging: 256 thr x 16B = 4KB/issue; 4 issues per 16KB tile; src pre-swizzled
  const int rlo = tid >> 3;           // 0..31 (+32 per issue)
  const int cbS = (tid & 7) * 16;     // byte col in 128B row
  const int swS = cbS ^ ((rlo & 7) << 4);

  // swizzled read offsets, loop-invariant (statically indexed -> registers)
  const int xr = (l15 & 7) << 4;
  int aoff[4][2], boff[4][2];
#pragma unroll
  for (int mi = 0; mi < 4; ++mi)
#pragma unroll
    for (int kk = 0; kk < 2; ++kk) {
      aoff[mi][kk] = (wr + mi * 16 + l15) * 128 + ((kk * 64 + lg * 16) ^ xr);
      boff[mi][kk] = (wc + mi * 16 + l15) * 128 + ((kk * 64 + lg * 16) ^ xr);
    }

  auto stage = [&](int bi, int kt) {
#pragma unroll
    for (int i = 0; i < 4; ++i) {
      int row = i * 32 + rlo;
      async16((const char*)(A + (long long)(rb + row) * Kdim + kt * 64) + swS,
              (char*)&As[bi][0] + row * 128 + cbS);
      async16((const char*)(Bt + (long long)(cb + row) * Kdim + kt * 64) + swS,
              (char*)&Bs[bi][0] + row * 128 + cbS);
    }
  };

  auto compute = [&](int bi) {
    const char* Ab = (const char*)&As[bi][0];
    const char* Bb = (const char*)&Bs[bi][0];
#pragma unroll
    for (int kk = 0; kk < 2; ++kk) {
      u16x8 a[4], b[4];
#pragma unroll
      for (int mi = 0; mi < 4; ++mi)
        a[mi] = *(const u16x8*)(Ab + aoff[mi][kk]);
#pragma unroll
      for (int ni = 0; ni < 4; ++ni)
        b[ni] = *(const u16x8*)(Bb + boff[ni][kk]);
#pragma unroll
      for (int mi = 0; mi < 4; ++mi)
#pragma unroll
        for (int ni = 0; ni < 4; ++ni)
          acc[mi][ni] = mfma16(a[mi], b[ni], acc[mi][ni]);
    }
  };

  const int nK = Kdim >> 6;
  stage(0, 0);
  __syncthreads();                    // drains vmcnt; buf0 ready
  for (int kt = 0; kt < nK; ++kt) {
    if (kt + 1 < nK) stage((kt + 1) & 1, kt + 1);  // in flight during compute
    compute(kt & 1);
    __syncthreads();                  // drains staged loads + WAR on buffers
  }

#pragma unroll
  for (int mi = 0; mi < 4; ++mi)
#pragma unroll
    for (int ni = 0; ni < 4; ++ni) {
      int col = cb + wc + ni * 16 + l15;
      float bv = bias[col];
      if (mode == 1 && col >= 2 * DD) {
        // V part: write transposed into Vt[(b*16+h)*64 + d][s]
        int h = (col >> 6) & 15, d = col & 63;
#pragma unroll
        for (int r = 0; r < 4; ++r) {
          int row = rb + wr + mi * 16 + lg * 4 + r;
          int b = row >> 11, s = row & 2047;
          Vt[(((long long)(b * HH + h) * HD + d) << 11) + s] = f2bf(acc[mi][ni][r] + bv);
        }
      } else {
#pragma unroll
        for (int r = 0; r < 4; ++r) {
          int row = rb + wr + mi * 16 + lg * 4 + r;
          float v = acc[mi][ni][r] + bv;
          if (mode) ((u16*)Cout)[(long long)row * Ndim + col] = f2bf(v);
          else      ((float*)Cout)[(long long)row * Ndim + col] = v;
        }
      }
    }
}

// ---------------- 3. flash attention, causal -------------------------------
// block = 512 thr (8 waves), fold-paired q-tiles: each block does q-tile
// (15-pair) then (pair) -> uniform 34 k-tile iters per block, no tail.
// Grid 512 (2/CU), XCD-bijective swizzle. Q/K read directly from qkv (scale
// folded into C8); V from Vt. K/V double-buffered LDS (pre-swizzled src);
// P per-wave swizzled LDS. Softmax: lane-local defer-max (THR=64 raw),
// per-lane partial l, single DPP reduce at finalize.
__global__ __launch_bounds__(512, 4) void attn_kernel(
    const u16* __restrict__ qkv, const u16* __restrict__ Vt,
    u16* __restrict__ ctx) {
  __shared__ __align__(16) u16 Ks[2][64 * 64];
  __shared__ __align__(16) u16 Vs[2][64 * 64];
  __shared__ __align__(16) u16 Ps[8][16 * 64];

  const int tid = threadIdx.x, lane = tid & 63, wid = tid >> 6;   // wid 0..7
  const int l15 = lane & 15, lg = lane >> 4;

  // XCD-bijective swizzle: 512 blocks, cpx = 64
  const int orig = (int)blockIdx.x;
  const int wgid = (orig & 7) * 64 + (orig >> 3);
  const int pair = wgid & 7;          // 0..7
  const int bh = wgid >> 3;           // 0..63
  const int b = bh >> 4, h = bh & 15;

  const u16* Qcol = qkv + (long long)b * SS * N3D + h * HD;            // Q cols
  const u16* Kcol = qkv + (long long)b * SS * N3D + DD + h * HD;       // K cols
  const u16* Vbh  = Vt + (long long)bh * HD * SS;
  char* Pw = (char*)&Ps[wid][0];

  // ---- loop-invariant LDS byte offsets (statically indexed -> registers) ----
  const int xr = (l15 & 7) << 4;
  int rdoff[2][4];   // K/V fragment reads: [kk|ks][ni|di]
#pragma unroll
  for (int kk = 0; kk < 2; ++kk)
#pragma unroll
    for (int ni = 0; ni < 4; ++ni)
      rdoff[kk][ni] = (ni * 16 + l15) * 128 + ((kk * 64 + lg * 16) ^ xr);
  int proff[2];      // P reads
#pragma unroll
  for (int ks = 0; ks < 2; ++ks)
    proff[ks] = l15 * 128 + ((ks * 64 + lg * 16) ^ xr);
  int pwoff[4][4];   // P writes [r][ni]
#pragma unroll
  for (int r = 0; r < 4; ++r) {
    int row = lg * 4 + r;
#pragma unroll
    for (int ni = 0; ni < 4; ++ni)
      pwoff[r][ni] = row * 128 + (((ni * 16 + l15) * 2) ^ ((row & 7) << 4));
  }

  // staging: 512 threads cover 64 rows x 128B for K and V each (src pre-swizzled)
  const int rlo = tid >> 3;            // 0..63
  const int cbS = (tid & 7) * 16;      // byte col
  const int swS = cbS ^ ((rlo & 7) << 4);

#pragma unroll 1
  for (int half = 0; half < 2; ++half) {
    const int qt = half ? pair : 15 - pair;   // heavy tile first
    const int q0 = qt * 128;
    const int qw = q0 + wid * 16;             // 16 q-rows per wave
    const int nkb = 2 * qt + 2;               // always even

    // Q fragments (raw; 1/8 scale folded into C8)
    u16x8 qf[2];
#pragma unroll
    for (int kk = 0; kk < 2; ++kk)
      qf[kk] = *(const u16x8*)(Qcol + (long long)(qw + l15) * N3D + kk * 32 + lg * 8);

    f32x4v acc[4] = {};
    float m_s[4], l_p[4];
#pragma unroll
    for (int r = 0; r < 4; ++r) { m_s[r] = -1e30f; l_p[r] = 0.f; }

    auto stage = [&](u16* Kdst, u16* Vdst, int kbase) {
      async16((const char*)(Kcol + (long long)(kbase + rlo) * N3D) + swS,
              (char*)Kdst + rlo * 128 + cbS);
      async16((const char*)(Vbh + (long long)rlo * SS + kbase) + swS,
              (char*)Vdst + rlo * 128 + cbS);
    };

    auto compute = [&](const char* Kb, const char* Vb, int kbase) {
      if (kbase > qw + 15) return;   // fully masked for this wave

      // ---- S = Q K^T (raw scores) ----
      f32x4v s[4] = {};
#pragma unroll
      for (int kk = 0; kk < 2; ++kk) {
        u16x8 bfr[4];
#pragma unroll
        for (int ni = 0; ni < 4; ++ni)
          bfr[ni] = *(const u16x8*)(Kb + rdoff[kk][ni]);
        __builtin_amdgcn_s_setprio(1);
#pragma unroll
        for (int ni = 0; ni < 4; ++ni)
          s[ni] = mfma16(qf[kk], bfr[ni], s[ni]);
        __builtin_amdgcn_s_setprio(0);
      }

      // ---- causal mask (diagonal-overlap tiles only) ----
      if (kbase + 63 > qw) {
#pragma unroll
        for (int ni = 0; ni < 4; ++ni) {
          int kcol = kbase + ni * 16 + l15;
#pragma unroll
          for (int r = 0; r < 4; ++r) {
            int qrow = qw + lg * 4 + r;
            if (kcol > qrow) s[ni][r] = -1e30f;
          }
        }
      }

      // ---- softmax: lane-local defer-max (THR=64 raw => p <= e^8) ----
      float lmax[4];
      bool need = false;
#pragma unroll
      for (int r = 0; r < 4; ++r) {
        lmax[r] = fmaxf(fmaxf(s[0][r], s[1][r]), fmaxf(s[2][r], s[3][r]));
        need = need || (lmax[r] > m_s[r] + 64.f);
      }
      if (__any(need)) {           // rare: establish/raise the shared row max
#pragma unroll
        for (int r = 0; r < 4; ++r) {
          float rm = rowmax16(lmax[r]);
          float newm = fmaxf(m_s[r], rm);
          float sc = __builtin_exp2f((m_s[r] - newm) * C8);
          m_s[r] = newm;
          l_p[r] *= sc;
#pragma unroll
          for (int di = 0; di < 4; ++di) acc[di][r] *= sc;
        }
      }
#pragma unroll
      for (int r = 0; r < 4; ++r) {
        float mC = m_s[r] * C8;
        float rsum = 0.f;
#pragma unroll
        for (int ni = 0; ni < 4; ++ni) {
          float p = __builtin_exp2f(__builtin_fmaf(s[ni][r], C8, -mC));
          s[ni][r] = p;
          rsum += p;
        }
        l_p[r] += rsum;            // per-lane partial; reduced once at finalize
      }

      // ---- P -> LDS (bf16, swizzled); same-wave RAW, no barrier ----
#pragma unroll
      for (int r = 0; r < 4; ++r)
#pragma unroll
        for (int ni = 0; ni < 4; ++ni)
          *(u16*)(Pw + pwoff[r][ni]) = f2bf(s[ni][r]);

      // ---- O += P V ----
#pragma unroll
      for (int ks = 0; ks < 2; ++ks) {
        u16x8 pa = *(const u16x8*)(Pw + proff[ks]);
        u16x8 vb[4];
#pragma unroll
        for (int di = 0; di < 4; ++di)
          vb[di] = *(const u16x8*)(Vb + rdoff[ks][di]);
        __builtin_amdgcn_s_setprio(1);
#pragma unroll
        for (int di = 0; di < 4; ++di)
          acc[di] = mfma16(pa, vb[di], acc[di]);
        __builtin_amdgcn_s_setprio(0);
      }
    };

    stage(&Ks[0][0], &Vs[0][0], 0);
    __syncthreads();              // drains vmcnt; buf0 ready

    for (int kb = 0; kb < nkb; kb += 2) {
      stage(&Ks[1][0], &Vs[1][0], (kb + 1) * 64);   // kb+1 < nkb (nkb even)
      compute((const char*)&Ks[0][0], (const char*)&Vs[0][0], kb * 64);
      __syncthreads();            // done reading buf0; buf1 staged
      if (kb + 2 < nkb) stage(&Ks[0][0], &Vs[0][0], (kb + 2) * 64);
      compute((const char*)&Ks[1][0], (const char*)&Vs[1][0], (kb + 1) * 64);
      __syncthreads();            // done reading buf1; buf0 staged
    }

    // finalize: ctx[b, q, h*64+d]
#pragma unroll
    for (int r = 0; r < 4; ++r) {
      float inv = 1.f / rowsum16(l_p[r]);
      int qrow = qw + lg * 4 + r;
#pragma unroll
      for (int di = 0; di < 4; ++di) {
        int d = di * 16 + l15;
        ctx[((long long)(b * SS + qrow)) * DD + h * HD + d] = f2bf(acc[di][r] * inv);
      }
    }
  }
}

// ---------------- launch -----------------------------------------------------
extern "C" void kernel_launch(void* const* d_in, const int* in_sizes, int n_in,
                              void* d_out, int out_size, void* d_ws, size_t ws_size,
                              hipStream_t stream) {
  const float* inp    = (const float*)d_in[0];
  const float* w_attn = (const float*)d_in[1];
  const float* b_attn = (const float*)d_in[2];
  const float* w_proj = (const float*)d_in[3];
  const float* b_proj = (const float*)d_in[4];
  float* out = (float*)d_out;
  char* ws = (char*)d_ws;

  // workspace layout (bytes)
  const long long off_A   = 0;                       // inp bf16 [8192][1024]  16MB
  const long long off_WAt = 16777216;                // w_attn^T bf16 [3072][1024]  6MB
  const long long off_WPt = 23068672;                // w_proj^T bf16 [1024][1024]  2MB
  const long long off_qkv = 25165824;                // qkv bf16 [8192][3072]  48MB (Q,K live; V unwritten)
  const long long off_ctx = 75497472;                // ctx bf16 [8192][1024] 16MB
  const long long off_Vt  = 92274688;                // Vt [64][64][2048] 16MB
  const long long need    = 109051904;
  if (ws_size < (size_t)need) return;

  u16* Abf = (u16*)(ws + off_A);
  u16* WAt = (u16*)(ws + off_WAt);
  u16* WPt = (u16*)(ws + off_WPt);
  u16* qkv = (u16*)(ws + off_qkv);
  u16* ctx = (u16*)(ws + off_ctx);
  u16* Vt  = (u16*)(ws + off_Vt);

  // 1. prep: inp->bf16 + both weight transposes (one kernel)
  prep_kernel<<<6144, 256, 0, stream>>>(inp, w_attn, w_proj, Abf, WAt, WPt);
  // 2. QKV gemm -> qkv (Q,K cols) + Vt (V cols, fused transpose)
  gemm_kernel<<<dim3(N3D / 128, MM / 128), 256, 0, stream>>>(
      Abf, WAt, b_attn, qkv, Vt, N3D, DD, 1);
  // 3. attention -> ctx bf16 [8192][1024]  (fold-paired uniform blocks)
  attn_kernel<<<512, 512, 0, stream>>>(qkv, Vt, ctx);
  // 4. output projection -> fp32 d_out
  gemm_kernel<<<dim3(DD / 128, MM / 128), 256, 0, stream>>>(
      ctx, WPt, b_proj, out, nullptr, DD, DD, 0);
}

// Round 9
// 181.362 us; speedup vs baseline: 3.2974x; 1.0227x over previous
//
#include <hip/hip_runtime.h>

// CausalSelfAttention on MI355X: bf16 MFMA pipeline.
// B=4, S=2048, D=1024, H=16, hd=64. fp32 in/out, bf16 internal compute.

#define DEV __device__ __forceinline__

typedef unsigned short u16;
typedef u16   u16x8 __attribute__((ext_vector_type(8)));
typedef u16   u16x4 __attribute__((ext_vector_type(4)));
typedef float f32x4v __attribute__((ext_vector_type(4)));
typedef __bf16 bf16x8 __attribute__((ext_vector_type(8)));

#define BB 4
#define SS 2048
#define DD 1024
#define HH 16
#define HD 64
#define MM (BB*SS)          // 8192
#define N3D (3*DD)          // 3072
#define C8  0.18033688011112042f   // log2(e)/8  (folds the 1/sqrt(64) scale)

DEV u16 f2bf(float f) { return __builtin_bit_cast(u16, (__bf16)f); }  // RNE
DEV float bf2f(u16 h) { return __builtin_bit_cast(float, (unsigned)h << 16); }

DEV f32x4v mfma16(u16x8 a, u16x8 b, f32x4v c) {
  return __builtin_amdgcn_mfma_f32_16x16x32_bf16(
      __builtin_bit_cast(bf16x8, a), __builtin_bit_cast(bf16x8, b), c, 0, 0, 0);
}

// async global->LDS, 16B per lane. LDS dest must be linear in lane order.
DEV void async16(const void* g, void* l) {
  __builtin_amdgcn_global_load_lds(
      (const __attribute__((address_space(1))) void*)g,
      (__attribute__((address_space(3))) void*)l, 16, 0, 0);
}

// DPP rotate-reduce within 16-lane rows (VALU pipe, no LDS traffic).
template <int C> DEV float dpp_fmax(float x) {
  int xi = __builtin_bit_cast(int, x);
  int y = __builtin_amdgcn_update_dpp(xi, xi, C, 0xF, 0xF, false);
  return fmaxf(x, __builtin_bit_cast(float, y));
}
template <int C> DEV float dpp_fadd(float x) {
  int xi = __builtin_bit_cast(int, x);
  int y = __builtin_amdgcn_update_dpp(xi, xi, C, 0xF, 0xF, false);
  return x + __builtin_bit_cast(float, y);
}
DEV float rowmax16(float x) {
  x = dpp_fmax<0x121>(x);
  x = dpp_fmax<0x122>(x);
  x = dpp_fmax<0x124>(x);
  x = dpp_fmax<0x128>(x);
  return x;
}
DEV float rowsum16(float x) {
  x = dpp_fadd<0x121>(x);
  x = dpp_fadd<0x122>(x);
  x = dpp_fadd<0x124>(x);
  x = dpp_fadd<0x128>(x);
  return x;
}

// ---------------- 1. prep: fp32->bf16 convert + both weight transposes -------
__global__ __launch_bounds__(256) void prep_kernel(
    const float* __restrict__ inp, const float* __restrict__ w_attn,
    const float* __restrict__ w_proj, u16* __restrict__ Abf,
    u16* __restrict__ WAt, u16* __restrict__ WPt) {
  const int bid = blockIdx.x;
  const int tid = threadIdx.x;
  if (bid < 4096) {
    __shared__ float t[32][33];
    const float* W; u16* Wt; int N, K, n0, k0;
    if (bid < 3072) { W = w_attn; Wt = WAt; N = N3D; K = DD;
                      n0 = (bid % 96) * 32; k0 = (bid / 96) * 32; }
    else            { W = w_proj; Wt = WPt; N = DD;  K = DD;
                      int tb = bid - 3072; n0 = (tb % 32) * 32; k0 = (tb / 32) * 32; }
    int tx = tid & 31, ty = tid >> 5;
    for (int i = ty; i < 32; i += 8)
      t[i][tx] = W[(long long)(k0 + i) * N + n0 + tx];
    __syncthreads();
    for (int i = ty; i < 32; i += 8)
      Wt[(long long)(n0 + i) * K + k0 + tx] = f2bf(t[tx][i]);
  } else {
    const long long n = (long long)MM * DD;
    long long i = (long long)(bid - 4096) * 256 + tid;
    for (long long j = i * 4; j < n; j += 2048LL * 256 * 4) {
      f32x4v v = *(const f32x4v*)(inp + j);
      u16x4 o;
      o.x = f2bf(v.x); o.y = f2bf(v.y); o.z = f2bf(v.z); o.w = f2bf(v.w);
      *(u16x4*)(Abf + j) = o;
    }
  }
}

// ---------------- 2. GEMM: C[M][N] = A[M][K] * Bt[N][K]^T + bias -------------
// 128x128 tile, BK=64, 4 waves, double-buffered 2-phase K-loop, XOR-swizzled
// LDS via 4 vaddr regs + immediate offsets, incremental stage pointers.
// mode 1: bf16 out; cols >= 2048 (V) scatter into Vt[bh][d][s].
__global__ __launch_bounds__(256) void gemm_kernel(
    const u16* __restrict__ A, const u16* __restrict__ Bt,
    const float* __restrict__ bias, void* __restrict__ Cout,
    u16* __restrict__ Vt, int Ndim, int Kdim, int mode) {
  // LDS layout: A0@0 A1@16384 B0@32768 B1@49152  (16KB each)
  __shared__ __align__(16) char smem[65536];

  const int tid = threadIdx.x;
  const int lane = tid & 63, wid = tid >> 6;
  const int l15 = lane & 15, lg = lane >> 4;

  const int nwg = (int)(gridDim.x * gridDim.y);
  const int orig = (int)(blockIdx.y * gridDim.x + blockIdx.x);
  const int wg = (orig & 7) * (nwg >> 3) + (orig >> 3);
  const int bx = wg % (int)gridDim.x, by = wg / (int)gridDim.x;
  const int rb = by * 128, cb = bx * 128;
  const int wr = (wid >> 1) * 64, wc = (wid & 1) * 64;

  f32x4v acc[4][4] = {};

  // staging geometry (pre-swizzled source, linear dest)
  const int rlo = tid >> 3;                 // 0..31
  const int cbS = (tid & 7) * 16;
  const int swS = cbS ^ ((rlo & 7) << 4);
  const int sd  = rlo * 128 + cbS;          // dest byte within 32-row chunk

  // read vaddrs: kk folds into ^64, mi/ni and buffer fold into immediates
  const int xr  = (l15 & 7) << 4;
  const int vaA = l15 * 128 + ((lg * 16) ^ xr);
  const int gvA0 = wr * 128 + vaA, gvA1 = gvA0 ^ 64;
  const int gvB0 = wc * 128 + vaA, gvB1 = gvB0 ^ 64;

  // incremental global row pointers (advance 128B per K-step)
  const char* pa[4];
  const char* pb[4];
#pragma unroll
  for (int i = 0; i < 4; ++i) {
    pa[i] = (const char*)A  + (long long)(rb + i * 32 + rlo) * (Kdim * 2) + swS;
    pb[i] = (const char*)Bt + (long long)(cb + i * 32 + rlo) * (Kdim * 2) + swS;
  }

  auto stage = [&](int dofs, int kb) {   // dofs: 0 or 16384; kb: byte delta
#pragma unroll
    for (int i = 0; i < 4; ++i) {
      async16(pa[i] + kb, smem + dofs + i * 4096 + sd);
      async16(pb[i] + kb, smem + 32768 + dofs + i * 4096 + sd);
    }
  };

  auto compute = [&](int aofs, int bofs) {
    u16x8 a0[4], b0[4], a1[4], b1[4];
#pragma unroll
    for (int mi = 0; mi < 4; ++mi) {
      a0[mi] = *(const u16x8*)(smem + aofs + mi * 2048 + gvA0);
      a1[mi] = *(const u16x8*)(smem + aofs + mi * 2048 + gvA1);
    }
#pragma unroll
    for (int ni = 0; ni < 4; ++ni) {
      b0[ni] = *(const u16x8*)(smem + bofs + ni * 2048 + gvB0);
      b1[ni] = *(const u16x8*)(smem + bofs + ni * 2048 + gvB1);
    }
#pragma unroll
    for (int mi = 0; mi < 4; ++mi)
#pragma unroll
      for (int ni = 0; ni < 4; ++ni) {
        acc[mi][ni] = mfma16(a0[mi], b0[ni], acc[mi][ni]);
        acc[mi][ni] = mfma16(a1[mi], b1[ni], acc[mi][ni]);
      }
  };

  const int nK = Kdim >> 6;          // 16 for both GEMMs (even)
  stage(0, 0);
  __syncthreads();
  for (int kt = 0; kt < nK; kt += 2) {
    stage(16384, 128);               // tile kt+1 -> A1/B1
    compute(0, 32768);               // A0/B0
    __syncthreads();
    if (kt + 2 < nK) stage(0, 256);  // tile kt+2 -> A0/B0
    compute(16384, 49152);           // A1/B1
    __syncthreads();
#pragma unroll
    for (int i = 0; i < 4; ++i) { pa[i] += 256; pb[i] += 256; }
  }

#pragma unroll
  for (int mi = 0; mi < 4; ++mi)
#pragma unroll
    for (int ni = 0; ni < 4; ++ni) {
      int col = cb + wc + ni * 16 + l15;
      float bv = bias[col];
      if (mode == 1 && col >= 2 * DD) {
        int h = (col >> 6) & 15, d = col & 63;
#pragma unroll
        for (int r = 0; r < 4; ++r) {
          int row = rb + wr + mi * 16 + lg * 4 + r;
          int b = row >> 11, s = row & 2047;
          Vt[(((long long)(b * HH + h) * HD + d) << 11) + s] = f2bf(acc[mi][ni][r] + bv);
        }
      } else {
#pragma unroll
        for (int r = 0; r < 4; ++r) {
          int row = rb + wr + mi * 16 + lg * 4 + r;
          float v = acc[mi][ni][r] + bv;
          if (mode) ((u16*)Cout)[(long long)row * Ndim + col] = f2bf(v);
          else      ((float*)Cout)[(long long)row * Ndim + col] = v;
        }
      }
    }
}

// ---------------- 3. flash attention, causal -------------------------------
// 512 thr (8 waves), fold-paired q-tiles (uniform 34 k-tiles/block), grid 512,
// XCD-bijective swizzle. All LDS accesses via 2 vaddr regs + immediates;
// incremental staging pointers; nested-fmax -> v_max3; defer-max softmax.
__global__ __launch_bounds__(512, 4) void attn_kernel(
    const u16* __restrict__ qkv, const u16* __restrict__ Vt,
    u16* __restrict__ ctx) {
  // LDS layout: K0@0 K1@8192 V0@16384 V1@24576 P@32768+wid*2048 (total 48KB)
  __shared__ __align__(16) char smem[49152];

  const int tid = threadIdx.x, lane = tid & 63, wid = tid >> 6;   // wid 0..7
  const int l15 = lane & 15, lg = lane >> 4;

  const int orig = (int)blockIdx.x;
  const int wgid = (orig & 7) * 64 + (orig >> 3);
  const int pair = wgid & 7;          // 0..7
  const int bh = wgid >> 3;           // 0..63
  const int b = bh >> 4, h = bh & 15;

  const u16* Qcol = qkv + (long long)b * SS * N3D + h * HD;
  const u16* Kcol = qkv + (long long)b * SS * N3D + DD + h * HD;
  const u16* Vbh  = Vt + (long long)bh * HD * SS;

  // ---- per-lane vaddr registers; all indices fold into ds immediates ----
  const int xr  = (l15 & 7) << 4;
  const int vaA = l15 * 128 + ((lg * 16) ^ xr);   // kk/ks = 0
  const int vaB = vaA ^ 64;                        // kk/ks = 1
  const int vpA = 32768 + wid * 2048 + vaA;        // P reads
  const int vpB = vpA ^ 64;

  int pw[16];                                      // P write addrs (absolute)
#pragma unroll
  for (int r = 0; r < 4; ++r) {
    int row = lg * 4 + r;
#pragma unroll
    for (int ni = 0; ni < 4; ++ni)
      pw[r * 4 + ni] = 32768 + wid * 2048 + row * 128 +
                       (((ni * 16 + l15) * 2) ^ ((row & 7) << 4));
  }

  // staging geometry
  const int rlo = tid >> 3;            // 0..63
  const int cbS = (tid & 7) * 16;
  const int swS = cbS ^ ((rlo & 7) << 4);
  const int sd  = rlo * 128 + cbS;
  const long long KSTP = 64LL * N3D * 2;   // 393216 B per k-tile (K rows)
  const long long VSTP = 64LL * 2;         // 128 B per k-tile (Vt cols)

  auto stage = [&](int dofs, const char* ka, const char* va) {
    async16(ka, smem + dofs + sd);             // K -> 0/8192
    async16(va, smem + 16384 + dofs + sd);     // V -> 16384/24576
  };

#pragma unroll 1
  for (int half = 0; half < 2; ++half) {
    const int qt = half ? pair : 15 - pair;
    const int q0 = qt * 128;
    const int qw = q0 + wid * 16;
    const int nkb = 2 * qt + 2;               // always even

    u16x8 qf[2];
#pragma unroll
    for (int kk = 0; kk < 2; ++kk)
      qf[kk] = *(const u16x8*)(Qcol + (long long)(qw + l15) * N3D + kk * 32 + lg * 8);

    f32x4v acc[4] = {};
    float m_s[4], l_p[4];
#pragma unroll
    for (int r = 0; r < 4; ++r) { m_s[r] = -1e30f; l_p[r] = 0.f; }

    const char* ka = (const char*)Kcol + (long long)rlo * (N3D * 2) + swS;
    const char* va = (const char*)Vbh + (long long)rlo * (SS * 2) + swS;

    auto compute = [&](int kofs, int vofs, int kbase) {
      if (kbase > qw + 15) return;

      // ---- S = Q K^T ----
      f32x4v s[4] = {};
      u16x8 bfr0[4], bfr1[4];
#pragma unroll
      for (int ni = 0; ni < 4; ++ni)
        bfr0[ni] = *(const u16x8*)(smem + kofs + ni * 2048 + vaA);
      __builtin_amdgcn_s_setprio(1);
#pragma unroll
      for (int ni = 0; ni < 4; ++ni)
        s[ni] = mfma16(qf[0], bfr0[ni], s[ni]);
      __builtin_amdgcn_s_setprio(0);
#pragma unroll
      for (int ni = 0; ni < 4; ++ni)
        bfr1[ni] = *(const u16x8*)(smem + kofs + ni * 2048 + vaB);
      __builtin_amdgcn_s_setprio(1);
#pragma unroll
      for (int ni = 0; ni < 4; ++ni)
        s[ni] = mfma16(qf[1], bfr1[ni], s[ni]);
      __builtin_amdgcn_s_setprio(0);

      // ---- causal mask (diagonal-overlap tiles only) ----
      if (kbase + 63 > qw) {
#pragma unroll
        for (int ni = 0; ni < 4; ++ni) {
          int kcol = kbase + ni * 16 + l15;
#pragma unroll
          for (int r = 0; r < 4; ++r) {
            int qrow = qw + lg * 4 + r;
            if (kcol > qrow) s[ni][r] = -1e30f;
          }
        }
      }

      // ---- softmax: lane-local defer-max (THR=64 raw => p <= e^8) ----
      float lmax[4];
      bool need = false;
#pragma unroll
      for (int r = 0; r < 4; ++r) {
        lmax[r] = fmaxf(fmaxf(fmaxf(s[0][r], s[1][r]), s[2][r]), s[3][r]); // max3+max
        need = need || (lmax[r] > m_s[r] + 64.f);
      }
      if (__any(need)) {
#pragma unroll
        for (int r = 0; r < 4; ++r) {
          float rm = rowmax16(lmax[r]);
          float newm = fmaxf(m_s[r], rm);
          float sc = __builtin_exp2f((m_s[r] - newm) * C8);
          m_s[r] = newm;
          l_p[r] *= sc;
#pragma unroll
          for (int di = 0; di < 4; ++di) acc[di][r] *= sc;
        }
      }
#pragma unroll
      for (int r = 0; r < 4; ++r) {
        float mC = m_s[r] * C8;
        float rsum = 0.f;
#pragma unroll
        for (int ni = 0; ni < 4; ++ni) {
          float p = __builtin_exp2f(__builtin_fmaf(s[ni][r], C8, -mC));
          s[ni][r] = p;
          rsum += p;
        }
        l_p[r] += rsum;
      }

      // ---- P -> LDS (bf16, swizzled, precomputed addrs) ----
#pragma unroll
      for (int r = 0; r < 4; ++r)
#pragma unroll
        for (int ni = 0; ni < 4; ++ni)
          *(u16*)(smem + pw[r * 4 + ni]) = f2bf(s[ni][r]);

      // ---- O += P V ----
      u16x8 pa0 = *(const u16x8*)(smem + vpA);
      u16x8 pa1 = *(const u16x8*)(smem + vpB);
      u16x8 vb0[4], vb1[4];
#pragma unroll
      for (int di = 0; di < 4; ++di) {
        vb0[di] = *(const u16x8*)(smem + vofs + di * 2048 + vaA);
        vb1[di] = *(const u16x8*)(smem + vofs + di * 2048 + vaB);
      }
      __builtin_amdgcn_s_setprio(1);
#pragma unroll
      for (int di = 0; di < 4; ++di) {
        acc[di] = mfma16(pa0, vb0[di], acc[di]);
        acc[di] = mfma16(pa1, vb1[di], acc[di]);
      }
      __builtin_amdgcn_s_setprio(0);
    };

    stage(0, ka, va);
    __syncthreads();              // buf0 ready

    for (int kb = 0; kb < nkb; kb += 2) {
      stage(8192, ka + KSTP, va + VSTP);          // tile kb+1 -> buf1
      compute(0, 16384, kb * 64);                 // buf0
      __syncthreads();
      if (kb + 2 < nkb) stage(0, ka + 2 * KSTP, va + 2 * VSTP);
      compute(8192, 24576, (kb + 1) * 64);        // buf1
      __syncthreads();
      ka += 2 * KSTP; va += 2 * VSTP;
    }

    // finalize: ctx[b, q, h*64+d]
#pragma unroll
    for (int r = 0; r < 4; ++r) {
      float inv = 1.f / rowsum16(l_p[r]);
      int qrow = qw + lg * 4 + r;
#pragma unroll
      for (int di = 0; di < 4; ++di) {
        int d = di * 16 + l15;
        ctx[((long long)(b * SS + qrow)) * DD + h * HD + d] = f2bf(acc[di][r] * inv);
      }
    }
  }
}

// ---------------- launch -----------------------------------------------------
extern "C" void kernel_launch(void* const* d_in, const int* in_sizes, int n_in,
                              void* d_out, int out_size, void* d_ws, size_t ws_size,
                              hipStream_t stream) {
  const float* inp    = (const float*)d_in[0];
  const float* w_attn = (const float*)d_in[1];
  const float* b_attn = (const float*)d_in[2];
  const float* w_proj = (const float*)d_in[3];
  const float* b_proj = (const float*)d_in[4];
  float* out = (float*)d_out;
  char* ws = (char*)d_ws;

  const long long off_A   = 0;                       // inp bf16 [8192][1024]  16MB
  const long long off_WAt = 16777216;                // w_attn^T bf16 [3072][1024]  6MB
  const long long off_WPt = 23068672;                // w_proj^T bf16 [1024][1024]  2MB
  const long long off_qkv = 25165824;                // qkv bf16 [8192][3072]  48MB
  const long long off_ctx = 75497472;                // ctx bf16 [8192][1024] 16MB
  const long long off_Vt  = 92274688;                // Vt [64][64][2048] 16MB
  const long long need    = 109051904;
  if (ws_size < (size_t)need) return;

  u16* Abf = (u16*)(ws + off_A);
  u16* WAt = (u16*)(ws + off_WAt);
  u16* WPt = (u16*)(ws + off_WPt);
  u16* qkv = (u16*)(ws + off_qkv);
  u16* ctx = (u16*)(ws + off_ctx);
  u16* Vt  = (u16*)(ws + off_Vt);

  prep_kernel<<<6144, 256, 0, stream>>>(inp, w_attn, w_proj, Abf, WAt, WPt);
  gemm_kernel<<<dim3(N3D / 128, MM / 128), 256, 0, stream>>>(
      Abf, WAt, b_attn, qkv, Vt, N3D, DD, 1);
  attn_kernel<<<512, 512, 0, stream>>>(qkv, Vt, ctx);
  gemm_kernel<<<dim3(DD / 128, MM / 128), 256, 0, stream>>>(
      ctx, WPt, b_proj, out, nullptr, DD, DD, 0);
}

// Round 10
// 178.124 us; speedup vs baseline: 3.3573x; 1.0182x over previous
//
#include <hip/hip_runtime.h>

// CausalSelfAttention on MI355X: bf16 MFMA pipeline.
// B=4, S=2048, D=1024, H=16, hd=64. fp32 in/out, bf16 internal compute.

#define DEV __device__ __forceinline__

typedef unsigned short u16;
typedef unsigned u32x4 __attribute__((ext_vector_type(4)));
typedef u16   u16x8 __attribute__((ext_vector_type(8)));
typedef u16   u16x4 __attribute__((ext_vector_type(4)));
typedef float f32x4v __attribute__((ext_vector_type(4)));
typedef __bf16 bf16x8 __attribute__((ext_vector_type(8)));

#define BB 4
#define SS 2048
#define DD 1024
#define HH 16
#define HD 64
#define MM (BB*SS)          // 8192
#define N3D (3*DD)          // 3072
#define C8  0.18033688011112042f   // log2(e)/8  (folds the 1/sqrt(64) scale)

DEV u16 f2bf(float f) { return __builtin_bit_cast(u16, (__bf16)f); }  // RNE
DEV float bf2f(u16 h) { return __builtin_bit_cast(float, (unsigned)h << 16); }

DEV f32x4v mfma16(u16x8 a, u16x8 b, f32x4v c) {
  return __builtin_amdgcn_mfma_f32_16x16x32_bf16(
      __builtin_bit_cast(bf16x8, a), __builtin_bit_cast(bf16x8, b), c, 0, 0, 0);
}

// async global->LDS, 16B per lane. LDS dest must be linear in lane order.
DEV void async16(const void* g, void* l) {
  __builtin_amdgcn_global_load_lds(
      (const __attribute__((address_space(1))) void*)g,
      (__attribute__((address_space(3))) void*)l, 16, 0, 0);
}

// ---------------- 1. prep: fp32->bf16 convert + both weight transposes -------
__global__ __launch_bounds__(256) void prep_kernel(
    const float* __restrict__ inp, const float* __restrict__ w_attn,
    const float* __restrict__ w_proj, u16* __restrict__ Abf,
    u16* __restrict__ WAt, u16* __restrict__ WPt) {
  const int bid = blockIdx.x;
  const int tid = threadIdx.x;
  if (bid < 4096) {
    __shared__ float t[32][33];
    const float* W; u16* Wt; int N, K, n0, k0;
    if (bid < 3072) { W = w_attn; Wt = WAt; N = N3D; K = DD;
                      n0 = (bid % 96) * 32; k0 = (bid / 96) * 32; }
    else            { W = w_proj; Wt = WPt; N = DD;  K = DD;
                      int tb = bid - 3072; n0 = (tb % 32) * 32; k0 = (tb / 32) * 32; }
    int tx = tid & 31, ty = tid >> 5;
    for (int i = ty; i < 32; i += 8)
      t[i][tx] = W[(long long)(k0 + i) * N + n0 + tx];
    __syncthreads();
    for (int i = ty; i < 32; i += 8)
      Wt[(long long)(n0 + i) * K + k0 + tx] = f2bf(t[tx][i]);
  } else {
    const long long n = (long long)MM * DD;
    long long i = (long long)(bid - 4096) * 256 + tid;
    for (long long j = i * 4; j < n; j += 2048LL * 256 * 4) {
      f32x4v v = *(const f32x4v*)(inp + j);
      u16x4 o;
      o.x = f2bf(v.x); o.y = f2bf(v.y); o.z = f2bf(v.z); o.w = f2bf(v.w);
      *(u16x4*)(Abf + j) = o;
    }
  }
}

// ---------------- 2. GEMM: C[M][N] = A[M][K] * Bt[N][K]^T + bias -------------
// 128x128 tile, BK=64, 4 waves, double-buffered 2-phase K-loop, XOR-swizzled
// LDS via 4 vaddr regs + immediate offsets, incremental stage pointers.
// mode 1: bf16 out; cols >= 2048 (V) scatter into Vt[bh][d][s].
__global__ __launch_bounds__(256) void gemm_kernel(
    const u16* __restrict__ A, const u16* __restrict__ Bt,
    const float* __restrict__ bias, void* __restrict__ Cout,
    u16* __restrict__ Vt, int Ndim, int Kdim, int mode) {
  // LDS layout: A0@0 A1@16384 B0@32768 B1@49152  (16KB each)
  __shared__ __align__(16) char smem[65536];

  const int tid = threadIdx.x;
  const int lane = tid & 63, wid = tid >> 6;
  const int l15 = lane & 15, lg = lane >> 4;

  const int nwg = (int)(gridDim.x * gridDim.y);
  const int orig = (int)(blockIdx.y * gridDim.x + blockIdx.x);
  const int wg = (orig & 7) * (nwg >> 3) + (orig >> 3);
  const int bx = wg % (int)gridDim.x, by = wg / (int)gridDim.x;
  const int rb = by * 128, cb = bx * 128;
  const int wr = (wid >> 1) * 64, wc = (wid & 1) * 64;

  f32x4v acc[4][4] = {};

  // staging geometry (pre-swizzled source, linear dest)
  const int rlo = tid >> 3;                 // 0..31
  const int cbS = (tid & 7) * 16;
  const int swS = cbS ^ ((rlo & 7) << 4);
  const int sd  = rlo * 128 + cbS;          // dest byte within 32-row chunk

  // read vaddrs: kk folds into ^64, mi/ni and buffer fold into immediates
  const int xr  = (l15 & 7) << 4;
  const int vaA = l15 * 128 + ((lg * 16) ^ xr);
  const int gvA0 = wr * 128 + vaA, gvA1 = gvA0 ^ 64;
  const int gvB0 = wc * 128 + vaA, gvB1 = gvB0 ^ 64;

  // incremental global row pointers (advance 128B per K-step)
  const char* pa[4];
  const char* pb[4];
#pragma unroll
  for (int i = 0; i < 4; ++i) {
    pa[i] = (const char*)A  + (long long)(rb + i * 32 + rlo) * (Kdim * 2) + swS;
    pb[i] = (const char*)Bt + (long long)(cb + i * 32 + rlo) * (Kdim * 2) + swS;
  }

  auto stage = [&](int dofs, int kb) {   // dofs: 0 or 16384; kb: byte delta
#pragma unroll
    for (int i = 0; i < 4; ++i) {
      async16(pa[i] + kb, smem + dofs + i * 4096 + sd);
      async16(pb[i] + kb, smem + 32768 + dofs + i * 4096 + sd);
    }
  };

  auto compute = [&](int aofs, int bofs) {
    u16x8 a0[4], b0[4], a1[4], b1[4];
#pragma unroll
    for (int mi = 0; mi < 4; ++mi) {
      a0[mi] = *(const u16x8*)(smem + aofs + mi * 2048 + gvA0);
      a1[mi] = *(const u16x8*)(smem + aofs + mi * 2048 + gvA1);
    }
#pragma unroll
    for (int ni = 0; ni < 4; ++ni) {
      b0[ni] = *(const u16x8*)(smem + bofs + ni * 2048 + gvB0);
      b1[ni] = *(const u16x8*)(smem + bofs + ni * 2048 + gvB1);
    }
#pragma unroll
    for (int mi = 0; mi < 4; ++mi)
#pragma unroll
      for (int ni = 0; ni < 4; ++ni) {
        acc[mi][ni] = mfma16(a0[mi], b0[ni], acc[mi][ni]);
        acc[mi][ni] = mfma16(a1[mi], b1[ni], acc[mi][ni]);
      }
  };

  const int nK = Kdim >> 6;          // 16 for both GEMMs (even)
  stage(0, 0);
  __syncthreads();
  for (int kt = 0; kt < nK; kt += 2) {
    stage(16384, 128);               // tile kt+1 -> A1/B1
    compute(0, 32768);               // A0/B0
    __syncthreads();
    if (kt + 2 < nK) stage(0, 256);  // tile kt+2 -> A0/B0
    compute(16384, 49152);           // A1/B1
    __syncthreads();
#pragma unroll
    for (int i = 0; i < 4; ++i) { pa[i] += 256; pb[i] += 256; }
  }

#pragma unroll
  for (int mi = 0; mi < 4; ++mi)
#pragma unroll
    for (int ni = 0; ni < 4; ++ni) {
      int col = cb + wc + ni * 16 + l15;
      float bv = bias[col];
      if (mode == 1 && col >= 2 * DD) {
        int h = (col >> 6) & 15, d = col & 63;
#pragma unroll
        for (int r = 0; r < 4; ++r) {
          int row = rb + wr + mi * 16 + lg * 4 + r;
          int b = row >> 11, s = row & 2047;
          Vt[(((long long)(b * HH + h) * HD + d) << 11) + s] = f2bf(acc[mi][ni][r] + bv);
        }
      } else {
#pragma unroll
        for (int r = 0; r < 4; ++r) {
          int row = rb + wr + mi * 16 + lg * 4 + r;
          float v = acc[mi][ni][r] + bv;
          if (mode) ((u16*)Cout)[(long long)row * Ndim + col] = f2bf(v);
          else      ((float*)Cout)[(long long)row * Ndim + col] = v;
        }
      }
    }
}

// ---------------- 3. flash attention, causal -------------------------------
// 512 thr (8 waves), fold-paired q-tiles (uniform 34 k-tiles/block), grid 512,
// XCD-bijective swizzle. Swapped QK^T (S^T = mfma(K,Q)) with ROW-PERMUTED
// K-feeds (rowA(m)=8*(m>>2)+(m&3), +4) so S^T output == PV A-fragment layout:
// lane (q=l15,lg) holds P at k = ks*32+lg*8+{0..7}. P stays in registers
// (cvt_pk pack) -> no P LDS round-trip; softmax state is scalar per lane.
// LDS: K/V double-buffered only (32KB). Defer-max (THR=64 raw).
__global__ __launch_bounds__(512, 4) void attn_kernel(
    const u16* __restrict__ qkv, const u16* __restrict__ Vt,
    u16* __restrict__ ctx) {
  // LDS layout: K0@0 K1@8192 V0@16384 V1@24576 (32KB)
  __shared__ __align__(16) char smem[32768];

  const int tid = threadIdx.x, lane = tid & 63, wid = tid >> 6;   // wid 0..7
  const int l15 = lane & 15, lg = lane >> 4;

  const int orig = (int)blockIdx.x;
  const int wgid = (orig & 7) * 64 + (orig >> 3);
  const int pair = wgid & 7;          // 0..7
  const int bh = wgid >> 3;           // 0..63
  const int b = bh >> 4, h = bh & 15;

  const u16* Qcol = qkv + (long long)b * SS * N3D + h * HD;
  const u16* Kcol = qkv + (long long)b * SS * N3D + DD + h * HD;
  const u16* Vbh  = Vt + (long long)bh * HD * SS;

  // K A-operand vaddrs, row-permuted: rowA = 8*(l15>>2)+(l15&3) (rowA&7=l15&3)
  const int rowA = 8 * (l15 >> 2) + (l15 & 3);
  const int vk0 = rowA * 128 + ((lg * 16) ^ ((l15 & 3) << 4));        // ab0 kk0
  const int vk1 = vk0 ^ 64;                                           // ab0 kk1
  const int vk2 = (rowA + 4) * 128 + ((lg * 16) ^ (((l15 & 3) + 4) << 4)); // ab1 kk0
  const int vk3 = vk2 ^ 64;                                           // ab1 kk1
  // V B-operand vaddr (n=d rows; contraction k at ks*64 bytes via ^64)
  const int vv0 = l15 * 128 + ((lg * 16) ^ ((l15 & 7) << 4));
  const int vv1 = vv0 ^ 64;

  // staging geometry
  const int rlo = tid >> 3;            // 0..63
  const int cbS = (tid & 7) * 16;
  const int swS = cbS ^ ((rlo & 7) << 4);
  const int sd  = rlo * 128 + cbS;
  const long long KSTP = 64LL * N3D * 2;   // bytes per k-tile (K rows)
  const long long VSTP = 64LL * 2;         // bytes per k-tile (Vt cols)

  auto stage = [&](int dofs, const char* ka, const char* va) {
    async16(ka, smem + dofs + sd);             // K -> 0/8192
    async16(va, smem + 16384 + dofs + sd);     // V -> 16384/24576
  };

#pragma unroll 1
  for (int half = 0; half < 2; ++half) {
    const int qt = half ? pair : 15 - pair;
    const int q0 = qt * 128;
    const int qw = q0 + wid * 16;
    const int nkb = 2 * qt + 2;               // always even

    u16x8 qf[2];
#pragma unroll
    for (int kk = 0; kk < 2; ++kk)
      qf[kk] = *(const u16x8*)(Qcol + (long long)(qw + l15) * N3D + kk * 32 + lg * 8);

    f32x4v acc[4] = {};
    float m_s = -1e30f, l_p = 0.f;

    const char* ka = (const char*)Kcol + (long long)rlo * (N3D * 2) + swS;
    const char* va = (const char*)Vbh + (long long)rlo * (SS * 2) + swS;

    auto compute = [&](int kofs, int vofs, int kbase) {
      if (kbase > qw + 15) return;

      // ---- S^T = K(permuted rows) x Q: pf[ks][ab][r] = P[q=l15][k] ----
      // k = kbase + ks*32 + lg*8 + ab*4 + r
      f32x4v pf[2][2] = {};
      {
        u16x8 k00 = *(const u16x8*)(smem + kofs + vk0);
        u16x8 k01 = *(const u16x8*)(smem + kofs + vk1);
        u16x8 k10 = *(const u16x8*)(smem + kofs + vk2);
        u16x8 k11 = *(const u16x8*)(smem + kofs + vk3);
        u16x8 k20 = *(const u16x8*)(smem + kofs + 4096 + vk0);
        u16x8 k21 = *(const u16x8*)(smem + kofs + 4096 + vk1);
        u16x8 k30 = *(const u16x8*)(smem + kofs + 4096 + vk2);
        u16x8 k31 = *(const u16x8*)(smem + kofs + 4096 + vk3);
        __builtin_amdgcn_s_setprio(1);
        pf[0][0] = mfma16(k00, qf[0], pf[0][0]);
        pf[0][0] = mfma16(k01, qf[1], pf[0][0]);
        pf[0][1] = mfma16(k10, qf[0], pf[0][1]);
        pf[0][1] = mfma16(k11, qf[1], pf[0][1]);
        pf[1][0] = mfma16(k20, qf[0], pf[1][0]);
        pf[1][0] = mfma16(k21, qf[1], pf[1][0]);
        pf[1][1] = mfma16(k30, qf[0], pf[1][1]);
        pf[1][1] = mfma16(k31, qf[1], pf[1][1]);
        __builtin_amdgcn_s_setprio(0);
      }

      // ---- causal mask ----
      if (kbase + 63 > qw) {
        const int qg = qw + l15;
        const int kl = kbase + lg * 8;
#pragma unroll
        for (int ks = 0; ks < 2; ++ks)
#pragma unroll
          for (int ab = 0; ab < 2; ++ab)
#pragma unroll
            for (int r = 0; r < 4; ++r)
              if (kl + ks * 32 + ab * 4 + r > qg) pf[ks][ab][r] = -1e30f;
      }

      // ---- softmax: scalar per lane (q=l15); lane-local defer (THR=64 raw) ----
      float lmax = pf[0][0][0];
#pragma unroll
      for (int ks = 0; ks < 2; ++ks)
#pragma unroll
        for (int ab = 0; ab < 2; ++ab)
#pragma unroll
          for (int r = 0; r < 4; ++r)
            lmax = fmaxf(lmax, pf[ks][ab][r]);
      if (__any(lmax > m_s + 64.f)) {        // rare: raise the shared row max
        float rm = fmaxf(lmax, __shfl_xor(lmax, 16));
        rm = fmaxf(rm, __shfl_xor(rm, 32));
        float newm = fmaxf(m_s, rm);
        float sc = __builtin_exp2f((m_s - newm) * C8);
        m_s = newm;
        l_p *= sc;
#pragma unroll
        for (int r = 0; r < 4; ++r) {
          float scq = __shfl(sc, (lane & 48) + lg * 4 + r);   // sc for q=lg*4+r
#pragma unroll
          for (int di = 0; di < 4; ++di) acc[di][r] *= scq;
        }
      }
      {
        float mC = m_s * C8;
        float rsum = 0.f;
#pragma unroll
        for (int ks = 0; ks < 2; ++ks)
#pragma unroll
          for (int ab = 0; ab < 2; ++ab)
#pragma unroll
            for (int r = 0; r < 4; ++r) {
              float p = __builtin_exp2f(__builtin_fmaf(pf[ks][ab][r], C8, -mC));
              pf[ks][ab][r] = p;
              rsum += p;
            }
        l_p += rsum;
      }

      // ---- pack P -> PV A-fragments (in registers, no LDS) ----
      u32x4 w0, w1;
      w0.x = (unsigned)f2bf(pf[0][0][0]) | ((unsigned)f2bf(pf[0][0][1]) << 16);
      w0.y = (unsigned)f2bf(pf[0][0][2]) | ((unsigned)f2bf(pf[0][0][3]) << 16);
      w0.z = (unsigned)f2bf(pf[0][1][0]) | ((unsigned)f2bf(pf[0][1][1]) << 16);
      w0.w = (unsigned)f2bf(pf[0][1][2]) | ((unsigned)f2bf(pf[0][1][3]) << 16);
      w1.x = (unsigned)f2bf(pf[1][0][0]) | ((unsigned)f2bf(pf[1][0][1]) << 16);
      w1.y = (unsigned)f2bf(pf[1][0][2]) | ((unsigned)f2bf(pf[1][0][3]) << 16);
      w1.z = (unsigned)f2bf(pf[1][1][0]) | ((unsigned)f2bf(pf[1][1][1]) << 16);
      w1.w = (unsigned)f2bf(pf[1][1][2]) | ((unsigned)f2bf(pf[1][1][3]) << 16);
      u16x8 pa0 = __builtin_bit_cast(u16x8, w0);
      u16x8 pa1 = __builtin_bit_cast(u16x8, w1);

      // ---- O += P V ----
      u16x8 v0[4], v1[4];
#pragma unroll
      for (int di = 0; di < 4; ++di) {
        v0[di] = *(const u16x8*)(smem + vofs + di * 2048 + vv0);
        v1[di] = *(const u16x8*)(smem + vofs + di * 2048 + vv1);
      }
      __builtin_amdgcn_s_setprio(1);
#pragma unroll
      for (int di = 0; di < 4; ++di) {
        acc[di] = mfma16(pa0, v0[di], acc[di]);
        acc[di] = mfma16(pa1, v1[di], acc[di]);
      }
      __builtin_amdgcn_s_setprio(0);
    };

    stage(0, ka, va);
    __syncthreads();              // buf0 ready

    for (int kb = 0; kb < nkb; kb += 2) {
      stage(8192, ka + KSTP, va + VSTP);          // tile kb+1 -> buf1
      compute(0, 16384, kb * 64);                 // buf0
      __syncthreads();
      if (kb + 2 < nkb) stage(0, ka + 2 * KSTP, va + 2 * VSTP);
      compute(8192, 24576, (kb + 1) * 64);        // buf1
      __syncthreads();
      ka += 2 * KSTP; va += 2 * VSTP;
    }

    // finalize: reduce l across lg-groups once; ctx[b, q, h*64+d]
    float l_red = l_p + __shfl_xor(l_p, 16);
    l_red += __shfl_xor(l_red, 32);
#pragma unroll
    for (int r = 0; r < 4; ++r) {
      float lq = __shfl(l_red, (lane & 48) + lg * 4 + r);   // l for q=lg*4+r
      float inv = 1.f / lq;
      int qrow = qw + lg * 4 + r;
#pragma unroll
      for (int di = 0; di < 4; ++di) {
        int d = di * 16 + l15;
        ctx[((long long)(b * SS + qrow)) * DD + h * HD + d] = f2bf(acc[di][r] * inv);
      }
    }
  }
}

// ---------------- launch -----------------------------------------------------
extern "C" void kernel_launch(void* const* d_in, const int* in_sizes, int n_in,
                              void* d_out, int out_size, void* d_ws, size_t ws_size,
                              hipStream_t stream) {
  const float* inp    = (const float*)d_in[0];
  const float* w_attn = (const float*)d_in[1];
  const float* b_attn = (const float*)d_in[2];
  const float* w_proj = (const float*)d_in[3];
  const float* b_proj = (const float*)d_in[4];
  float* out = (float*)d_out;
  char* ws = (char*)d_ws;

  const long long off_A   = 0;                       // inp bf16 [8192][1024]  16MB
  const long long off_WAt = 16777216;                // w_attn^T bf16 [3072][1024]  6MB
  const long long off_WPt = 23068672;                // w_proj^T bf16 [1024][1024]  2MB
  const long long off_qkv = 25165824;                // qkv bf16 [8192][3072]  48MB
  const long long off_ctx = 75497472;                // ctx bf16 [8192][1024] 16MB
  const long long off_Vt  = 92274688;                // Vt [64][64][2048] 16MB
  const long long need    = 109051904;
  if (ws_size < (size_t)need) return;

  u16* Abf = (u16*)(ws + off_A);
  u16* WAt = (u16*)(ws + off_WAt);
  u16* WPt = (u16*)(ws + off_WPt);
  u16* qkv = (u16*)(ws + off_qkv);
  u16* ctx = (u16*)(ws + off_ctx);
  u16* Vt  = (u16*)(ws + off_Vt);

  prep_kernel<<<6144, 256, 0, stream>>>(inp, w_attn, w_proj, Abf, WAt, WPt);
  gemm_kernel<<<dim3(N3D / 128, MM / 128), 256, 0, stream>>>(
      Abf, WAt, b_attn, qkv, Vt, N3D, DD, 1);
  attn_kernel<<<512, 512, 0, stream>>>(qkv, Vt, ctx);
  gemm_kernel<<<dim3(DD / 128, MM / 128), 256, 0, stream>>>(
      ctx, WPt, b_proj, out, nullptr, DD, DD, 0);
}

// Round 11
// 175.496 us; speedup vs baseline: 3.4076x; 1.0150x over previous
//
#include <hip/hip_runtime.h>

// CausalSelfAttention on MI355X: bf16 MFMA pipeline.
// B=4, S=2048, D=1024, H=16, hd=64. fp32 in/out, bf16 internal compute.

#define DEV __device__ __forceinline__

typedef unsigned short u16;
typedef unsigned u32x4 __attribute__((ext_vector_type(4)));
typedef u16   u16x8 __attribute__((ext_vector_type(8)));
typedef u16   u16x4 __attribute__((ext_vector_type(4)));
typedef float f32x4v __attribute__((ext_vector_type(4)));
typedef __bf16 bf16x8 __attribute__((ext_vector_type(8)));

#define BB 4
#define SS 2048
#define DD 1024
#define HH 16
#define HD 64
#define MM (BB*SS)          // 8192
#define N3D (3*DD)          // 3072
#define C8  0.18033688011112042f   // log2(e)/8  (folds the 1/sqrt(64) scale)

DEV u16 f2bf(float f) { return __builtin_bit_cast(u16, (__bf16)f); }  // RNE
DEV float bf2f(u16 h) { return __builtin_bit_cast(float, (unsigned)h << 16); }

DEV f32x4v mfma16(u16x8 a, u16x8 b, f32x4v c) {
  return __builtin_amdgcn_mfma_f32_16x16x32_bf16(
      __builtin_bit_cast(bf16x8, a), __builtin_bit_cast(bf16x8, b), c, 0, 0, 0);
}

// async global->LDS, 16B per lane. LDS dest must be linear in lane order.
DEV void async16(const void* g, void* l) {
  __builtin_amdgcn_global_load_lds(
      (const __attribute__((address_space(1))) void*)g,
      (__attribute__((address_space(3))) void*)l, 16, 0, 0);
}

// ---------------- 1. prep: fp32->bf16 convert + both weight transposes -------
__global__ __launch_bounds__(256) void prep_kernel(
    const float* __restrict__ inp, const float* __restrict__ w_attn,
    const float* __restrict__ w_proj, u16* __restrict__ Abf,
    u16* __restrict__ WAt, u16* __restrict__ WPt) {
  const int bid = blockIdx.x;
  const int tid = threadIdx.x;
  if (bid < 4096) {
    __shared__ float t[32][33];
    const float* W; u16* Wt; int N, K, n0, k0;
    if (bid < 3072) { W = w_attn; Wt = WAt; N = N3D; K = DD;
                      n0 = (bid % 96) * 32; k0 = (bid / 96) * 32; }
    else            { W = w_proj; Wt = WPt; N = DD;  K = DD;
                      int tb = bid - 3072; n0 = (tb % 32) * 32; k0 = (tb / 32) * 32; }
    int tx = tid & 31, ty = tid >> 5;
    for (int i = ty; i < 32; i += 8)
      t[i][tx] = W[(long long)(k0 + i) * N + n0 + tx];
    __syncthreads();
    for (int i = ty; i < 32; i += 8)
      Wt[(long long)(n0 + i) * K + k0 + tx] = f2bf(t[tx][i]);
  } else {
    const long long n = (long long)MM * DD;
    long long i = (long long)(bid - 4096) * 256 + tid;
    for (long long j = i * 4; j < n; j += 2048LL * 256 * 4) {
      f32x4v v = *(const f32x4v*)(inp + j);
      u16x4 o;
      o.x = f2bf(v.x); o.y = f2bf(v.y); o.z = f2bf(v.z); o.w = f2bf(v.w);
      *(u16x4*)(Abf + j) = o;
    }
  }
}

// ---------------- 2. GEMM: C[M][N] = A[M][K] * Bt[N][K]^T + bias -------------
// 128x128 tile, BK=64, 4 waves, double-buffered 2-phase K-loop, XOR-swizzled
// LDS via 4 vaddr regs + immediate offsets, incremental stage pointers.
// mode 1: bf16 out; cols >= 2048 (V) scatter into Vt[bh][d][s].
__global__ __launch_bounds__(256) void gemm_kernel(
    const u16* __restrict__ A, const u16* __restrict__ Bt,
    const float* __restrict__ bias, void* __restrict__ Cout,
    u16* __restrict__ Vt, int Ndim, int Kdim, int mode) {
  // LDS layout: A0@0 A1@16384 B0@32768 B1@49152  (16KB each)
  __shared__ __align__(16) char smem[65536];

  const int tid = threadIdx.x;
  const int lane = tid & 63, wid = tid >> 6;
  const int l15 = lane & 15, lg = lane >> 4;

  const int nwg = (int)(gridDim.x * gridDim.y);
  const int orig = (int)(blockIdx.y * gridDim.x + blockIdx.x);
  const int wg = (orig & 7) * (nwg >> 3) + (orig >> 3);
  const int bx = wg % (int)gridDim.x, by = wg / (int)gridDim.x;
  const int rb = by * 128, cb = bx * 128;
  const int wr = (wid >> 1) * 64, wc = (wid & 1) * 64;

  f32x4v acc[4][4] = {};

  // staging geometry (pre-swizzled source, linear dest)
  const int rlo = tid >> 3;                 // 0..31
  const int cbS = (tid & 7) * 16;
  const int swS = cbS ^ ((rlo & 7) << 4);
  const int sd  = rlo * 128 + cbS;          // dest byte within 32-row chunk

  // read vaddrs: kk folds into ^64, mi/ni and buffer fold into immediates
  const int xr  = (l15 & 7) << 4;
  const int vaA = l15 * 128 + ((lg * 16) ^ xr);
  const int gvA0 = wr * 128 + vaA, gvA1 = gvA0 ^ 64;
  const int gvB0 = wc * 128 + vaA, gvB1 = gvB0 ^ 64;

  // incremental global row pointers (advance 128B per K-step)
  const char* pa[4];
  const char* pb[4];
#pragma unroll
  for (int i = 0; i < 4; ++i) {
    pa[i] = (const char*)A  + (long long)(rb + i * 32 + rlo) * (Kdim * 2) + swS;
    pb[i] = (const char*)Bt + (long long)(cb + i * 32 + rlo) * (Kdim * 2) + swS;
  }

  auto stage = [&](int dofs, int kb) {   // dofs: 0 or 16384; kb: byte delta
#pragma unroll
    for (int i = 0; i < 4; ++i) {
      async16(pa[i] + kb, smem + dofs + i * 4096 + sd);
      async16(pb[i] + kb, smem + 32768 + dofs + i * 4096 + sd);
    }
  };

  auto compute = [&](int aofs, int bofs) {
    u16x8 a0[4], b0[4], a1[4], b1[4];
#pragma unroll
    for (int mi = 0; mi < 4; ++mi) {
      a0[mi] = *(const u16x8*)(smem + aofs + mi * 2048 + gvA0);
      a1[mi] = *(const u16x8*)(smem + aofs + mi * 2048 + gvA1);
    }
#pragma unroll
    for (int ni = 0; ni < 4; ++ni) {
      b0[ni] = *(const u16x8*)(smem + bofs + ni * 2048 + gvB0);
      b1[ni] = *(const u16x8*)(smem + bofs + ni * 2048 + gvB1);
    }
#pragma unroll
    for (int mi = 0; mi < 4; ++mi)
#pragma unroll
      for (int ni = 0; ni < 4; ++ni) {
        acc[mi][ni] = mfma16(a0[mi], b0[ni], acc[mi][ni]);
        acc[mi][ni] = mfma16(a1[mi], b1[ni], acc[mi][ni]);
      }
  };

  const int nK = Kdim >> 6;          // 16 for both GEMMs (even)
  stage(0, 0);
  __syncthreads();
  for (int kt = 0; kt < nK; kt += 2) {
    stage(16384, 128);               // tile kt+1 -> A1/B1
    compute(0, 32768);               // A0/B0
    __syncthreads();
    if (kt + 2 < nK) stage(0, 256);  // tile kt+2 -> A0/B0
    compute(16384, 49152);           // A1/B1
    __syncthreads();
#pragma unroll
    for (int i = 0; i < 4; ++i) { pa[i] += 256; pb[i] += 256; }
  }

#pragma unroll
  for (int mi = 0; mi < 4; ++mi)
#pragma unroll
    for (int ni = 0; ni < 4; ++ni) {
      int col = cb + wc + ni * 16 + l15;
      float bv = bias[col];
      if (mode == 1 && col >= 2 * DD) {
        int h = (col >> 6) & 15, d = col & 63;
#pragma unroll
        for (int r = 0; r < 4; ++r) {
          int row = rb + wr + mi * 16 + lg * 4 + r;
          int b = row >> 11, s = row & 2047;
          Vt[(((long long)(b * HH + h) * HD + d) << 11) + s] = f2bf(acc[mi][ni][r] + bv);
        }
      } else {
#pragma unroll
        for (int r = 0; r < 4; ++r) {
          int row = rb + wr + mi * 16 + lg * 4 + r;
          float v = acc[mi][ni][r] + bv;
          if (mode) ((u16*)Cout)[(long long)row * Ndim + col] = f2bf(v);
          else      ((float*)Cout)[(long long)row * Ndim + col] = v;
        }
      }
    }
}

// ---------------- 3. flash attention, causal -------------------------------
// 256 thr (4 waves), 32 q-rows/wave (mi=2 row-blocks of 16) -> one 128-row
// q-tile per block; grid 1024, ALL blocks co-resident (32KB LDS, <=128 VGPR,
// 4 blocks/CU). Per-XCD: 8 dedicated heads (K/V fits its L2); qt order
// quarter-interleaved so any stride-32 4-subset has equal total cost.
// Swapped QK^T (S^T = mfma(K,Q), row-permuted K feeds) -> P in registers.
// Conflict-free swizzle key(row) = (row&3)|(((row>>3)&1)<<2) on K and V.
// Defer-max softmax (THR=64 raw), per-lane partial l, one reduce at end.
__global__ __launch_bounds__(256, 4) void attn_kernel(
    const u16* __restrict__ qkv, const u16* __restrict__ Vt,
    u16* __restrict__ ctx) {
  // LDS layout: K0@0 K1@8192 V0@16384 V1@24576 (32KB)
  __shared__ __align__(16) char smem[32768];

  const int tid = threadIdx.x, lane = tid & 63, wid = tid >> 6;   // wid 0..3
  const int l15 = lane & 15, lg = lane >> 4;

  // dispatch: d -> xcd = d&7, rank = d>>3 (0..127); per XCD: 16 qt-groups x 8 bh
  const int d = (int)blockIdx.x;
  const int rank = d >> 3;
  const int t = rank >> 3;            // 0..15
  const int jj = t & 3, q4 = t >> 2;
  // qt table [15,14,13,12, 8,9,10,11, 7,6,5,4, 0,1,2,3]: stride-4 subsets sum 30
  const int qt = (q4 == 0) ? 15 - jj : (q4 == 1) ? 8 + jj
               : (q4 == 2) ? 7 - jj  : jj;
  const int bh = (d & 7) * 8 + (rank & 7);
  const int b = bh >> 4, h = bh & 15;

  const u16* Qcol = qkv + (long long)b * SS * N3D + h * HD;
  const u16* Kcol = qkv + (long long)b * SS * N3D + DD + h * HD;
  const u16* Vbh  = Vt + (long long)bh * HD * SS;

  // K A-operand vaddrs, row-permuted rowA = 8*(l15>>2)+(l15&3); key uses
  // (row&3)|(((row>>3)&1)<<2) which is invariant under +4/+32 row offsets.
  const int rowA = 8 * (l15 >> 2) + (l15 & 3);
  const int kA = (((l15 & 3) | (((l15 >> 2) & 1) << 2))) << 4;
  const int vk0 = rowA * 128 + ((lg * 16) ^ kA);   // ks0 ab0 kk0
  const int vk1 = vk0 ^ 64;                        // kk1
  const int vk2 = vk0 + 512;                       // ab1 (+4 rows, same key)
  const int vk3 = vk2 ^ 64;
  // V B-operand vaddr (rows = d 0..15 per di block)
  const int kV = (((l15 & 3) | (((l15 >> 3) & 1) << 2))) << 4;
  const int vv0 = l15 * 128 + ((lg * 16) ^ kV);
  const int vv1 = vv0 ^ 64;

  // staging geometry: 256 thr cover 32 rows x 128B per issue; 2 issues each
  // for K (rows 0..63) and V (d 0..63). Source pre-swizzled with key(rlo).
  const int rlo = tid >> 3;            // 0..31
  const int cbS = (tid & 7) * 16;
  const int kw = (((rlo & 3) | (((rlo >> 3) & 1) << 2))) << 4;  // = key(rlo+32)
  const int swS = cbS ^ kw;
  const int sd  = rlo * 128 + cbS;
  const long long KSTP = 64LL * N3D * 2;   // bytes per k-tile (K rows)
  const long long VSTP = 64LL * 2;         // bytes per k-tile (Vt cols)
  const long long KHLF = 32LL * N3D * 2;   // +32 K rows
  const long long VHLF = 32LL * SS * 2;    // +32 V rows (d)

  auto stage = [&](int dofs, const char* ka, const char* va) {
    async16(ka,        smem + dofs + sd);
    async16(ka + KHLF, smem + dofs + 4096 + sd);
    async16(va,        smem + 16384 + dofs + sd);
    async16(va + VHLF, smem + 16384 + dofs + 4096 + sd);
  };

  const int q0 = qt * 128;
  const int qw = q0 + wid * 32;        // 32 q-rows per wave
  const int nkb = 2 * qt + 2;          // always even

  // Q fragments: rows qw + mi*16 + l15
  u16x8 qf[2][2];
#pragma unroll
  for (int mi = 0; mi < 2; ++mi)
#pragma unroll
    for (int kk = 0; kk < 2; ++kk)
      qf[mi][kk] = *(const u16x8*)(Qcol + (long long)(qw + mi * 16 + l15) * N3D +
                                   kk * 32 + lg * 8);

  f32x4v acc[2][4] = {};
  float m_s[2] = {-1e30f, -1e30f}, l_p[2] = {0.f, 0.f};

  const char* ka = (const char*)Kcol + (long long)rlo * (N3D * 2) + swS;
  const char* va = (const char*)Vbh + (long long)rlo * (SS * 2) + swS;

  auto compute = [&](int kofs, int vofs, int kbase) {
    if (kbase > qw + 31) return;

    // ---- S^T = K(permuted rows) x Q: pf[mi][ks][ab][r] = P[q][k] ----
    // q = qw + mi*16 + l15;  k = kbase + ks*32 + lg*8 + ab*4 + r
    f32x4v pf[2][2][2] = {};
    {
      u16x8 kf0, kf1;
      kf0 = *(const u16x8*)(smem + kofs + vk0);
      kf1 = *(const u16x8*)(smem + kofs + vk1);
      __builtin_amdgcn_s_setprio(1);
      pf[0][0][0] = mfma16(kf0, qf[0][0], pf[0][0][0]);
      pf[0][0][0] = mfma16(kf1, qf[0][1], pf[0][0][0]);
      pf[1][0][0] = mfma16(kf0, qf[1][0], pf[1][0][0]);
      pf[1][0][0] = mfma16(kf1, qf[1][1], pf[1][0][0]);
      __builtin_amdgcn_s_setprio(0);
      kf0 = *(const u16x8*)(smem + kofs + vk2);
      kf1 = *(const u16x8*)(smem + kofs + vk3);
      __builtin_amdgcn_s_setprio(1);
      pf[0][0][1] = mfma16(kf0, qf[0][0], pf[0][0][1]);
      pf[0][0][1] = mfma16(kf1, qf[0][1], pf[0][0][1]);
      pf[1][0][1] = mfma16(kf0, qf[1][0], pf[1][0][1]);
      pf[1][0][1] = mfma16(kf1, qf[1][1], pf[1][0][1]);
      __builtin_amdgcn_s_setprio(0);
      kf0 = *(const u16x8*)(smem + kofs + 4096 + vk0);
      kf1 = *(const u16x8*)(smem + kofs + 4096 + vk1);
      __builtin_amdgcn_s_setprio(1);
      pf[0][1][0] = mfma16(kf0, qf[0][0], pf[0][1][0]);
      pf[0][1][0] = mfma16(kf1, qf[0][1], pf[0][1][0]);
      pf[1][1][0] = mfma16(kf0, qf[1][0], pf[1][1][0]);
      pf[1][1][0] = mfma16(kf1, qf[1][1], pf[1][1][0]);
      __builtin_amdgcn_s_setprio(0);
      kf0 = *(const u16x8*)(smem + kofs + 4096 + vk2);
      kf1 = *(const u16x8*)(smem + kofs + 4096 + vk3);
      __builtin_amdgcn_s_setprio(1);
      pf[0][1][1] = mfma16(kf0, qf[0][0], pf[0][1][1]);
      pf[0][1][1] = mfma16(kf1, qf[0][1], pf[0][1][1]);
      pf[1][1][1] = mfma16(kf0, qf[1][0], pf[1][1][1]);
      pf[1][1][1] = mfma16(kf1, qf[1][1], pf[1][1][1]);
      __builtin_amdgcn_s_setprio(0);
    }

    // ---- causal mask ----
    if (kbase + 63 > qw) {
      const int kl = kbase + lg * 8;
#pragma unroll
      for (int mi = 0; mi < 2; ++mi) {
        const int qg = qw + mi * 16 + l15;
#pragma unroll
        for (int ks = 0; ks < 2; ++ks)
#pragma unroll
          for (int ab = 0; ab < 2; ++ab)
#pragma unroll
            for (int r = 0; r < 4; ++r)
              if (kl + ks * 32 + ab * 4 + r > qg) pf[mi][ks][ab][r] = -1e30f;
      }
    }

    // ---- softmax: per-lane scalar state (q = l15 within mi); defer-max ----
    float lmax[2];
    bool need = false;
#pragma unroll
    for (int mi = 0; mi < 2; ++mi) {
      float v0 = fmaxf(fmaxf(fmaxf(pf[mi][0][0][0], pf[mi][0][0][1]),
                             pf[mi][0][0][2]), pf[mi][0][0][3]);
      float v1 = fmaxf(fmaxf(fmaxf(pf[mi][0][1][0], pf[mi][0][1][1]),
                             pf[mi][0][1][2]), pf[mi][0][1][3]);
      float v2 = fmaxf(fmaxf(fmaxf(pf[mi][1][0][0], pf[mi][1][0][1]),
                             pf[mi][1][0][2]), pf[mi][1][0][3]);
      float v3 = fmaxf(fmaxf(fmaxf(pf[mi][1][1][0], pf[mi][1][1][1]),
                             pf[mi][1][1][2]), pf[mi][1][1][3]);
      lmax[mi] = fmaxf(fmaxf(v0, v1), fmaxf(v2, v3));
      need = need || (lmax[mi] > m_s[mi] + 64.f);
    }
    if (__any(need)) {           // rare: raise shared row max (uniform per l15)
#pragma unroll
      for (int mi = 0; mi < 2; ++mi) {
        float rm = fmaxf(lmax[mi], __shfl_xor(lmax[mi], 16));
        rm = fmaxf(rm, __shfl_xor(rm, 32));
        float newm = fmaxf(m_s[mi], rm);
        float sc = __builtin_exp2f((m_s[mi] - newm) * C8);
        m_s[mi] = newm;
        l_p[mi] *= sc;
#pragma unroll
        for (int r = 0; r < 4; ++r) {
          float scq = __shfl(sc, (lane & 48) + lg * 4 + r);
#pragma unroll
          for (int di = 0; di < 4; ++di) acc[mi][di][r] *= scq;
        }
      }
    }
#pragma unroll
    for (int mi = 0; mi < 2; ++mi) {
      float mC = m_s[mi] * C8;
      float rsum = 0.f;
#pragma unroll
      for (int ks = 0; ks < 2; ++ks)
#pragma unroll
        for (int ab = 0; ab < 2; ++ab)
#pragma unroll
          for (int r = 0; r < 4; ++r) {
            float p = __builtin_exp2f(__builtin_fmaf(pf[mi][ks][ab][r], C8, -mC));
            pf[mi][ks][ab][r] = p;
            rsum += p;
          }
      l_p[mi] += rsum;
    }

    // ---- pack P -> PV A-fragments (in registers) ----
    u16x8 pa[2][2];
#pragma unroll
    for (int mi = 0; mi < 2; ++mi)
#pragma unroll
      for (int ks = 0; ks < 2; ++ks) {
        u32x4 w;
        w.x = (unsigned)f2bf(pf[mi][ks][0][0]) | ((unsigned)f2bf(pf[mi][ks][0][1]) << 16);
        w.y = (unsigned)f2bf(pf[mi][ks][0][2]) | ((unsigned)f2bf(pf[mi][ks][0][3]) << 16);
        w.z = (unsigned)f2bf(pf[mi][ks][1][0]) | ((unsigned)f2bf(pf[mi][ks][1][1]) << 16);
        w.w = (unsigned)f2bf(pf[mi][ks][1][2]) | ((unsigned)f2bf(pf[mi][ks][1][3]) << 16);
        pa[mi][ks] = __builtin_bit_cast(u16x8, w);
      }

    // ---- O += P V ----
#pragma unroll
    for (int di = 0; di < 4; ++di) {
      u16x8 v0 = *(const u16x8*)(smem + vofs + di * 2048 + vv0);
      u16x8 v1 = *(const u16x8*)(smem + vofs + di * 2048 + vv1);
      __builtin_amdgcn_s_setprio(1);
      acc[0][di] = mfma16(pa[0][0], v0, acc[0][di]);
      acc[0][di] = mfma16(pa[0][1], v1, acc[0][di]);
      acc[1][di] = mfma16(pa[1][0], v0, acc[1][di]);
      acc[1][di] = mfma16(pa[1][1], v1, acc[1][di]);
      __builtin_amdgcn_s_setprio(0);
    }
  };

  stage(0, ka, va);
  __syncthreads();              // buf0 ready

  for (int kb = 0; kb < nkb; kb += 2) {
    stage(8192, ka + KSTP, va + VSTP);          // tile kb+1 -> buf1
    compute(0, 16384, kb * 64);                 // buf0
    __syncthreads();
    if (kb + 2 < nkb) stage(0, ka + 2 * KSTP, va + 2 * VSTP);
    compute(8192, 24576, (kb + 1) * 64);        // buf1
    __syncthreads();
    ka += 2 * KSTP; va += 2 * VSTP;
  }

  // finalize: reduce l across lg-groups once; ctx[b, q, h*64+d]
#pragma unroll
  for (int mi = 0; mi < 2; ++mi) {
    float l_red = l_p[mi] + __shfl_xor(l_p[mi], 16);
    l_red += __shfl_xor(l_red, 32);
#pragma unroll
    for (int r = 0; r < 4; ++r) {
      float lq = __shfl(l_red, (lane & 48) + lg * 4 + r);
      float inv = 1.f / lq;
      int qrow = qw + mi * 16 + lg * 4 + r;
#pragma unroll
      for (int di = 0; di < 4; ++di) {
        int dd = di * 16 + l15;
        ctx[((long long)(b * SS + qrow)) * DD + h * HD + dd] = f2bf(acc[mi][di][r] * inv);
      }
    }
  }
}

// ---------------- launch -----------------------------------------------------
extern "C" void kernel_launch(void* const* d_in, const int* in_sizes, int n_in,
                              void* d_out, int out_size, void* d_ws, size_t ws_size,
                              hipStream_t stream) {
  const float* inp    = (const float*)d_in[0];
  const float* w_attn = (const float*)d_in[1];
  const float* b_attn = (const float*)d_in[2];
  const float* w_proj = (const float*)d_in[3];
  const float* b_proj = (const float*)d_in[4];
  float* out = (float*)d_out;
  char* ws = (char*)d_ws;

  const long long off_A   = 0;                       // inp bf16 [8192][1024]  16MB
  const long long off_WAt = 16777216;                // w_attn^T bf16 [3072][1024]  6MB
  const long long off_WPt = 23068672;                // w_proj^T bf16 [1024][1024]  2MB
  const long long off_qkv = 25165824;                // qkv bf16 [8192][3072]  48MB
  const long long off_ctx = 75497472;                // ctx bf16 [8192][1024] 16MB
  const long long off_Vt  = 92274688;                // Vt [64][64][2048] 16MB
  const long long need    = 109051904;
  if (ws_size < (size_t)need) return;

  u16* Abf = (u16*)(ws + off_A);
  u16* WAt = (u16*)(ws + off_WAt);
  u16* WPt = (u16*)(ws + off_WPt);
  u16* qkv = (u16*)(ws + off_qkv);
  u16* ctx = (u16*)(ws + off_ctx);
  u16* Vt  = (u16*)(ws + off_Vt);

  prep_kernel<<<6144, 256, 0, stream>>>(inp, w_attn, w_proj, Abf, WAt, WPt);
  gemm_kernel<<<dim3(N3D / 128, MM / 128), 256, 0, stream>>>(
      Abf, WAt, b_attn, qkv, Vt, N3D, DD, 1);
  attn_kernel<<<1024, 256, 0, stream>>>(qkv, Vt, ctx);
  gemm_kernel<<<dim3(DD / 128, MM / 128), 256, 0, stream>>>(
      ctx, WPt, b_proj, out, nullptr, DD, DD, 0);
}

// Round 12
// 172.607 us; speedup vs baseline: 3.4647x; 1.0167x over previous
//
#include <hip/hip_runtime.h>

// CausalSelfAttention on MI355X: bf16 MFMA pipeline.
// B=4, S=2048, D=1024, H=16, hd=64. fp32 in/out, bf16 internal compute.

#define DEV __device__ __forceinline__

typedef unsigned short u16;
typedef unsigned u32x4 __attribute__((ext_vector_type(4)));
typedef u16   u16x8 __attribute__((ext_vector_type(8)));
typedef u16   u16x4 __attribute__((ext_vector_type(4)));
typedef float f32x4v __attribute__((ext_vector_type(4)));
typedef __bf16 bf16x8 __attribute__((ext_vector_type(8)));

#define BB 4
#define SS 2048
#define DD 1024
#define HH 16
#define HD 64
#define MM (BB*SS)          // 8192
#define N3D (3*DD)          // 3072
#define C8  0.18033688011112042f   // log2(e)/8  (folds the 1/sqrt(64) scale)

DEV u16 f2bf(float f) { return __builtin_bit_cast(u16, (__bf16)f); }  // RNE
DEV float bf2f(u16 h) { return __builtin_bit_cast(float, (unsigned)h << 16); }

DEV f32x4v mfma16(u16x8 a, u16x8 b, f32x4v c) {
  return __builtin_amdgcn_mfma_f32_16x16x32_bf16(
      __builtin_bit_cast(bf16x8, a), __builtin_bit_cast(bf16x8, b), c, 0, 0, 0);
}

// async global->LDS, 16B per lane. LDS dest must be linear in lane order.
DEV void async16(const void* g, void* l) {
  __builtin_amdgcn_global_load_lds(
      (const __attribute__((address_space(1))) void*)g,
      (__attribute__((address_space(3))) void*)l, 16, 0, 0);
}

#define WAIT_VM(N) asm volatile("s_waitcnt vmcnt(" #N ")" ::: "memory")
#define BAR() __builtin_amdgcn_s_barrier()

// ---------------- 1. prep: fp32->bf16 convert + both weight transposes -------
__global__ __launch_bounds__(256) void prep_kernel(
    const float* __restrict__ inp, const float* __restrict__ w_attn,
    const float* __restrict__ w_proj, u16* __restrict__ Abf,
    u16* __restrict__ WAt, u16* __restrict__ WPt) {
  const int bid = blockIdx.x;
  const int tid = threadIdx.x;
  if (bid < 4096) {
    __shared__ float t[32][33];
    const float* W; u16* Wt; int N, K, n0, k0;
    if (bid < 3072) { W = w_attn; Wt = WAt; N = N3D; K = DD;
                      n0 = (bid % 96) * 32; k0 = (bid / 96) * 32; }
    else            { W = w_proj; Wt = WPt; N = DD;  K = DD;
                      int tb = bid - 3072; n0 = (tb % 32) * 32; k0 = (tb / 32) * 32; }
    int tx = tid & 31, ty = tid >> 5;
    for (int i = ty; i < 32; i += 8)
      t[i][tx] = W[(long long)(k0 + i) * N + n0 + tx];
    __syncthreads();
    for (int i = ty; i < 32; i += 8)
      Wt[(long long)(n0 + i) * K + k0 + tx] = f2bf(t[tx][i]);
  } else {
    const long long n = (long long)MM * DD;
    long long i = (long long)(bid - 4096) * 256 + tid;
    for (long long j = i * 4; j < n; j += 2048LL * 256 * 4) {
      f32x4v v = *(const f32x4v*)(inp + j);
      u16x4 o;
      o.x = f2bf(v.x); o.y = f2bf(v.y); o.z = f2bf(v.z); o.w = f2bf(v.w);
      *(u16x4*)(Abf + j) = o;
    }
  }
}

// ---------------- 2. GEMM: C[M][N] = A[M][K] * Bt[N][K]^T + bias -------------
// 128x128 tile, BK=64, 4 waves, double-buffered K-loop with COUNTED vmcnt
// (T4: loads for tile t+1 stay in flight across compute of tile t; no
// vmcnt(0) drain in the main loop). XOR-swizzled LDS via vaddr+immediates.
// mode 1: bf16 out; cols >= 2048 (V) scatter into Vt[bh][d][s].
__global__ __launch_bounds__(256) void gemm_kernel(
    const u16* __restrict__ A, const u16* __restrict__ Bt,
    const float* __restrict__ bias, void* __restrict__ Cout,
    u16* __restrict__ Vt, int Ndim, int Kdim, int mode) {
  // LDS layout: A0@0 A1@16384 B0@32768 B1@49152  (16KB each)
  __shared__ __align__(16) char smem[65536];

  const int tid = threadIdx.x;
  const int lane = tid & 63, wid = tid >> 6;
  const int l15 = lane & 15, lg = lane >> 4;

  const int nwg = (int)(gridDim.x * gridDim.y);
  const int orig = (int)(blockIdx.y * gridDim.x + blockIdx.x);
  const int wg = (orig & 7) * (nwg >> 3) + (orig >> 3);
  const int bx = wg % (int)gridDim.x, by = wg / (int)gridDim.x;
  const int rb = by * 128, cb = bx * 128;
  const int wr = (wid >> 1) * 64, wc = (wid & 1) * 64;

  f32x4v acc[4][4] = {};

  // staging geometry (pre-swizzled source, linear dest)
  const int rlo = tid >> 3;                 // 0..31
  const int cbS = (tid & 7) * 16;
  const int swS = cbS ^ ((rlo & 7) << 4);
  const int sd  = rlo * 128 + cbS;          // dest byte within 32-row chunk

  // read vaddrs: kk folds into ^64, mi/ni and buffer fold into immediates
  const int xr  = (l15 & 7) << 4;
  const int vaA = l15 * 128 + ((lg * 16) ^ xr);
  const int gvA0 = wr * 128 + vaA, gvA1 = gvA0 ^ 64;
  const int gvB0 = wc * 128 + vaA, gvB1 = gvB0 ^ 64;

  // incremental global row pointers (advance per K-step)
  const char* pa[4];
  const char* pb[4];
#pragma unroll
  for (int i = 0; i < 4; ++i) {
    pa[i] = (const char*)A  + (long long)(rb + i * 32 + rlo) * (Kdim * 2) + swS;
    pb[i] = (const char*)Bt + (long long)(cb + i * 32 + rlo) * (Kdim * 2) + swS;
  }

  auto stage = [&](int dofs, int kb) {   // dofs: 0 or 16384; kb: byte delta
#pragma unroll
    for (int i = 0; i < 4; ++i) {
      async16(pa[i] + kb, smem + dofs + i * 4096 + sd);
      async16(pb[i] + kb, smem + 32768 + dofs + i * 4096 + sd);
    }
  };

  auto compute = [&](int aofs, int bofs) {
    u16x8 a0[4], b0[4], a1[4], b1[4];
#pragma unroll
    for (int mi = 0; mi < 4; ++mi) {
      a0[mi] = *(const u16x8*)(smem + aofs + mi * 2048 + gvA0);
      a1[mi] = *(const u16x8*)(smem + aofs + mi * 2048 + gvA1);
    }
#pragma unroll
    for (int ni = 0; ni < 4; ++ni) {
      b0[ni] = *(const u16x8*)(smem + bofs + ni * 2048 + gvB0);
      b1[ni] = *(const u16x8*)(smem + bofs + ni * 2048 + gvB1);
    }
#pragma unroll
    for (int mi = 0; mi < 4; ++mi)
#pragma unroll
      for (int ni = 0; ni < 4; ++ni) {
        acc[mi][ni] = mfma16(a0[mi], b0[ni], acc[mi][ni]);
        acc[mi][ni] = mfma16(a1[mi], b1[ni], acc[mi][ni]);
      }
  };

  const int nK = Kdim >> 6;          // 16 for both GEMMs (even)
  stage(0, 0);                       // tile 0 -> buf0 (8 loads)
  stage(16384, 128);                 // tile 1 -> buf1 (16 outstanding)
  int kt = 0;
  for (; kt + 2 < nK; kt += 2) {
    WAIT_VM(8); BAR();               // buf0 (oldest 8) landed, block-wide
    compute(0, 32768);
    BAR();                           // all waves done reading buf0
    stage(0, 256);                   // tile kt+2 -> buf0
    WAIT_VM(8); BAR();               // buf1 landed
    compute(16384, 49152);
    BAR();
    stage(16384, 384);               // tile kt+3 -> buf1
#pragma unroll
    for (int i = 0; i < 4; ++i) { pa[i] += 256; pb[i] += 256; }
  }
  WAIT_VM(8); BAR();
  compute(0, 32768);                 // tile nK-2
  WAIT_VM(0); BAR();
  compute(16384, 49152);             // tile nK-1

#pragma unroll
  for (int mi = 0; mi < 4; ++mi)
#pragma unroll
    for (int ni = 0; ni < 4; ++ni) {
      int col = cb + wc + ni * 16 + l15;
      float bv = bias[col];
      if (mode == 1 && col >= 2 * DD) {
        int h = (col >> 6) & 15, d = col & 63;
#pragma unroll
        for (int r = 0; r < 4; ++r) {
          int row = rb + wr + mi * 16 + lg * 4 + r;
          int b = row >> 11, s = row & 2047;
          Vt[(((long long)(b * HH + h) * HD + d) << 11) + s] = f2bf(acc[mi][ni][r] + bv);
        }
      } else {
#pragma unroll
        for (int r = 0; r < 4; ++r) {
          int row = rb + wr + mi * 16 + lg * 4 + r;
          float v = acc[mi][ni][r] + bv;
          if (mode) ((u16*)Cout)[(long long)row * Ndim + col] = f2bf(v);
          else      ((float*)Cout)[(long long)row * Ndim + col] = v;
        }
      }
    }
}

// ---------------- 3. flash attention, causal -------------------------------
// 256 thr (4 waves), 32 q-rows/wave, one 128-row q-tile per block; grid 1024,
// all co-resident (4 blocks/CU). Per-CU resident qt sets are {15,14,1,0},
// {13,12,3,2},{11,10,5,4},{9,8,7,6} (heavies together -> short solo tail).
// Counted-vmcnt double-buffer (no drain in main loop). Swapped QK^T with
// row-permuted K feeds -> P in registers. Conflict-free swizzle key
// (row&3)|(((row>>3)&1)<<2). Defer-max softmax (THR=64 raw).
__global__ __launch_bounds__(256, 4) void attn_kernel(
    const u16* __restrict__ qkv, const u16* __restrict__ Vt,
    u16* __restrict__ ctx) {
  // LDS layout: K0@0 K1@8192 V0@16384 V1@24576 (32KB)
  __shared__ __align__(16) char smem[32768];

  const int tid = threadIdx.x, lane = tid & 63, wid = tid >> 6;   // wid 0..3
  const int l15 = lane & 15, lg = lane >> 4;

  // dispatch: d -> xcd = d&7, rank = d>>3; co-resident quadruple on a CU has
  // t = {t0, t0+4, t0+8, t0+12}; qt(t) chosen so each quadruple is
  // {15,14,1,0} / {13,12,3,2} / {11,10,5,4} / {9,8,7,6}.
  const int d = (int)blockIdx.x;
  const int rank = d >> 3;
  const int t = rank >> 3;            // 0..15
  const int jj = t & 3, q4 = t >> 2;
  const int qt = (q4 == 0) ? 15 - 2 * jj : (q4 == 1) ? 14 - 2 * jj
               : (q4 == 2) ? 1 + 2 * jj  : 2 * jj;
  const int bh = (d & 7) * 8 + (rank & 7);
  const int b = bh >> 4, h = bh & 15;

  const u16* Qcol = qkv + (long long)b * SS * N3D + h * HD;
  const u16* Kcol = qkv + (long long)b * SS * N3D + DD + h * HD;
  const u16* Vbh  = Vt + (long long)bh * HD * SS;

  // K A-operand vaddrs, row-permuted rowA = 8*(l15>>2)+(l15&3); key uses
  // (row&3)|(((row>>3)&1)<<2) which is invariant under +4/+32 row offsets.
  const int rowA = 8 * (l15 >> 2) + (l15 & 3);
  const int kA = (((l15 & 3) | (((l15 >> 2) & 1) << 2))) << 4;
  const int vk0 = rowA * 128 + ((lg * 16) ^ kA);   // ks0 ab0 kk0
  const int vk1 = vk0 ^ 64;                        // kk1
  const int vk2 = vk0 + 512;                       // ab1 (+4 rows, same key)
  const int vk3 = vk2 ^ 64;
  // V B-operand vaddr (rows = d 0..15 per di block)
  const int kV = (((l15 & 3) | (((l15 >> 3) & 1) << 2))) << 4;
  const int vv0 = l15 * 128 + ((lg * 16) ^ kV);
  const int vv1 = vv0 ^ 64;

  // staging geometry: 256 thr cover 32 rows x 128B per issue; 2 issues each
  // for K (rows 0..63) and V (d 0..63). Source pre-swizzled with key(rlo).
  const int rlo = tid >> 3;            // 0..31
  const int cbS = (tid & 7) * 16;
  const int kw = (((rlo & 3) | (((rlo >> 3) & 1) << 2))) << 4;  // = key(rlo+32)
  const int swS = cbS ^ kw;
  const int sd  = rlo * 128 + cbS;
  const long long KSTP = 64LL * N3D * 2;   // bytes per k-tile (K rows)
  const long long VSTP = 64LL * 2;         // bytes per k-tile (Vt cols)
  const long long KHLF = 32LL * N3D * 2;   // +32 K rows
  const long long VHLF = 32LL * SS * 2;    // +32 V rows (d)

  auto stage = [&](int dofs, const char* ka, const char* va) {  // 4 loads
    async16(ka,        smem + dofs + sd);
    async16(ka + KHLF, smem + dofs + 4096 + sd);
    async16(va,        smem + 16384 + dofs + sd);
    async16(va + VHLF, smem + 16384 + dofs + 4096 + sd);
  };

  const int q0 = qt * 128;
  const int qw = q0 + wid * 32;        // 32 q-rows per wave
  const int nkb = 2 * qt + 2;          // always even, >= 2

  // Q fragments: rows qw + mi*16 + l15
  u16x8 qf[2][2];
#pragma unroll
  for (int mi = 0; mi < 2; ++mi)
#pragma unroll
    for (int kk = 0; kk < 2; ++kk)
      qf[mi][kk] = *(const u16x8*)(Qcol + (long long)(qw + mi * 16 + l15) * N3D +
                                   kk * 32 + lg * 8);

  f32x4v acc[2][4] = {};
  float m_s[2] = {-1e30f, -1e30f}, l_p[2] = {0.f, 0.f};

  const char* ka = (const char*)Kcol + (long long)rlo * (N3D * 2) + swS;
  const char* va = (const char*)Vbh + (long long)rlo * (SS * 2) + swS;

  auto compute = [&](int kofs, int vofs, int kbase) {
    if (kbase > qw + 31) return;

    // ---- S^T = K(permuted rows) x Q: pf[mi][ks][ab][r] = P[q][k] ----
    // q = qw + mi*16 + l15;  k = kbase + ks*32 + lg*8 + ab*4 + r
    f32x4v pf[2][2][2] = {};
    {
      u16x8 kf0, kf1;
      kf0 = *(const u16x8*)(smem + kofs + vk0);
      kf1 = *(const u16x8*)(smem + kofs + vk1);
      __builtin_amdgcn_s_setprio(1);
      pf[0][0][0] = mfma16(kf0, qf[0][0], pf[0][0][0]);
      pf[0][0][0] = mfma16(kf1, qf[0][1], pf[0][0][0]);
      pf[1][0][0] = mfma16(kf0, qf[1][0], pf[1][0][0]);
      pf[1][0][0] = mfma16(kf1, qf[1][1], pf[1][0][0]);
      __builtin_amdgcn_s_setprio(0);
      kf0 = *(const u16x8*)(smem + kofs + vk2);
      kf1 = *(const u16x8*)(smem + kofs + vk3);
      __builtin_amdgcn_s_setprio(1);
      pf[0][0][1] = mfma16(kf0, qf[0][0], pf[0][0][1]);
      pf[0][0][1] = mfma16(kf1, qf[0][1], pf[0][0][1]);
      pf[1][0][1] = mfma16(kf0, qf[1][0], pf[1][0][1]);
      pf[1][0][1] = mfma16(kf1, qf[1][1], pf[1][0][1]);
      __builtin_amdgcn_s_setprio(0);
      kf0 = *(const u16x8*)(smem + kofs + 4096 + vk0);
      kf1 = *(const u16x8*)(smem + kofs + 4096 + vk1);
      __builtin_amdgcn_s_setprio(1);
      pf[0][1][0] = mfma16(kf0, qf[0][0], pf[0][1][0]);
      pf[0][1][0] = mfma16(kf1, qf[0][1], pf[0][1][0]);
      pf[1][1][0] = mfma16(kf0, qf[1][0], pf[1][1][0]);
      pf[1][1][0] = mfma16(kf1, qf[1][1], pf[1][1][0]);
      __builtin_amdgcn_s_setprio(0);
      kf0 = *(const u16x8*)(smem + kofs + 4096 + vk2);
      kf1 = *(const u16x8*)(smem + kofs + 4096 + vk3);
      __builtin_amdgcn_s_setprio(1);
      pf[0][1][1] = mfma16(kf0, qf[0][0], pf[0][1][1]);
      pf[0][1][1] = mfma16(kf1, qf[0][1], pf[0][1][1]);
      pf[1][1][1] = mfma16(kf0, qf[1][0], pf[1][1][1]);
      pf[1][1][1] = mfma16(kf1, qf[1][1], pf[1][1][1]);
      __builtin_amdgcn_s_setprio(0);
    }

    // ---- causal mask ----
    if (kbase + 63 > qw) {
      const int kl = kbase + lg * 8;
#pragma unroll
      for (int mi = 0; mi < 2; ++mi) {
        const int qg = qw + mi * 16 + l15;
#pragma unroll
        for (int ks = 0; ks < 2; ++ks)
#pragma unroll
          for (int ab = 0; ab < 2; ++ab)
#pragma unroll
            for (int r = 0; r < 4; ++r)
              if (kl + ks * 32 + ab * 4 + r > qg) pf[mi][ks][ab][r] = -1e30f;
      }
    }

    // ---- softmax: per-lane scalar state (q = l15 within mi); defer-max ----
    float lmax[2];
    bool need = false;
#pragma unroll
    for (int mi = 0; mi < 2; ++mi) {
      float v0 = fmaxf(fmaxf(fmaxf(pf[mi][0][0][0], pf[mi][0][0][1]),
                             pf[mi][0][0][2]), pf[mi][0][0][3]);
      float v1 = fmaxf(fmaxf(fmaxf(pf[mi][0][1][0], pf[mi][0][1][1]),
                             pf[mi][0][1][2]), pf[mi][0][1][3]);
      float v2 = fmaxf(fmaxf(fmaxf(pf[mi][1][0][0], pf[mi][1][0][1]),
                             pf[mi][1][0][2]), pf[mi][1][0][3]);
      float v3 = fmaxf(fmaxf(fmaxf(pf[mi][1][1][0], pf[mi][1][1][1]),
                             pf[mi][1][1][2]), pf[mi][1][1][3]);
      lmax[mi] = fmaxf(fmaxf(v0, v1), fmaxf(v2, v3));
      need = need || (lmax[mi] > m_s[mi] + 64.f);
    }
    if (__any(need)) {           // rare: raise shared row max (uniform per l15)
#pragma unroll
      for (int mi = 0; mi < 2; ++mi) {
        float rm = fmaxf(lmax[mi], __shfl_xor(lmax[mi], 16));
        rm = fmaxf(rm, __shfl_xor(rm, 32));
        float newm = fmaxf(m_s[mi], rm);
        float sc = __builtin_exp2f((m_s[mi] - newm) * C8);
        m_s[mi] = newm;
        l_p[mi] *= sc;
#pragma unroll
        for (int r = 0; r < 4; ++r) {
          float scq = __shfl(sc, (lane & 48) + lg * 4 + r);
#pragma unroll
          for (int di = 0; di < 4; ++di) acc[mi][di][r] *= scq;
        }
      }
    }
#pragma unroll
    for (int mi = 0; mi < 2; ++mi) {
      float mC = m_s[mi] * C8;
      float rsum = 0.f;
#pragma unroll
      for (int ks = 0; ks < 2; ++ks)
#pragma unroll
        for (int ab = 0; ab < 2; ++ab)
#pragma unroll
          for (int r = 0; r < 4; ++r) {
            float p = __builtin_exp2f(__builtin_fmaf(pf[mi][ks][ab][r], C8, -mC));
            pf[mi][ks][ab][r] = p;
            rsum += p;
          }
      l_p[mi] += rsum;
    }

    // ---- pack P -> PV A-fragments (in registers) ----
    u16x8 pa[2][2];
#pragma unroll
    for (int mi = 0; mi < 2; ++mi)
#pragma unroll
      for (int ks = 0; ks < 2; ++ks) {
        u32x4 w;
        w.x = (unsigned)f2bf(pf[mi][ks][0][0]) | ((unsigned)f2bf(pf[mi][ks][0][1]) << 16);
        w.y = (unsigned)f2bf(pf[mi][ks][0][2]) | ((unsigned)f2bf(pf[mi][ks][0][3]) << 16);
        w.z = (unsigned)f2bf(pf[mi][ks][1][0]) | ((unsigned)f2bf(pf[mi][ks][1][1]) << 16);
        w.w = (unsigned)f2bf(pf[mi][ks][1][2]) | ((unsigned)f2bf(pf[mi][ks][1][3]) << 16);
        pa[mi][ks] = __builtin_bit_cast(u16x8, w);
      }

    // ---- O += P V ----
#pragma unroll
    for (int di = 0; di < 4; ++di) {
      u16x8 v0 = *(const u16x8*)(smem + vofs + di * 2048 + vv0);
      u16x8 v1 = *(const u16x8*)(smem + vofs + di * 2048 + vv1);
      __builtin_amdgcn_s_setprio(1);
      acc[0][di] = mfma16(pa[0][0], v0, acc[0][di]);
      acc[0][di] = mfma16(pa[0][1], v1, acc[0][di]);
      acc[1][di] = mfma16(pa[1][0], v0, acc[1][di]);
      acc[1][di] = mfma16(pa[1][1], v1, acc[1][di]);
      __builtin_amdgcn_s_setprio(0);
    }
  };

  stage(0, ka, va);                          // tile 0 -> buf0 (4 loads)
  stage(8192, ka + KSTP, va + VSTP);         // tile 1 -> buf1 (8 outstanding)

  int kb = 0;
  for (; kb + 2 < nkb; kb += 2) {
    WAIT_VM(4); BAR();                       // buf0 (oldest 4) landed
    compute(0, 16384, kb * 64);
    BAR();                                   // all waves done reading buf0
    stage(0, ka + 2 * KSTP, va + 2 * VSTP);  // tile kb+2 -> buf0
    WAIT_VM(4); BAR();                       // buf1 landed
    compute(8192, 24576, (kb + 1) * 64);
    BAR();
    stage(8192, ka + 3 * KSTP, va + 3 * VSTP); // tile kb+3 -> buf1
    ka += 2 * KSTP; va += 2 * VSTP;
  }
  WAIT_VM(4); BAR();
  compute(0, 16384, kb * 64);                // tile nkb-2
  WAIT_VM(0); BAR();
  compute(8192, 24576, (kb + 1) * 64);       // tile nkb-1

  // finalize: reduce l across lg-groups once; ctx[b, q, h*64+d]
#pragma unroll
  for (int mi = 0; mi < 2; ++mi) {
    float l_red = l_p[mi] + __shfl_xor(l_p[mi], 16);
    l_red += __shfl_xor(l_red, 32);
#pragma unroll
    for (int r = 0; r < 4; ++r) {
      float lq = __shfl(l_red, (lane & 48) + lg * 4 + r);
      float inv = 1.f / lq;
      int qrow = qw + mi * 16 + lg * 4 + r;
#pragma unroll
      for (int di = 0; di < 4; ++di) {
        int dd = di * 16 + l15;
        ctx[((long long)(b * SS + qrow)) * DD + h * HD + dd] = f2bf(acc[mi][di][r] * inv);
      }
    }
  }
}

// ---------------- launch -----------------------------------------------------
extern "C" void kernel_launch(void* const* d_in, const int* in_sizes, int n_in,
                              void* d_out, int out_size, void* d_ws, size_t ws_size,
                              hipStream_t stream) {
  const float* inp    = (const float*)d_in[0];
  const float* w_attn = (const float*)d_in[1];
  const float* b_attn = (const float*)d_in[2];
  const float* w_proj = (const float*)d_in[3];
  const float* b_proj = (const float*)d_in[4];
  float* out = (float*)d_out;
  char* ws = (char*)d_ws;

  const long long off_A   = 0;                       // inp bf16 [8192][1024]  16MB
  const long long off_WAt = 16777216;                // w_attn^T bf16 [3072][1024]  6MB
  const long long off_WPt = 23068672;                // w_proj^T bf16 [1024][1024]  2MB
  const long long off_qkv = 25165824;                // qkv bf16 [8192][3072]  48MB
  const long long off_ctx = 75497472;                // ctx bf16 [8192][1024] 16MB
  const long long off_Vt  = 92274688;                // Vt [64][64][2048] 16MB
  const long long need    = 109051904;
  if (ws_size < (size_t)need) return;

  u16* Abf = (u16*)(ws + off_A);
  u16* WAt = (u16*)(ws + off_WAt);
  u16* WPt = (u16*)(ws + off_WPt);
  u16* qkv = (u16*)(ws + off_qkv);
  u16* ctx = (u16*)(ws + off_ctx);
  u16* Vt  = (u16*)(ws + off_Vt);

  prep_kernel<<<6144, 256, 0, stream>>>(inp, w_attn, w_proj, Abf, WAt, WPt);
  gemm_kernel<<<dim3(N3D / 128, MM / 128), 256, 0, stream>>>(
      Abf, WAt, b_attn, qkv, Vt, N3D, DD, 1);
  attn_kernel<<<1024, 256, 0, stream>>>(qkv, Vt, ctx);
  gemm_kernel<<<dim3(DD / 128, MM / 128), 256, 0, stream>>>(
      ctx, WPt, b_proj, out, nullptr, DD, DD, 0);
}